// Round 3
// baseline (1984.698 us; speedup 1.0000x reference)
//
#include <hip/hip_runtime.h>
#include <hip/hip_bf16.h>

#define L_SEQ 4096
#define HID 1024
#define NH 4
#define DH 256
#define CK 64
#define BL_TOT 8192   // B*L

__device__ __forceinline__ void storev(float* p, float v) { *p = v; }
__device__ __forceinline__ void storev(__hip_bfloat16* p, float v) { *p = __float2bfloat16(v); }
__device__ __forceinline__ float loadv(const float* p) { return *p; }
__device__ __forceinline__ float loadv(const __hip_bfloat16* p) { return __bfloat162float(*p); }

// ---------------- f32 GEMM: C[M,N] = A[M,K] * B[N,K]^T ----------------
// 64x64 tile, BK=32, 256 threads, 4x4 micro-tile. Vector-ALU f32 (full f32
// fidelity for the chaos-sensitive K/V path; MFMA comes once green).
template <typename AT, typename CT>
__global__ __launch_bounds__(256) void gemm_bt_f32(const AT* __restrict__ A,
                                                   const float* __restrict__ B,
                                                   CT* __restrict__ C, int M, int N, int K) {
    __shared__ float As[64][33];
    __shared__ float Bs[64][33];
    const int tid = threadIdx.x;
    const int tx = tid & 15, ty = tid >> 4;
    const int m0 = blockIdx.x * 64, n0 = blockIdx.y * 64;
    const int lr = tid >> 2, lk = (tid & 3) * 8;
    float acc[4][4];
#pragma unroll
    for (int i = 0; i < 4; ++i)
#pragma unroll
        for (int j = 0; j < 4; ++j) acc[i][j] = 0.f;

    for (int k0 = 0; k0 < K; k0 += 32) {
        float av[8], bv[8];
        const AT* ap = A + (size_t)(m0 + lr) * K + k0 + lk;
        const float* bp = B + (size_t)(n0 + lr) * K + k0 + lk;
#pragma unroll
        for (int t = 0; t < 8; ++t) { av[t] = loadv(ap + t); bv[t] = bp[t]; }
        __syncthreads();
#pragma unroll
        for (int t = 0; t < 8; ++t) { As[lr][lk + t] = av[t]; Bs[lr][lk + t] = bv[t]; }
        __syncthreads();
#pragma unroll
        for (int kk = 0; kk < 32; ++kk) {
            float a4[4], b4[4];
#pragma unroll
            for (int i = 0; i < 4; ++i) a4[i] = As[ty * 4 + i][kk];
#pragma unroll
            for (int j = 0; j < 4; ++j) b4[j] = Bs[tx * 4 + j][kk];
#pragma unroll
            for (int i = 0; i < 4; ++i)
#pragma unroll
                for (int j = 0; j < 4; ++j) acc[i][j] += a4[i] * b4[j];
        }
    }
#pragma unroll
    for (int i = 0; i < 4; ++i)
#pragma unroll
        for (int j = 0; j < 4; ++j)
            storev(&C[(size_t)(m0 + ty * 4 + i) * N + n0 + tx * 4 + j], acc[i][j]);
}

// ---------------- beta = sigmoid(x @ Wbeta^T) ----------------
__global__ __launch_bounds__(256) void beta_kernel(const float* __restrict__ x,
                                                   const float* __restrict__ Wb,
                                                   float* __restrict__ betaB) {
    const int t = blockIdx.x;  // 0..8191
    const int tid = threadIdx.x;
    const int wave = tid >> 6, lane = tid & 63;
    const float* xr = x + (size_t)t * HID;
    float s[4] = {0.f, 0.f, 0.f, 0.f};
    for (int i = tid; i < HID; i += 256) {
        float xv = xr[i];
        s[0] += xv * Wb[i];
        s[1] += xv * Wb[HID + i];
        s[2] += xv * Wb[2 * HID + i];
        s[3] += xv * Wb[3 * HID + i];
    }
#pragma unroll
    for (int off = 32; off; off >>= 1)
#pragma unroll
        for (int h = 0; h < 4; ++h) s[h] += __shfl_down(s[h], off);
    __shared__ float red[4][4];
    if (lane == 0)
#pragma unroll
        for (int h = 0; h < 4; ++h) red[wave][h] = s[h];
    __syncthreads();
    if (tid < 4) {
        float tot = red[0][tid] + red[1][tid] + red[2][tid] + red[3][tid];
        betaB[(size_t)t * 4 + tid] = 1.f / (1.f + expf(-tot));
    }
}

// ---------------- causal depthwise conv (KS=4) + silu + silu (+ per-head l2norm) ----------------
template <typename OUT>
__global__ __launch_bounds__(256) void conv_kernel(const float* __restrict__ G,
                                                   const float* __restrict__ w,  // [HID][KS]
                                                   OUT* __restrict__ out, int do_norm) {
    const int bl = blockIdx.x;  // b*L + l
    const int l = bl & (L_SEQ - 1);
    const int tid = threadIdx.x;
    const int wave = tid >> 6, lane = tid & 63;
    float vals[4];
#pragma unroll
    for (int h = 0; h < 4; ++h) {
        const int c = tid + 256 * h;
        float acc = 0.f;
#pragma unroll
        for (int j = 0; j < 4; ++j) {
            int ls = l - 3 + j;
            float xv = 0.f;
            if (ls >= 0) xv = G[(size_t)(bl - 3 + j) * HID + c];
            acc += xv * w[c * 4 + j];
        }
        float s1 = acc / (1.f + expf(-acc));
        float s2 = s1 / (1.f + expf(-s1));
        vals[h] = s2;
    }
    if (do_norm) {
        float sq[4];
#pragma unroll
        for (int h = 0; h < 4; ++h) sq[h] = vals[h] * vals[h];
#pragma unroll
        for (int off = 32; off; off >>= 1)
#pragma unroll
            for (int h = 0; h < 4; ++h) sq[h] += __shfl_down(sq[h], off);
        __shared__ float red[4][4];
        __shared__ float nrm[4];
        if (lane == 0)
#pragma unroll
            for (int h = 0; h < 4; ++h) red[wave][h] = sq[h];
        __syncthreads();
        if (tid < 4) {
            float tot = red[0][tid] + red[1][tid] + red[2][tid] + red[3][tid];
            nrm[tid] = 1.f / fmaxf(sqrtf(tot), 1e-12f);
        }
        __syncthreads();
#pragma unroll
        for (int h = 0; h < 4; ++h) vals[h] *= nrm[h];
    }
#pragma unroll
    for (int h = 0; h < 4; ++h) storev(&out[(size_t)bl * HID + tid + 256 * h], vals[h]);
}

// ---------------- T matrix per chunk ----------------
__global__ __launch_bounds__(256) void tmat_kernel(const float* __restrict__ Km,
                                                   const float* __restrict__ betaB,
                                                   float* __restrict__ Tg) {
    const int chunk = blockIdx.x;  // 0..127 = b*64+n
    const size_t l0 = (size_t)chunk * 64;
    const int tid = threadIdx.x;
    const int jj = tid & 63;
    const int iw = tid >> 6;
    __shared__ float Kt[64 * 65];
    __shared__ float Ts[64 * 65];
    __shared__ float betS[256];
    betS[tid] = betaB[(size_t)chunk * 256 + tid];
    float acc[16];
#pragma unroll
    for (int s = 0; s < 16; ++s) acc[s] = 0.f;

    for (int ft = 0; ft < 16; ++ft) {
        __syncthreads();
#pragma unroll
        for (int s = 0; s < 16; ++s) {
            int idx = tid + 256 * s;
            Kt[(idx >> 6) * 65 + (idx & 63)] = Km[(l0 + (idx >> 6)) * HID + ft * 64 + (idx & 63)];
        }
        __syncthreads();
        const int h = ft >> 2;
        float part[16];
#pragma unroll
        for (int s = 0; s < 16; ++s) part[s] = 0.f;
        for (int ff = 0; ff < 64; ++ff) {
            float kj = Kt[jj * 65 + ff];
#pragma unroll
            for (int s = 0; s < 16; ++s) part[s] += Kt[(iw + 4 * s) * 65 + ff] * kj;
        }
#pragma unroll
        for (int s = 0; s < 16; ++s) acc[s] += betS[(iw + 4 * s) * 4 + h] * part[s];
    }
    __syncthreads();
#pragma unroll
    for (int s = 0; s < 16; ++s) {
        int i = iw + 4 * s;
        float v = (i > jj) ? -acc[s] : ((i == jj) ? 1.f : 0.f);
        Ts[i * 65 + jj] = v;
    }
    __syncthreads();
    // serial recurrence: T[i,c<i] = 2*T0[i,c] + sum_{j<i} T0[i,j]*T[j,c]
    for (int i = 1; i < 64; ++i) {
        float v = 0.f;
        if (tid < i) {
            v = 2.f * Ts[i * 65 + tid];
            for (int j = 0; j < i; ++j) v += Ts[i * 65 + j] * Ts[j * 65 + tid];
        }
        __syncthreads();
        if (tid < i) Ts[i * 65 + tid] = v;
        __syncthreads();
    }
#pragma unroll
    for (int s = 0; s < 16; ++s) {
        int idx = tid + 256 * s;
        Tg[(size_t)chunk * 4096 + idx] = Ts[(idx >> 6) * 65 + (idx & 63)];
    }
}

// ---------------- W = T*Kb, U = T*Vb  (LDS-staged: safe for Wm==Vm aliasing) ----------------
__global__ __launch_bounds__(256) void wu_kernel(const float* __restrict__ Tg,
                                                 const float* __restrict__ Km,
                                                 const float* __restrict__ Vm,
                                                 const float* __restrict__ betaB,
                                                 float* __restrict__ Wm, float* __restrict__ Um) {
    const int chunk = blockIdx.x;  // 128
    const int h = blockIdx.y;      // 4
    const size_t l0 = (size_t)chunk * 64;
    const int tid = threadIdx.x;
    const int lane = tid & 63, rgrp = tid >> 6;
    __shared__ float Ts[64 * 65];
    __shared__ float KbS[64 * 65];
    __shared__ float VbS[64 * 65];
    __shared__ float betS[64];
#pragma unroll
    for (int s = 0; s < 16; ++s) {
        int idx = tid + 256 * s;
        Ts[(idx >> 6) * 65 + (idx & 63)] = Tg[(size_t)chunk * 4096 + idx];
    }
    if (tid < 64) betS[tid] = betaB[(l0 + tid) * 4 + h];

    for (int fp = 0; fp < 4; ++fp) {
        const int f0 = h * 256 + fp * 64;
        __syncthreads();  // prev-iter compute done; betS/Ts visible on fp==0
#pragma unroll
        for (int s = 0; s < 16; ++s) {
            int idx = tid + 256 * s;
            int row = idx >> 6, col = idx & 63;
            float bj = betS[row];
            size_t gi = (l0 + row) * HID + f0 + col;
            KbS[row * 65 + col] = Km[gi] * bj;
            VbS[row * 65 + col] = Vm[gi] * bj;
        }
        __syncthreads();
        float accW[16], accU[16];
#pragma unroll
        for (int cc = 0; cc < 16; ++cc) { accW[cc] = 0.f; accU[cc] = 0.f; }
        for (int j = 0; j < 64; ++j) {
            float kb = KbS[j * 65 + lane];
            float vb = VbS[j * 65 + lane];
#pragma unroll
            for (int cc = 0; cc < 16; ++cc) {
                float tv = Ts[(rgrp + 4 * cc) * 65 + j];
                accW[cc] += tv * kb;
                accU[cc] += tv * vb;
            }
        }
#pragma unroll
        for (int cc = 0; cc < 16; ++cc) {
            size_t go = (l0 + rgrp + 4 * cc) * HID + f0 + lane;
            Wm[go] = accW[cc];
            Um[go] = accU[cc];
        }
    }
}

// ---------------- per-chunk diagonal dots ----------------
__global__ __launch_bounds__(256) void kwku_kernel(const float* __restrict__ Km,
                                                   const float* __restrict__ Wm,
                                                   const float* __restrict__ Um,
                                                   float* __restrict__ kw, float* __restrict__ ku) {
    const int chunk = blockIdx.x;  // b*64+n
    const int h = blockIdx.y;
    const int e = threadIdx.x;
    const int b = chunk >> 6, n = chunk & 63;
    size_t base = (size_t)chunk * 64 * HID + h * 256 + e;
    float skw = 0.f, sku = 0.f;
    for (int c = 0; c < 64; ++c) {
        float kv = Km[base + (size_t)c * HID];
        skw += kv * Wm[base + (size_t)c * HID];
        sku += kv * Um[base + (size_t)c * HID];
    }
    size_t o = (((size_t)b * 4 + h) * 64 + n) * 256 + e;
    kw[o] = skw;
    ku[o] = sku;
}

// ---------------- diagonal scan over chunks ----------------
__global__ __launch_bounds__(256) void scan_kernel(const float* __restrict__ kw,
                                                   const float* __restrict__ ku,
                                                   float* __restrict__ dsA) {
    const int bh = blockIdx.x;  // 0..7
    const int e = threadIdx.x;
    float ds = 0.f;
    for (int n = 0; n < 64; ++n) {
        size_t idx = ((size_t)bh * 64 + n) * 256 + e;
        dsA[idx] = ds;
        ds = ds * (1.f - kw[idx]) + ku[idx];
    }
}

__device__ __forceinline__ float block_sum(float v, float* red) {
#pragma unroll
    for (int off = 32; off; off >>= 1) v += __shfl_down(v, off);
    const int wave = threadIdx.x >> 6;
    if ((threadIdx.x & 63) == 0) red[wave] = v;
    __syncthreads();
    float t = red[0] + red[1] + red[2] + red[3];
    __syncthreads();
    return t;
}

// ---------------- o = q*ds + [c<=b]*A*(u - w*ds); fused RMSNorm + bf16 cast ----------------
// ob aliases Qb: each thread reads its own q elements into registers before
// overwriting them -> alias-safe.
__global__ __launch_bounds__(256) void o_kernel(const __hip_bfloat16* __restrict__ Qb,
                                                const float* __restrict__ Km,
                                                const float* __restrict__ Wm,
                                                const float* __restrict__ Um,
                                                const float* __restrict__ dsA,
                                                const float* __restrict__ rmsw,
                                                __hip_bfloat16* __restrict__ ob) {
    const int bl = blockIdx.x;
    const int b = bl >> 12, l = bl & (L_SEQ - 1);
    const int n = l >> 6, cpos = l & 63;
    const int tid = threadIdx.x;
    __shared__ float red[4];
    const size_t rowb = (size_t)bl * HID;
    float dsv[4], qv[4], ov[4];
#pragma unroll
    for (int h = 0; h < 4; ++h) {
        dsv[h] = dsA[(((size_t)b * 4 + h) * 64 + n) * 256 + tid];
        qv[h] = __bfloat162float(Qb[rowb + tid + 256 * h]);
    }
    const bool doA = (cpos <= b);  // tril on the (B=2, C=64) A matrix
    float Aval = 0.f;
    if (doA) {
        float s = 0.f;
#pragma unroll
        for (int h = 0; h < 4; ++h) s += qv[h] * Km[rowb + tid + 256 * h];
        Aval = block_sum(s, red);
    }
    float ss = 0.f;
#pragma unroll
    for (int h = 0; h < 4; ++h) {
        int c = tid + 256 * h;
        float u = Um[rowb + c] - Wm[rowb + c] * dsv[h];
        float o = qv[h] * dsv[h];
        if (doA) o += Aval * u;
        ov[h] = o;
        ss += o * o;
    }
    float tot = block_sum(ss, red);
    float scale = rsqrtf(tot * (1.f / 1024.f) + 1e-5f);
#pragma unroll
    for (int h = 0; h < 4; ++h) {
        int c = tid + 256 * h;
        ob[rowb + c] = __float2bfloat16(ov[h] * scale * rmsw[c]);
    }
}

// ---------------- final state S = sum_n K^T (U - W*ds_n), f32 direct to out1 ----------------
__global__ __launch_bounds__(256) void s_kernel(const float* __restrict__ Km,
                                                const float* __restrict__ Wm,
                                                const float* __restrict__ Um,
                                                const float* __restrict__ dsA,
                                                float* __restrict__ Sout) {
    const int bh = blockIdx.x;  // 0..7 = b*4+h
    const int b = bh >> 2, h = bh & 3;
    const int dt = blockIdx.y, et = blockIdx.z;  // 0..3 each
    const int tid = threadIdx.x;
    const int td = tid >> 4, te = tid & 15;
    __shared__ float KtS[64 * 68];
    __shared__ float UtS[64 * 68];
    __shared__ float dse[64];
    float acc[16];
#pragma unroll
    for (int q2 = 0; q2 < 16; ++q2) acc[q2] = 0.f;
    for (int n = 0; n < 64; ++n) {
        const size_t l0 = ((size_t)b * 64 + n) * 64;
        __syncthreads();
        if (tid < 64) dse[tid] = dsA[((size_t)bh * 64 + n) * 256 + et * 64 + tid];
        __syncthreads();
#pragma unroll
        for (int s = 0; s < 16; ++s) {
            int idx = tid + 256 * s;
            int c = idx >> 6, qq = idx & 63;
            size_t gK = (l0 + c) * HID + h * 256 + dt * 64 + qq;
            size_t gU = (l0 + c) * HID + h * 256 + et * 64 + qq;
            KtS[c * 68 + qq] = Km[gK];
            UtS[c * 68 + qq] = Um[gU] - Wm[gU] * dse[qq];
        }
        __syncthreads();
        for (int c = 0; c < 64; ++c) {
            float4 kd = *(const float4*)&KtS[c * 68 + td * 4];
            float4 ue = *(const float4*)&UtS[c * 68 + te * 4];
            acc[0] += kd.x * ue.x;   acc[1] += kd.x * ue.y;   acc[2] += kd.x * ue.z;   acc[3] += kd.x * ue.w;
            acc[4] += kd.y * ue.x;   acc[5] += kd.y * ue.y;   acc[6] += kd.y * ue.z;   acc[7] += kd.y * ue.w;
            acc[8] += kd.z * ue.x;   acc[9] += kd.z * ue.y;   acc[10] += kd.z * ue.z;  acc[11] += kd.z * ue.w;
            acc[12] += kd.w * ue.x;  acc[13] += kd.w * ue.y;  acc[14] += kd.w * ue.z;  acc[15] += kd.w * ue.w;
        }
    }
    // S layout: ((b*4+h)*256 + d)*256 + e
#pragma unroll
    for (int i = 0; i < 4; ++i)
#pragma unroll
        for (int j = 0; j < 4; ++j)
            Sout[((size_t)bh * 256 + dt * 64 + td * 4 + i) * 256 + et * 64 + te * 4 + j] = acc[i * 4 + j];
}

extern "C" void kernel_launch(void* const* d_in, const int* in_sizes, int n_in,
                              void* d_out, int out_size, void* d_ws, size_t ws_size,
                              hipStream_t stream) {
    const float* x     = (const float*)d_in[0];
    const float* Wq    = (const float*)d_in[1];
    const float* Wk    = (const float*)d_in[2];
    const float* Wv    = (const float*)d_in[3];
    const float* convq = (const float*)d_in[4];
    const float* convk = (const float*)d_in[5];
    const float* convv = (const float*)d_in[6];
    const float* Wbeta = (const float*)d_in[7];
    const float* rmsw  = (const float*)d_in[8];
    const float* Wo    = (const float*)d_in[9];

    // ---- workspace map (~121 MiB; aliases documented) ----
    char* ws = (char*)d_ws;
    size_t off = 0;
    auto alloc = [&](size_t bytes) {
        char* p = ws + off;
        off += (bytes + 255) & ~(size_t)255;
        return (void*)p;
    };
    float* Gt   = (float*)alloc((size_t)BL_TOT * HID * 4);  // gemm out; later Um
    float* Km   = (float*)alloc((size_t)BL_TOT * HID * 4);
    float* Vm   = (float*)alloc((size_t)BL_TOT * HID * 4);  // later Wm (wu is LDS-staged -> alias-safe)
    __hip_bfloat16* Qm = (__hip_bfloat16*)alloc((size_t)BL_TOT * HID * 2);  // later ob
    float* Tg    = (float*)alloc((size_t)128 * 4096 * 4);
    float* betaB = (float*)alloc((size_t)BL_TOT * 4 * 4);
    float* kwB   = (float*)alloc((size_t)8 * 64 * 256 * 4);
    float* kuB   = (float*)alloc((size_t)8 * 64 * 256 * 4);
    float* dsA   = (float*)alloc((size_t)8 * 64 * 256 * 4);
    float* Um = Gt;   // Gt dead after conv-V
    float* Wm = Vm;   // Vm dead after wu_kernel's LDS staging
    __hip_bfloat16* ob = Qm;  // Qm(q) dead after o_kernel reads its own row

    // Reference output dtype is float32 -> d_out is float*.
    float* out0 = (float*)d_out;                       // (B, L, HID)
    float* out1 = out0 + (size_t)BL_TOT * HID;         // (B, H, DH, DH)

    dim3 blk(256);
    dim3 ggrid(BL_TOT / 64, HID / 64);  // (128, 16)

    beta_kernel<<<BL_TOT, blk, 0, stream>>>(x, Wbeta, betaB);

    // Q path
    gemm_bt_f32<float, float><<<ggrid, blk, 0, stream>>>(x, Wq, Gt, BL_TOT, HID, HID);
    conv_kernel<__hip_bfloat16><<<BL_TOT, blk, 0, stream>>>(Gt, convq, Qm, 1);
    // K path
    gemm_bt_f32<float, float><<<ggrid, blk, 0, stream>>>(x, Wk, Gt, BL_TOT, HID, HID);
    conv_kernel<float><<<BL_TOT, blk, 0, stream>>>(Gt, convk, Km, 1);
    // V path
    gemm_bt_f32<float, float><<<ggrid, blk, 0, stream>>>(x, Wv, Gt, BL_TOT, HID, HID);
    conv_kernel<float><<<BL_TOT, blk, 0, stream>>>(Gt, convv, Vm, 0);

    // chunked delta rule
    tmat_kernel<<<128, blk, 0, stream>>>(Km, betaB, Tg);
    wu_kernel<<<dim3(128, 4), blk, 0, stream>>>(Tg, Km, Vm, betaB, Wm, Um);
    kwku_kernel<<<dim3(128, 4), blk, 0, stream>>>(Km, Wm, Um, kwB, kuB);
    scan_kernel<<<8, blk, 0, stream>>>(kwB, kuB, dsA);
    o_kernel<<<BL_TOT, blk, 0, stream>>>(Qm, Km, Wm, Um, dsA, rmsw, ob);
    s_kernel<<<dim3(8, 4, 4), blk, 0, stream>>>(Km, Wm, Um, dsA, out1);

    // final projection (bf16 A, f32 weights, f32 out)
    gemm_bt_f32<__hip_bfloat16, float><<<ggrid, blk, 0, stream>>>(ob, Wo, out0, BL_TOT, HID, HID);
}

// Round 4
// 875.325 us; speedup vs baseline: 2.2674x; 2.2674x over previous
//
#include <hip/hip_runtime.h>
#include <hip/hip_bf16.h>

#define L_SEQ 4096
#define HID 1024
#define NH 4
#define DH 256
#define CK 64
#define BL_TOT 8192   // B*L

typedef short v8s __attribute__((ext_vector_type(8)));
typedef unsigned short v8u __attribute__((ext_vector_type(8)));
typedef float v4f __attribute__((ext_vector_type(4)));

__device__ __forceinline__ void storev(float* p, float v) { *p = v; }
__device__ __forceinline__ void storev(__hip_bfloat16* p, float v) { *p = __float2bfloat16(v); }

__device__ __forceinline__ unsigned short f2bu(float f) {
    __hip_bfloat16 h = __float2bfloat16(f);
    return *(unsigned short*)&h;
}
__device__ __forceinline__ float bu2f(unsigned short u) {
    __hip_bfloat16 h = *(__hip_bfloat16*)&u;
    return __bfloat162float(h);
}

// ---------------- f32 -> (bf16 hi, bf16 lo) split ----------------
__global__ __launch_bounds__(256) void split_kernel(const float* __restrict__ in,
                                                    unsigned short* __restrict__ hi,
                                                    unsigned short* __restrict__ lo, int n) {
    int i = blockIdx.x * 256 + threadIdx.x;
    int stride = gridDim.x * 256;
    for (; i < n; i += stride) {
        float v = in[i];
        unsigned short h = f2bu(v);
        hi[i] = h;
        lo[i] = f2bu(v - bu2f(h));
    }
}

// ---------------- MFMA bf16 GEMM: C[M,N] = A[M,K] * B[N,K]^T  (f32 out) ----------------
// SPLIT=1: A=Ah+Al, B=Bh+Bl, 3-term (hi*hi + hi*lo + lo*hi) -> ~f32 fidelity.
template <int SPLIT>
__global__ __launch_bounds__(256) void gemm_mfma(const unsigned short* __restrict__ Ah,
                                                 const unsigned short* __restrict__ Al,
                                                 const unsigned short* __restrict__ Bh,
                                                 const unsigned short* __restrict__ Bl,
                                                 float* __restrict__ C, int M, int N, int K) {
    __shared__ unsigned short AsH[128 * 40];
    __shared__ unsigned short BsH[128 * 40];
    __shared__ unsigned short AsL[SPLIT ? 128 * 40 : 8];
    __shared__ unsigned short BsL[SPLIT ? 128 * 40 : 8];
    const int tid = threadIdx.x;
    const int wave = tid >> 6, lane = tid & 63;
    const int quad = lane >> 4, l16 = lane & 15;
    const int m0 = blockIdx.x * 128, n0 = blockIdx.y * 128;
    const int wm = (wave >> 1) * 64, wn = (wave & 1) * 64;
    const int r0 = tid >> 2;        // tile row (0..63); +64 for second issue
    const int kk = (tid & 3) * 8;   // k offset within BK=32 (8 bf16 = 16B)

    v4f acc[4][4];
#pragma unroll
    for (int a = 0; a < 4; ++a)
#pragma unroll
        for (int b = 0; b < 4; ++b) { v4f z = {0.f, 0.f, 0.f, 0.f}; acc[a][b] = z; }

    for (int k0 = 0; k0 < K; k0 += 32) {
        v8u ah0 = *(const v8u*)(Ah + (size_t)(m0 + r0) * K + k0 + kk);
        v8u ah1 = *(const v8u*)(Ah + (size_t)(m0 + r0 + 64) * K + k0 + kk);
        v8u bh0 = *(const v8u*)(Bh + (size_t)(n0 + r0) * K + k0 + kk);
        v8u bh1 = *(const v8u*)(Bh + (size_t)(n0 + r0 + 64) * K + k0 + kk);
        v8u al0, al1, bl0, bl1;
        if (SPLIT) {
            al0 = *(const v8u*)(Al + (size_t)(m0 + r0) * K + k0 + kk);
            al1 = *(const v8u*)(Al + (size_t)(m0 + r0 + 64) * K + k0 + kk);
            bl0 = *(const v8u*)(Bl + (size_t)(n0 + r0) * K + k0 + kk);
            bl1 = *(const v8u*)(Bl + (size_t)(n0 + r0 + 64) * K + k0 + kk);
        }
        __syncthreads();
        *(v8u*)&AsH[r0 * 40 + kk] = ah0;
        *(v8u*)&AsH[(r0 + 64) * 40 + kk] = ah1;
        *(v8u*)&BsH[r0 * 40 + kk] = bh0;
        *(v8u*)&BsH[(r0 + 64) * 40 + kk] = bh1;
        if (SPLIT) {
            *(v8u*)&AsL[r0 * 40 + kk] = al0;
            *(v8u*)&AsL[(r0 + 64) * 40 + kk] = al1;
            *(v8u*)&BsL[r0 * 40 + kk] = bl0;
            *(v8u*)&BsL[(r0 + 64) * 40 + kk] = bl1;
        }
        __syncthreads();
        v8s afh[4], bfh[4], afl[4], bfl[4];
#pragma unroll
        for (int mt = 0; mt < 4; ++mt) afh[mt] = *(const v8s*)&AsH[(wm + mt * 16 + l16) * 40 + quad * 8];
#pragma unroll
        for (int nt = 0; nt < 4; ++nt) bfh[nt] = *(const v8s*)&BsH[(wn + nt * 16 + l16) * 40 + quad * 8];
        if (SPLIT) {
#pragma unroll
            for (int mt = 0; mt < 4; ++mt) afl[mt] = *(const v8s*)&AsL[(wm + mt * 16 + l16) * 40 + quad * 8];
#pragma unroll
            for (int nt = 0; nt < 4; ++nt) bfl[nt] = *(const v8s*)&BsL[(wn + nt * 16 + l16) * 40 + quad * 8];
        }
#pragma unroll
        for (int mt = 0; mt < 4; ++mt)
#pragma unroll
            for (int nt = 0; nt < 4; ++nt) {
                acc[mt][nt] = __builtin_amdgcn_mfma_f32_16x16x32_bf16(afh[mt], bfh[nt], acc[mt][nt], 0, 0, 0);
                if (SPLIT) {
                    acc[mt][nt] = __builtin_amdgcn_mfma_f32_16x16x32_bf16(afh[mt], bfl[nt], acc[mt][nt], 0, 0, 0);
                    acc[mt][nt] = __builtin_amdgcn_mfma_f32_16x16x32_bf16(afl[mt], bfh[nt], acc[mt][nt], 0, 0, 0);
                }
            }
    }
    // C/D layout (m89-verified): col = lane&15, row = (lane>>4)*4 + reg
#pragma unroll
    for (int mt = 0; mt < 4; ++mt)
#pragma unroll
        for (int nt = 0; nt < 4; ++nt) {
            int row = m0 + wm + mt * 16 + quad * 4;
            int col = n0 + wn + nt * 16 + l16;
#pragma unroll
            for (int r = 0; r < 4; ++r)
                C[(size_t)(row + r) * N + col] = acc[mt][nt][r];
        }
}

// ---------------- beta = sigmoid(x @ Wbeta^T) ----------------
__global__ __launch_bounds__(256) void beta_kernel(const float* __restrict__ x,
                                                   const float* __restrict__ Wb,
                                                   float* __restrict__ betaB) {
    const int t = blockIdx.x;  // 0..8191
    const int tid = threadIdx.x;
    const int wave = tid >> 6, lane = tid & 63;
    const float* xr = x + (size_t)t * HID;
    float s[4] = {0.f, 0.f, 0.f, 0.f};
    for (int i = tid; i < HID; i += 256) {
        float xv = xr[i];
        s[0] += xv * Wb[i];
        s[1] += xv * Wb[HID + i];
        s[2] += xv * Wb[2 * HID + i];
        s[3] += xv * Wb[3 * HID + i];
    }
#pragma unroll
    for (int off = 32; off; off >>= 1)
#pragma unroll
        for (int h = 0; h < 4; ++h) s[h] += __shfl_down(s[h], off);
    __shared__ float red[4][4];
    if (lane == 0)
#pragma unroll
        for (int h = 0; h < 4; ++h) red[wave][h] = s[h];
    __syncthreads();
    if (tid < 4) {
        float tot = red[0][tid] + red[1][tid] + red[2][tid] + red[3][tid];
        betaB[(size_t)t * 4 + tid] = 1.f / (1.f + expf(-tot));
    }
}

// ---------------- causal depthwise conv (KS=4) + silu + silu (+ per-head l2norm) ----------------
template <typename OUT>
__global__ __launch_bounds__(256) void conv_kernel(const float* __restrict__ G,
                                                   const float* __restrict__ w,  // [HID][KS]
                                                   OUT* __restrict__ out, int do_norm) {
    const int bl = blockIdx.x;  // b*L + l
    const int l = bl & (L_SEQ - 1);
    const int tid = threadIdx.x;
    const int wave = tid >> 6, lane = tid & 63;
    float vals[4];
#pragma unroll
    for (int h = 0; h < 4; ++h) {
        const int c = tid + 256 * h;
        float acc = 0.f;
#pragma unroll
        for (int j = 0; j < 4; ++j) {
            int ls = l - 3 + j;
            float xv = 0.f;
            if (ls >= 0) xv = G[(size_t)(bl - 3 + j) * HID + c];
            acc += xv * w[c * 4 + j];
        }
        float s1 = acc / (1.f + expf(-acc));
        float s2 = s1 / (1.f + expf(-s1));
        vals[h] = s2;
    }
    if (do_norm) {
        float sq[4];
#pragma unroll
        for (int h = 0; h < 4; ++h) sq[h] = vals[h] * vals[h];
#pragma unroll
        for (int off = 32; off; off >>= 1)
#pragma unroll
            for (int h = 0; h < 4; ++h) sq[h] += __shfl_down(sq[h], off);
        __shared__ float red[4][4];
        __shared__ float nrm[4];
        if (lane == 0)
#pragma unroll
            for (int h = 0; h < 4; ++h) red[wave][h] = sq[h];
        __syncthreads();
        if (tid < 4) {
            float tot = red[0][tid] + red[1][tid] + red[2][tid] + red[3][tid];
            nrm[tid] = 1.f / fmaxf(sqrtf(tot), 1e-12f);
        }
        __syncthreads();
#pragma unroll
        for (int h = 0; h < 4; ++h) vals[h] *= nrm[h];
    }
#pragma unroll
    for (int h = 0; h < 4; ++h) storev(&out[(size_t)bl * HID + tid + 256 * h], vals[h]);
}

// ---------------- T matrix per chunk ----------------
__global__ __launch_bounds__(256) void tmat_kernel(const float* __restrict__ Km,
                                                   const float* __restrict__ betaB,
                                                   float* __restrict__ Tg) {
    const int chunk = blockIdx.x;  // 0..127 = b*64+n
    const size_t l0 = (size_t)chunk * 64;
    const int tid = threadIdx.x;
    const int jj = tid & 63;
    const int iw = tid >> 6;
    __shared__ float Kt[64 * 65];
    __shared__ float Ts[64 * 65];
    __shared__ float betS[256];
    betS[tid] = betaB[(size_t)chunk * 256 + tid];
    float acc[16];
#pragma unroll
    for (int s = 0; s < 16; ++s) acc[s] = 0.f;

    for (int ft = 0; ft < 16; ++ft) {
        __syncthreads();
#pragma unroll
        for (int s = 0; s < 16; ++s) {
            int idx = tid + 256 * s;
            Kt[(idx >> 6) * 65 + (idx & 63)] = Km[(l0 + (idx >> 6)) * HID + ft * 64 + (idx & 63)];
        }
        __syncthreads();
        const int h = ft >> 2;
        float part[16];
#pragma unroll
        for (int s = 0; s < 16; ++s) part[s] = 0.f;
        for (int ff = 0; ff < 64; ++ff) {
            float kj = Kt[jj * 65 + ff];
#pragma unroll
            for (int s = 0; s < 16; ++s) part[s] += Kt[(iw + 4 * s) * 65 + ff] * kj;
        }
#pragma unroll
        for (int s = 0; s < 16; ++s) acc[s] += betS[(iw + 4 * s) * 4 + h] * part[s];
    }
    __syncthreads();
#pragma unroll
    for (int s = 0; s < 16; ++s) {
        int i = iw + 4 * s;
        float v = (i > jj) ? -acc[s] : ((i == jj) ? 1.f : 0.f);
        Ts[i * 65 + jj] = v;
    }
    __syncthreads();
    // serial recurrence: T[i,c<i] = 2*T0[i,c] + sum_{j<i} T0[i,j]*T[j,c]
    for (int i = 1; i < 64; ++i) {
        float v = 0.f;
        if (tid < i) {
            v = 2.f * Ts[i * 65 + tid];
            for (int j = 0; j < i; ++j) v += Ts[i * 65 + j] * Ts[j * 65 + tid];
        }
        __syncthreads();
        if (tid < i) Ts[i * 65 + tid] = v;
        __syncthreads();
    }
#pragma unroll
    for (int s = 0; s < 16; ++s) {
        int idx = tid + 256 * s;
        Tg[(size_t)chunk * 4096 + idx] = Ts[(idx >> 6) * 65 + (idx & 63)];
    }
}

// ---------------- W = T*Kb, U = T*Vb  (LDS-staged: safe for Wm==Vm aliasing) ----------------
__global__ __launch_bounds__(256) void wu_kernel(const float* __restrict__ Tg,
                                                 const float* __restrict__ Km,
                                                 const float* __restrict__ Vm,
                                                 const float* __restrict__ betaB,
                                                 float* __restrict__ Wm, float* __restrict__ Um) {
    const int chunk = blockIdx.x;  // 128
    const int h = blockIdx.y;      // 4
    const size_t l0 = (size_t)chunk * 64;
    const int tid = threadIdx.x;
    const int lane = tid & 63, rgrp = tid >> 6;
    __shared__ float Ts[64 * 65];
    __shared__ float KbS[64 * 65];
    __shared__ float VbS[64 * 65];
    __shared__ float betS[64];
#pragma unroll
    for (int s = 0; s < 16; ++s) {
        int idx = tid + 256 * s;
        Ts[(idx >> 6) * 65 + (idx & 63)] = Tg[(size_t)chunk * 4096 + idx];
    }
    if (tid < 64) betS[tid] = betaB[(l0 + tid) * 4 + h];

    for (int fp = 0; fp < 4; ++fp) {
        const int f0 = h * 256 + fp * 64;
        __syncthreads();  // prev-iter compute done; betS/Ts visible on fp==0
#pragma unroll
        for (int s = 0; s < 16; ++s) {
            int idx = tid + 256 * s;
            int row = idx >> 6, col = idx & 63;
            float bj = betS[row];
            size_t gi = (l0 + row) * HID + f0 + col;
            KbS[row * 65 + col] = Km[gi] * bj;
            VbS[row * 65 + col] = Vm[gi] * bj;
        }
        __syncthreads();
        float accW[16], accU[16];
#pragma unroll
        for (int cc = 0; cc < 16; ++cc) { accW[cc] = 0.f; accU[cc] = 0.f; }
        for (int j = 0; j < 64; ++j) {
            float kb = KbS[j * 65 + lane];
            float vb = VbS[j * 65 + lane];
#pragma unroll
            for (int cc = 0; cc < 16; ++cc) {
                float tv = Ts[(rgrp + 4 * cc) * 65 + j];
                accW[cc] += tv * kb;
                accU[cc] += tv * vb;
            }
        }
#pragma unroll
        for (int cc = 0; cc < 16; ++cc) {
            size_t go = (l0 + rgrp + 4 * cc) * HID + f0 + lane;
            Wm[go] = accW[cc];
            Um[go] = accU[cc];
        }
    }
}

// ---------------- per-chunk diagonal dots ----------------
__global__ __launch_bounds__(256) void kwku_kernel(const float* __restrict__ Km,
                                                   const float* __restrict__ Wm,
                                                   const float* __restrict__ Um,
                                                   float* __restrict__ kw, float* __restrict__ ku) {
    const int chunk = blockIdx.x;  // b*64+n
    const int h = blockIdx.y;
    const int e = threadIdx.x;
    const int b = chunk >> 6, n = chunk & 63;
    size_t base = (size_t)chunk * 64 * HID + h * 256 + e;
    float skw = 0.f, sku = 0.f;
    for (int c = 0; c < 64; ++c) {
        float kv = Km[base + (size_t)c * HID];
        skw += kv * Wm[base + (size_t)c * HID];
        sku += kv * Um[base + (size_t)c * HID];
    }
    size_t o = (((size_t)b * 4 + h) * 64 + n) * 256 + e;
    kw[o] = skw;
    ku[o] = sku;
}

// ---------------- diagonal scan over chunks ----------------
__global__ __launch_bounds__(256) void scan_kernel(const float* __restrict__ kw,
                                                   const float* __restrict__ ku,
                                                   float* __restrict__ dsA) {
    const int bh = blockIdx.x;  // 0..7
    const int e = threadIdx.x;
    float ds = 0.f;
    for (int n = 0; n < 64; ++n) {
        size_t idx = ((size_t)bh * 64 + n) * 256 + e;
        dsA[idx] = ds;
        ds = ds * (1.f - kw[idx]) + ku[idx];
    }
}

__device__ __forceinline__ float block_sum(float v, float* red) {
#pragma unroll
    for (int off = 32; off; off >>= 1) v += __shfl_down(v, off);
    const int wave = threadIdx.x >> 6;
    if ((threadIdx.x & 63) == 0) red[wave] = v;
    __syncthreads();
    float t = red[0] + red[1] + red[2] + red[3];
    __syncthreads();
    return t;
}

// ---------------- o = q*ds + [c<=b]*A*(u - w*ds); fused RMSNorm + bf16 cast ----------------
// ob aliases Qb: each thread reads its own q elements into registers before
// overwriting them -> alias-safe.
__global__ __launch_bounds__(256) void o_kernel(const __hip_bfloat16* __restrict__ Qb,
                                                const float* __restrict__ Km,
                                                const float* __restrict__ Wm,
                                                const float* __restrict__ Um,
                                                const float* __restrict__ dsA,
                                                const float* __restrict__ rmsw,
                                                __hip_bfloat16* __restrict__ ob) {
    const int bl = blockIdx.x;
    const int b = bl >> 12, l = bl & (L_SEQ - 1);
    const int n = l >> 6, cpos = l & 63;
    const int tid = threadIdx.x;
    __shared__ float red[4];
    const size_t rowb = (size_t)bl * HID;
    float dsv[4], qv[4], ov[4];
#pragma unroll
    for (int h = 0; h < 4; ++h) {
        dsv[h] = dsA[(((size_t)b * 4 + h) * 64 + n) * 256 + tid];
        qv[h] = __bfloat162float(Qb[rowb + tid + 256 * h]);
    }
    const bool doA = (cpos <= b);  // tril on the (B=2, C=64) A matrix
    float Aval = 0.f;
    if (doA) {
        float s = 0.f;
#pragma unroll
        for (int h = 0; h < 4; ++h) s += qv[h] * Km[rowb + tid + 256 * h];
        Aval = block_sum(s, red);
    }
    float ss = 0.f;
#pragma unroll
    for (int h = 0; h < 4; ++h) {
        int c = tid + 256 * h;
        float u = Um[rowb + c] - Wm[rowb + c] * dsv[h];
        float o = qv[h] * dsv[h];
        if (doA) o += Aval * u;
        ov[h] = o;
        ss += o * o;
    }
    float tot = block_sum(ss, red);
    float scale = rsqrtf(tot * (1.f / 1024.f) + 1e-5f);
#pragma unroll
    for (int h = 0; h < 4; ++h) {
        int c = tid + 256 * h;
        ob[rowb + c] = __float2bfloat16(ov[h] * scale * rmsw[c]);
    }
}

// ---------------- final state S = sum_n K^T (U - W*ds_n), f32 direct to out1 ----------------
__global__ __launch_bounds__(256) void s_kernel(const float* __restrict__ Km,
                                                const float* __restrict__ Wm,
                                                const float* __restrict__ Um,
                                                const float* __restrict__ dsA,
                                                float* __restrict__ Sout) {
    const int bh = blockIdx.x;  // 0..7 = b*4+h
    const int b = bh >> 2, h = bh & 3;
    const int dt = blockIdx.y, et = blockIdx.z;  // 0..3 each
    const int tid = threadIdx.x;
    const int td = tid >> 4, te = tid & 15;
    __shared__ float KtS[64 * 68];
    __shared__ float UtS[64 * 68];
    __shared__ float dse[64];
    float acc[16];
#pragma unroll
    for (int q2 = 0; q2 < 16; ++q2) acc[q2] = 0.f;
    for (int n = 0; n < 64; ++n) {
        const size_t l0 = ((size_t)b * 64 + n) * 64;
        __syncthreads();
        if (tid < 64) dse[tid] = dsA[((size_t)bh * 64 + n) * 256 + et * 64 + tid];
        __syncthreads();
#pragma unroll
        for (int s = 0; s < 16; ++s) {
            int idx = tid + 256 * s;
            int c = idx >> 6, qq = idx & 63;
            size_t gK = (l0 + c) * HID + h * 256 + dt * 64 + qq;
            size_t gU = (l0 + c) * HID + h * 256 + et * 64 + qq;
            KtS[c * 68 + qq] = Km[gK];
            UtS[c * 68 + qq] = Um[gU] - Wm[gU] * dse[qq];
        }
        __syncthreads();
        for (int c = 0; c < 64; ++c) {
            float4 kd = *(const float4*)&KtS[c * 68 + td * 4];
            float4 ue = *(const float4*)&UtS[c * 68 + te * 4];
            acc[0] += kd.x * ue.x;   acc[1] += kd.x * ue.y;   acc[2] += kd.x * ue.z;   acc[3] += kd.x * ue.w;
            acc[4] += kd.y * ue.x;   acc[5] += kd.y * ue.y;   acc[6] += kd.y * ue.z;   acc[7] += kd.y * ue.w;
            acc[8] += kd.z * ue.x;   acc[9] += kd.z * ue.y;   acc[10] += kd.z * ue.z;  acc[11] += kd.z * ue.w;
            acc[12] += kd.w * ue.x;  acc[13] += kd.w * ue.y;  acc[14] += kd.w * ue.z;  acc[15] += kd.w * ue.w;
        }
    }
    // S layout: ((b*4+h)*256 + d)*256 + e
#pragma unroll
    for (int i = 0; i < 4; ++i)
#pragma unroll
        for (int j = 0; j < 4; ++j)
            Sout[((size_t)bh * 256 + dt * 64 + td * 4 + i) * 256 + et * 64 + te * 4 + j] = acc[i * 4 + j];
}

extern "C" void kernel_launch(void* const* d_in, const int* in_sizes, int n_in,
                              void* d_out, int out_size, void* d_ws, size_t ws_size,
                              hipStream_t stream) {
    const float* x     = (const float*)d_in[0];
    const float* Wq    = (const float*)d_in[1];
    const float* Wk    = (const float*)d_in[2];
    const float* Wv    = (const float*)d_in[3];
    const float* convq = (const float*)d_in[4];
    const float* convk = (const float*)d_in[5];
    const float* convv = (const float*)d_in[6];
    const float* Wbeta = (const float*)d_in[7];
    const float* rmsw  = (const float*)d_in[8];
    const float* Wo    = (const float*)d_in[9];

    // ---- workspace map (~136 MiB; aliases documented) ----
    char* ws = (char*)d_ws;
    size_t off = 0;
    auto alloc = [&](size_t bytes) {
        char* p = ws + off;
        off += (bytes + 255) & ~(size_t)255;
        return (void*)p;
    };
    unsigned short* xhi = (unsigned short*)alloc((size_t)BL_TOT * HID * 2);  // later Qm/ob
    unsigned short* xlo = (unsigned short*)alloc((size_t)BL_TOT * HID * 2);
    unsigned short* whi = (unsigned short*)alloc((size_t)HID * HID * 2);     // per-GEMM reuse
    unsigned short* wlo = (unsigned short*)alloc((size_t)HID * HID * 2);
    float* Gt   = (float*)alloc((size_t)BL_TOT * HID * 4);  // gemm out; later Um
    float* Km   = (float*)alloc((size_t)BL_TOT * HID * 4);
    float* Vm   = (float*)alloc((size_t)BL_TOT * HID * 4);  // later Wm (wu is LDS-staged -> alias-safe)
    float* Tg    = (float*)alloc((size_t)128 * 4096 * 4);
    float* betaB = (float*)alloc((size_t)BL_TOT * 4 * 4);
    float* kwB   = (float*)alloc((size_t)8 * 64 * 256 * 4);
    float* kuB   = (float*)alloc((size_t)8 * 64 * 256 * 4);
    float* dsA   = (float*)alloc((size_t)8 * 64 * 256 * 4);
    float* Um = Gt;                           // Gt dead after the last conv
    float* Wm = Vm;                           // Vm dead after wu_kernel's LDS staging
    __hip_bfloat16* Qm = (__hip_bfloat16*)xhi;  // xhi dead after Q GEMM (last GEMM)
    __hip_bfloat16* ob = Qm;                  // q dead after o_kernel reads its own row

    float* out0 = (float*)d_out;                // (B, L, HID) f32
    float* out1 = out0 + (size_t)BL_TOT * HID;  // (B, H, DH, DH) f32

    dim3 blk(256);
    dim3 ggrid(BL_TOT / 128, HID / 128);  // (64, 8)
    const int NTOK = BL_TOT * HID;

    split_kernel<<<4096, blk, 0, stream>>>(x, xhi, xlo, NTOK);
    beta_kernel<<<BL_TOT, blk, 0, stream>>>(x, Wbeta, betaB);

    // V path (split bf16 -> ~f32 fidelity)
    split_kernel<<<1024, blk, 0, stream>>>(Wv, whi, wlo, HID * HID);
    gemm_mfma<1><<<ggrid, blk, 0, stream>>>(xhi, xlo, whi, wlo, Gt, BL_TOT, HID, HID);
    conv_kernel<float><<<BL_TOT, blk, 0, stream>>>(Gt, convv, Vm, 0);
    // K path (split bf16)
    split_kernel<<<1024, blk, 0, stream>>>(Wk, whi, wlo, HID * HID);
    gemm_mfma<1><<<ggrid, blk, 0, stream>>>(xhi, xlo, whi, wlo, Gt, BL_TOT, HID, HID);
    conv_kernel<float><<<BL_TOT, blk, 0, stream>>>(Gt, convk, Km, 1);
    // Q path (plain bf16; q is cast to bf16 downstream anyway). Last GEMM: frees xhi.
    split_kernel<<<1024, blk, 0, stream>>>(Wq, whi, wlo, HID * HID);
    gemm_mfma<0><<<ggrid, blk, 0, stream>>>(xhi, nullptr, whi, nullptr, Gt, BL_TOT, HID, HID);
    conv_kernel<__hip_bfloat16><<<BL_TOT, blk, 0, stream>>>(Gt, convq, Qm, 1);

    // chunked delta rule
    tmat_kernel<<<128, blk, 0, stream>>>(Km, betaB, Tg);
    wu_kernel<<<dim3(128, 4), blk, 0, stream>>>(Tg, Km, Vm, betaB, Wm, Um);
    kwku_kernel<<<dim3(128, 4), blk, 0, stream>>>(Km, Wm, Um, kwB, kuB);
    scan_kernel<<<8, blk, 0, stream>>>(kwB, kuB, dsA);
    o_kernel<<<BL_TOT, blk, 0, stream>>>(Qm, Km, Wm, Um, dsA, rmsw, ob);
    s_kernel<<<dim3(8, 4, 4), blk, 0, stream>>>(Km, Wm, Um, dsA, out1);

    // final projection: o(bf16) @ Wo^T -> f32 out0
    split_kernel<<<1024, blk, 0, stream>>>(Wo, whi, wlo, HID * HID);
    gemm_mfma<0><<<ggrid, blk, 0, stream>>>((const unsigned short*)ob, nullptr, whi, nullptr,
                                            out0, BL_TOT, HID, HID);
}

// Round 5
// 758.003 us; speedup vs baseline: 2.6183x; 1.1548x over previous
//
#include <hip/hip_runtime.h>
#include <hip/hip_bf16.h>

#define L_SEQ 4096
#define HID 1024
#define NH 4
#define DH 256
#define CK 64
#define BL_TOT 8192   // B*L

typedef short v8s __attribute__((ext_vector_type(8)));
typedef unsigned short v8u __attribute__((ext_vector_type(8)));
typedef float v4f __attribute__((ext_vector_type(4)));

__device__ __forceinline__ void storev(float* p, float v) { *p = v; }
__device__ __forceinline__ void storev(__hip_bfloat16* p, float v) { *p = __float2bfloat16(v); }

__device__ __forceinline__ unsigned short f2bu(float f) {
    __hip_bfloat16 h = __float2bfloat16(f);
    return *(unsigned short*)&h;
}
__device__ __forceinline__ float bu2f(unsigned short u) {
    __hip_bfloat16 h = *(__hip_bfloat16*)&u;
    return __bfloat162float(h);
}

// ---------------- f32 -> (bf16 hi, bf16 lo) split ----------------
__global__ __launch_bounds__(256) void split_kernel(const float* __restrict__ in,
                                                    unsigned short* __restrict__ hi,
                                                    unsigned short* __restrict__ lo, int n) {
    int i = blockIdx.x * 256 + threadIdx.x;
    int stride = gridDim.x * 256;
    for (; i < n; i += stride) {
        float v = in[i];
        unsigned short h = f2bu(v);
        hi[i] = h;
        lo[i] = f2bu(v - bu2f(h));
    }
}

// ---------------- f32 -> bf16 (hi only) ----------------
__global__ __launch_bounds__(256) void f2b_kernel(const float* __restrict__ in,
                                                  unsigned short* __restrict__ hi, int n) {
    int i = blockIdx.x * 256 + threadIdx.x;
    int stride = gridDim.x * 256;
    for (; i < n; i += stride) hi[i] = f2bu(in[i]);
}

// ---------------- MFMA bf16 GEMM: C[M,N] = A[M,K] * B[N,K]^T  (f32 out) ----------------
// SPLIT=1: A=Ah+Al, B=Bh+Bl, 3-term (hi*hi + hi*lo + lo*hi) -> ~f32 fidelity.
template <int SPLIT>
__global__ __launch_bounds__(256) void gemm_mfma(const unsigned short* __restrict__ Ah,
                                                 const unsigned short* __restrict__ Al,
                                                 const unsigned short* __restrict__ Bh,
                                                 const unsigned short* __restrict__ Bl,
                                                 float* __restrict__ C, int M, int N, int K) {
    __shared__ unsigned short AsH[128 * 40];
    __shared__ unsigned short BsH[128 * 40];
    __shared__ unsigned short AsL[SPLIT ? 128 * 40 : 8];
    __shared__ unsigned short BsL[SPLIT ? 128 * 40 : 8];
    const int tid = threadIdx.x;
    const int wave = tid >> 6, lane = tid & 63;
    const int quad = lane >> 4, l16 = lane & 15;
    const int m0 = blockIdx.x * 128, n0 = blockIdx.y * 128;
    const int wm = (wave >> 1) * 64, wn = (wave & 1) * 64;
    const int r0 = tid >> 2;        // tile row (0..63); +64 for second issue
    const int kk = (tid & 3) * 8;   // k offset within BK=32 (8 bf16 = 16B)

    v4f acc[4][4];
#pragma unroll
    for (int a = 0; a < 4; ++a)
#pragma unroll
        for (int b = 0; b < 4; ++b) { v4f z = {0.f, 0.f, 0.f, 0.f}; acc[a][b] = z; }

    for (int k0 = 0; k0 < K; k0 += 32) {
        v8u ah0 = *(const v8u*)(Ah + (size_t)(m0 + r0) * K + k0 + kk);
        v8u ah1 = *(const v8u*)(Ah + (size_t)(m0 + r0 + 64) * K + k0 + kk);
        v8u bh0 = *(const v8u*)(Bh + (size_t)(n0 + r0) * K + k0 + kk);
        v8u bh1 = *(const v8u*)(Bh + (size_t)(n0 + r0 + 64) * K + k0 + kk);
        v8u al0, al1, bl0, bl1;
        if (SPLIT) {
            al0 = *(const v8u*)(Al + (size_t)(m0 + r0) * K + k0 + kk);
            al1 = *(const v8u*)(Al + (size_t)(m0 + r0 + 64) * K + k0 + kk);
            bl0 = *(const v8u*)(Bl + (size_t)(n0 + r0) * K + k0 + kk);
            bl1 = *(const v8u*)(Bl + (size_t)(n0 + r0 + 64) * K + k0 + kk);
        }
        __syncthreads();
        *(v8u*)&AsH[r0 * 40 + kk] = ah0;
        *(v8u*)&AsH[(r0 + 64) * 40 + kk] = ah1;
        *(v8u*)&BsH[r0 * 40 + kk] = bh0;
        *(v8u*)&BsH[(r0 + 64) * 40 + kk] = bh1;
        if (SPLIT) {
            *(v8u*)&AsL[r0 * 40 + kk] = al0;
            *(v8u*)&AsL[(r0 + 64) * 40 + kk] = al1;
            *(v8u*)&BsL[r0 * 40 + kk] = bl0;
            *(v8u*)&BsL[(r0 + 64) * 40 + kk] = bl1;
        }
        __syncthreads();
        v8s afh[4], bfh[4], afl[4], bfl[4];
#pragma unroll
        for (int mt = 0; mt < 4; ++mt) afh[mt] = *(const v8s*)&AsH[(wm + mt * 16 + l16) * 40 + quad * 8];
#pragma unroll
        for (int nt = 0; nt < 4; ++nt) bfh[nt] = *(const v8s*)&BsH[(wn + nt * 16 + l16) * 40 + quad * 8];
        if (SPLIT) {
#pragma unroll
            for (int mt = 0; mt < 4; ++mt) afl[mt] = *(const v8s*)&AsL[(wm + mt * 16 + l16) * 40 + quad * 8];
#pragma unroll
            for (int nt = 0; nt < 4; ++nt) bfl[nt] = *(const v8s*)&BsL[(wn + nt * 16 + l16) * 40 + quad * 8];
        }
#pragma unroll
        for (int mt = 0; mt < 4; ++mt)
#pragma unroll
            for (int nt = 0; nt < 4; ++nt) {
                acc[mt][nt] = __builtin_amdgcn_mfma_f32_16x16x32_bf16(afh[mt], bfh[nt], acc[mt][nt], 0, 0, 0);
                if (SPLIT) {
                    acc[mt][nt] = __builtin_amdgcn_mfma_f32_16x16x32_bf16(afh[mt], bfl[nt], acc[mt][nt], 0, 0, 0);
                    acc[mt][nt] = __builtin_amdgcn_mfma_f32_16x16x32_bf16(afl[mt], bfh[nt], acc[mt][nt], 0, 0, 0);
                }
            }
    }
    // C/D layout (m89-verified): col = lane&15, row = (lane>>4)*4 + reg
#pragma unroll
    for (int mt = 0; mt < 4; ++mt)
#pragma unroll
        for (int nt = 0; nt < 4; ++nt) {
            int row = m0 + wm + mt * 16 + quad * 4;
            int col = n0 + wn + nt * 16 + l16;
#pragma unroll
            for (int r = 0; r < 4; ++r)
                C[(size_t)(row + r) * N + col] = acc[mt][nt][r];
        }
}

// ---------------- beta = sigmoid(x @ Wbeta^T) ----------------
__global__ __launch_bounds__(256) void beta_kernel(const float* __restrict__ x,
                                                   const float* __restrict__ Wb,
                                                   float* __restrict__ betaB) {
    const int t = blockIdx.x;  // 0..8191
    const int tid = threadIdx.x;
    const int wave = tid >> 6, lane = tid & 63;
    const float* xr = x + (size_t)t * HID;
    float s[4] = {0.f, 0.f, 0.f, 0.f};
    for (int i = tid; i < HID; i += 256) {
        float xv = xr[i];
        s[0] += xv * Wb[i];
        s[1] += xv * Wb[HID + i];
        s[2] += xv * Wb[2 * HID + i];
        s[3] += xv * Wb[3 * HID + i];
    }
#pragma unroll
    for (int off = 32; off; off >>= 1)
#pragma unroll
        for (int h = 0; h < 4; ++h) s[h] += __shfl_down(s[h], off);
    __shared__ float red[4][4];
    if (lane == 0)
#pragma unroll
        for (int h = 0; h < 4; ++h) red[wave][h] = s[h];
    __syncthreads();
    if (tid < 4) {
        float tot = red[0][tid] + red[1][tid] + red[2][tid] + red[3][tid];
        betaB[(size_t)t * 4 + tid] = 1.f / (1.f + expf(-tot));
    }
}

// ---------------- causal depthwise conv (KS=4) + silu + silu (+ per-head l2norm) ----------------
template <typename OUT>
__global__ __launch_bounds__(256) void conv_kernel(const float* __restrict__ G,
                                                   const float* __restrict__ w,  // [HID][KS]
                                                   OUT* __restrict__ out, int do_norm) {
    const int bl = blockIdx.x;  // b*L + l
    const int l = bl & (L_SEQ - 1);
    const int tid = threadIdx.x;
    const int wave = tid >> 6, lane = tid & 63;
    float vals[4];
#pragma unroll
    for (int h = 0; h < 4; ++h) {
        const int c = tid + 256 * h;
        float acc = 0.f;
#pragma unroll
        for (int j = 0; j < 4; ++j) {
            int ls = l - 3 + j;
            float xv = 0.f;
            if (ls >= 0) xv = G[(size_t)(bl - 3 + j) * HID + c];
            acc += xv * w[c * 4 + j];
        }
        float s1 = acc / (1.f + expf(-acc));
        float s2 = s1 / (1.f + expf(-s1));
        vals[h] = s2;
    }
    if (do_norm) {
        float sq[4];
#pragma unroll
        for (int h = 0; h < 4; ++h) sq[h] = vals[h] * vals[h];
#pragma unroll
        for (int off = 32; off; off >>= 1)
#pragma unroll
            for (int h = 0; h < 4; ++h) sq[h] += __shfl_down(sq[h], off);
        __shared__ float red[4][4];
        __shared__ float nrm[4];
        if (lane == 0)
#pragma unroll
            for (int h = 0; h < 4; ++h) red[wave][h] = sq[h];
        __syncthreads();
        if (tid < 4) {
            float tot = red[0][tid] + red[1][tid] + red[2][tid] + red[3][tid];
            nrm[tid] = 1.f / fmaxf(sqrtf(tot), 1e-12f);
        }
        __syncthreads();
#pragma unroll
        for (int h = 0; h < 4; ++h) vals[h] *= nrm[h];
    }
#pragma unroll
    for (int h = 0; h < 4; ++h) storev(&out[(size_t)bl * HID + tid + 256 * h], vals[h]);
}

// ---------------- T matrix per chunk ----------------
__global__ __launch_bounds__(256) void tmat_kernel(const float* __restrict__ Km,
                                                   const float* __restrict__ betaB,
                                                   float* __restrict__ Tg) {
    const int chunk = blockIdx.x;  // 0..127 = b*64+n
    const size_t l0 = (size_t)chunk * 64;
    const int tid = threadIdx.x;
    const int jj = tid & 63;
    const int iw = tid >> 6;
    __shared__ float Kt[64 * 65];
    __shared__ float Ts[64 * 65];
    __shared__ float betS[256];
    betS[tid] = betaB[(size_t)chunk * 256 + tid];
    float acc[16];
#pragma unroll
    for (int s = 0; s < 16; ++s) acc[s] = 0.f;

    for (int ft = 0; ft < 16; ++ft) {
        __syncthreads();
#pragma unroll
        for (int s = 0; s < 16; ++s) {
            int idx = tid + 256 * s;
            Kt[(idx >> 6) * 65 + (idx & 63)] = Km[(l0 + (idx >> 6)) * HID + ft * 64 + (idx & 63)];
        }
        __syncthreads();
        const int h = ft >> 2;
        float part[16];
#pragma unroll
        for (int s = 0; s < 16; ++s) part[s] = 0.f;
        for (int ff = 0; ff < 64; ++ff) {
            float kj = Kt[jj * 65 + ff];
#pragma unroll
            for (int s = 0; s < 16; ++s) part[s] += Kt[(iw + 4 * s) * 65 + ff] * kj;
        }
#pragma unroll
        for (int s = 0; s < 16; ++s) acc[s] += betS[(iw + 4 * s) * 4 + h] * part[s];
    }
    __syncthreads();
#pragma unroll
    for (int s = 0; s < 16; ++s) {
        int i = iw + 4 * s;
        float v = (i > jj) ? -acc[s] : ((i == jj) ? 1.f : 0.f);
        Ts[i * 65 + jj] = v;
    }
    __syncthreads();
    // serial recurrence: T[i,c<i] = 2*T0[i,c] + sum_{j<i} T0[i,j]*T[j,c]
    for (int i = 1; i < 64; ++i) {
        float v = 0.f;
        if (tid < i) {
            v = 2.f * Ts[i * 65 + tid];
            for (int j = 0; j < i; ++j) v += Ts[i * 65 + j] * Ts[j * 65 + tid];
        }
        __syncthreads();
        if (tid < i) Ts[i * 65 + tid] = v;
        __syncthreads();
    }
#pragma unroll
    for (int s = 0; s < 16; ++s) {
        int idx = tid + 256 * s;
        Tg[(size_t)chunk * 4096 + idx] = Ts[(idx >> 6) * 65 + (idx & 63)];
    }
}

// ---------------- W = T*Kb, U = T*Vb  (LDS-staged: safe for Wm==Vm aliasing) ----------------
__global__ __launch_bounds__(256) void wu_kernel(const float* __restrict__ Tg,
                                                 const float* __restrict__ Km,
                                                 const float* __restrict__ Vm,
                                                 const float* __restrict__ betaB,
                                                 float* __restrict__ Wm, float* __restrict__ Um) {
    const int chunk = blockIdx.x;  // 128
    const int h = blockIdx.y;      // 4
    const size_t l0 = (size_t)chunk * 64;
    const int tid = threadIdx.x;
    const int lane = tid & 63, rgrp = tid >> 6;
    __shared__ float Ts[64 * 65];
    __shared__ float KbS[64 * 65];
    __shared__ float VbS[64 * 65];
    __shared__ float betS[64];
#pragma unroll
    for (int s = 0; s < 16; ++s) {
        int idx = tid + 256 * s;
        Ts[(idx >> 6) * 65 + (idx & 63)] = Tg[(size_t)chunk * 4096 + idx];
    }
    if (tid < 64) betS[tid] = betaB[(l0 + tid) * 4 + h];

    for (int fp = 0; fp < 4; ++fp) {
        const int f0 = h * 256 + fp * 64;
        __syncthreads();  // prev-iter compute done; betS/Ts visible on fp==0
#pragma unroll
        for (int s = 0; s < 16; ++s) {
            int idx = tid + 256 * s;
            int row = idx >> 6, col = idx & 63;
            float bj = betS[row];
            size_t gi = (l0 + row) * HID + f0 + col;
            KbS[row * 65 + col] = Km[gi] * bj;
            VbS[row * 65 + col] = Vm[gi] * bj;
        }
        __syncthreads();
        float accW[16], accU[16];
#pragma unroll
        for (int cc = 0; cc < 16; ++cc) { accW[cc] = 0.f; accU[cc] = 0.f; }
        for (int j = 0; j < 64; ++j) {
            float kb = KbS[j * 65 + lane];
            float vb = VbS[j * 65 + lane];
#pragma unroll
            for (int cc = 0; cc < 16; ++cc) {
                float tv = Ts[(rgrp + 4 * cc) * 65 + j];
                accW[cc] += tv * kb;
                accU[cc] += tv * vb;
            }
        }
#pragma unroll
        for (int cc = 0; cc < 16; ++cc) {
            size_t go = (l0 + rgrp + 4 * cc) * HID + f0 + lane;
            Wm[go] = accW[cc];
            Um[go] = accU[cc];
        }
    }
}

// ---------------- per-chunk diagonal dots ----------------
__global__ __launch_bounds__(256) void kwku_kernel(const float* __restrict__ Km,
                                                   const float* __restrict__ Wm,
                                                   const float* __restrict__ Um,
                                                   float* __restrict__ kw, float* __restrict__ ku) {
    const int chunk = blockIdx.x;  // b*64+n
    const int h = blockIdx.y;
    const int e = threadIdx.x;
    const int b = chunk >> 6, n = chunk & 63;
    size_t base = (size_t)chunk * 64 * HID + h * 256 + e;
    float skw = 0.f, sku = 0.f;
    for (int c = 0; c < 64; ++c) {
        float kv = Km[base + (size_t)c * HID];
        skw += kv * Wm[base + (size_t)c * HID];
        sku += kv * Um[base + (size_t)c * HID];
    }
    size_t o = (((size_t)b * 4 + h) * 64 + n) * 256 + e;
    kw[o] = skw;
    ku[o] = sku;
}

// ---------------- diagonal scan over chunks ----------------
__global__ __launch_bounds__(256) void scan_kernel(const float* __restrict__ kw,
                                                   const float* __restrict__ ku,
                                                   float* __restrict__ dsA) {
    const int bh = blockIdx.x;  // 0..7
    const int e = threadIdx.x;
    float ds = 0.f;
    for (int n = 0; n < 64; ++n) {
        size_t idx = ((size_t)bh * 64 + n) * 256 + e;
        dsA[idx] = ds;
        ds = ds * (1.f - kw[idx]) + ku[idx];
    }
}

__device__ __forceinline__ float block_sum(float v, float* red) {
#pragma unroll
    for (int off = 32; off; off >>= 1) v += __shfl_down(v, off);
    const int wave = threadIdx.x >> 6;
    if ((threadIdx.x & 63) == 0) red[wave] = v;
    __syncthreads();
    float t = red[0] + red[1] + red[2] + red[3];
    __syncthreads();
    return t;
}

// ---------------- o = q*ds + [c<=b]*A*(u - w*ds); fused RMSNorm + bf16 cast ----------------
// ob aliases Qb: each thread reads its own q elements into registers before
// overwriting them -> alias-safe.
__global__ __launch_bounds__(256) void o_kernel(const __hip_bfloat16* __restrict__ Qb,
                                                const float* __restrict__ Km,
                                                const float* __restrict__ Wm,
                                                const float* __restrict__ Um,
                                                const float* __restrict__ dsA,
                                                const float* __restrict__ rmsw,
                                                __hip_bfloat16* __restrict__ ob) {
    const int bl = blockIdx.x;
    const int b = bl >> 12, l = bl & (L_SEQ - 1);
    const int n = l >> 6, cpos = l & 63;
    const int tid = threadIdx.x;
    __shared__ float red[4];
    const size_t rowb = (size_t)bl * HID;
    float dsv[4], qv[4], ov[4];
#pragma unroll
    for (int h = 0; h < 4; ++h) {
        dsv[h] = dsA[(((size_t)b * 4 + h) * 64 + n) * 256 + tid];
        qv[h] = __bfloat162float(Qb[rowb + tid + 256 * h]);
    }
    const bool doA = (cpos <= b);  // tril on the (B=2, C=64) A matrix
    float Aval = 0.f;
    if (doA) {
        float s = 0.f;
#pragma unroll
        for (int h = 0; h < 4; ++h) s += qv[h] * Km[rowb + tid + 256 * h];
        Aval = block_sum(s, red);
    }
    float ss = 0.f;
#pragma unroll
    for (int h = 0; h < 4; ++h) {
        int c = tid + 256 * h;
        float u = Um[rowb + c] - Wm[rowb + c] * dsv[h];
        float o = qv[h] * dsv[h];
        if (doA) o += Aval * u;
        ov[h] = o;
        ss += o * o;
    }
    float tot = block_sum(ss, red);
    float scale = rsqrtf(tot * (1.f / 1024.f) + 1e-5f);
#pragma unroll
    for (int h = 0; h < 4; ++h) {
        int c = tid + 256 * h;
        ob[rowb + c] = __float2bfloat16(ov[h] * scale * rmsw[c]);
    }
}

// ---------------- partial state: Spart[ns] = sum_{n in ns-range} K^T (U - W*ds_n) ----------------
#define NSPLIT 8
__global__ __launch_bounds__(256) void s_kernel(const float* __restrict__ Km,
                                                const float* __restrict__ Wm,
                                                const float* __restrict__ Um,
                                                const float* __restrict__ dsA,
                                                float* __restrict__ Spart) {
    const int bh = blockIdx.x;  // 0..7 = b*4+h
    const int b = bh >> 2, h = bh & 3;
    const int dt = blockIdx.y;            // 0..3
    const int et = blockIdx.z & 3;        // 0..3
    const int ns = blockIdx.z >> 2;       // 0..7
    const int tid = threadIdx.x;
    const int td = tid >> 4, te = tid & 15;
    __shared__ float KtS[64 * 68];
    __shared__ float UtS[64 * 68];
    __shared__ float dse[64];
    float acc[16];
#pragma unroll
    for (int q2 = 0; q2 < 16; ++q2) acc[q2] = 0.f;
    const int nlo = ns * (64 / NSPLIT), nhi = nlo + (64 / NSPLIT);
    for (int n = nlo; n < nhi; ++n) {
        const size_t l0 = ((size_t)b * 64 + n) * 64;
        __syncthreads();
        if (tid < 64) dse[tid] = dsA[((size_t)bh * 64 + n) * 256 + et * 64 + tid];
        __syncthreads();
#pragma unroll
        for (int s = 0; s < 16; ++s) {
            int idx = tid + 256 * s;
            int c = idx >> 6, qq = idx & 63;
            size_t gK = (l0 + c) * HID + h * 256 + dt * 64 + qq;
            size_t gU = (l0 + c) * HID + h * 256 + et * 64 + qq;
            KtS[c * 68 + qq] = Km[gK];
            UtS[c * 68 + qq] = Um[gU] - Wm[gU] * dse[qq];
        }
        __syncthreads();
        for (int c = 0; c < 64; ++c) {
            float4 kd = *(const float4*)&KtS[c * 68 + td * 4];
            float4 ue = *(const float4*)&UtS[c * 68 + te * 4];
            acc[0] += kd.x * ue.x;   acc[1] += kd.x * ue.y;   acc[2] += kd.x * ue.z;   acc[3] += kd.x * ue.w;
            acc[4] += kd.y * ue.x;   acc[5] += kd.y * ue.y;   acc[6] += kd.y * ue.z;   acc[7] += kd.y * ue.w;
            acc[8] += kd.z * ue.x;   acc[9] += kd.z * ue.y;   acc[10] += kd.z * ue.z;  acc[11] += kd.z * ue.w;
            acc[12] += kd.w * ue.x;  acc[13] += kd.w * ue.y;  acc[14] += kd.w * ue.z;  acc[15] += kd.w * ue.w;
        }
    }
    float* out = Spart + (size_t)ns * (8 * 256 * 256);
#pragma unroll
    for (int i = 0; i < 4; ++i)
#pragma unroll
        for (int j = 0; j < 4; ++j)
            out[((size_t)bh * 256 + dt * 64 + td * 4 + i) * 256 + et * 64 + te * 4 + j] = acc[i * 4 + j];
}

// ---------------- reduce NSPLIT partials -> out1 ----------------
__global__ __launch_bounds__(256) void sreduce_kernel(const float* __restrict__ Spart,
                                                      float* __restrict__ out) {
    int i = blockIdx.x * 256 + threadIdx.x;  // 8*256*256 = 524288 total
    float s = 0.f;
#pragma unroll
    for (int ns = 0; ns < NSPLIT; ++ns) s += Spart[(size_t)ns * (8 * 256 * 256) + i];
    out[i] = s;
}

extern "C" void kernel_launch(void* const* d_in, const int* in_sizes, int n_in,
                              void* d_out, int out_size, void* d_ws, size_t ws_size,
                              hipStream_t stream) {
    const float* x     = (const float*)d_in[0];
    const float* Wq    = (const float*)d_in[1];
    const float* Wk    = (const float*)d_in[2];
    const float* Wv    = (const float*)d_in[3];
    const float* convq = (const float*)d_in[4];
    const float* convk = (const float*)d_in[5];
    const float* convv = (const float*)d_in[6];
    const float* Wbeta = (const float*)d_in[7];
    const float* rmsw  = (const float*)d_in[8];
    const float* Wo    = (const float*)d_in[9];

    // ---- workspace map (~136 MiB; aliases documented) ----
    char* ws = (char*)d_ws;
    size_t off = 0;
    auto alloc = [&](size_t bytes) {
        char* p = ws + off;
        off += (bytes + 255) & ~(size_t)255;
        return (void*)p;
    };
    unsigned short* xhi = (unsigned short*)alloc((size_t)BL_TOT * HID * 2);  // later Qm/ob
    unsigned short* xlo = (unsigned short*)alloc((size_t)BL_TOT * HID * 2);  // later Spart (16.78 MB)
    unsigned short* whi = (unsigned short*)alloc((size_t)HID * HID * 2);     // per-GEMM reuse
    unsigned short* wlo = (unsigned short*)alloc((size_t)HID * HID * 2);
    float* Gt   = (float*)alloc((size_t)BL_TOT * HID * 4);  // gemm out; later Um
    float* Km   = (float*)alloc((size_t)BL_TOT * HID * 4);
    float* Vm   = (float*)alloc((size_t)BL_TOT * HID * 4);  // later Wm (wu is LDS-staged -> alias-safe)
    float* Tg    = (float*)alloc((size_t)128 * 4096 * 4);
    float* betaB = (float*)alloc((size_t)BL_TOT * 4 * 4);
    float* kwB   = (float*)alloc((size_t)8 * 64 * 256 * 4);
    float* kuB   = (float*)alloc((size_t)8 * 64 * 256 * 4);
    float* dsA   = (float*)alloc((size_t)8 * 64 * 256 * 4);
    float* Um = Gt;                             // Gt dead after the last conv
    float* Wm = Vm;                             // Vm dead after wu_kernel's LDS staging
    __hip_bfloat16* Qm = (__hip_bfloat16*)xhi;  // xhi dead after Q GEMM (last GEMM)
    __hip_bfloat16* ob = Qm;                    // q dead after o_kernel reads its own row
    float* Spart = (float*)xlo;                 // xlo dead after K GEMM; NSPLIT*8*256*256*4 = 16.78 MB exactly

    float* out0 = (float*)d_out;                // (B, L, HID) f32
    float* out1 = out0 + (size_t)BL_TOT * HID;  // (B, H, DH, DH) f32

    dim3 blk(256);
    dim3 ggrid(BL_TOT / 128, HID / 128);  // (64, 8)
    const int NTOK = BL_TOT * HID;

    split_kernel<<<4096, blk, 0, stream>>>(x, xhi, xlo, NTOK);
    beta_kernel<<<BL_TOT, blk, 0, stream>>>(x, Wbeta, betaB);

    // V path (plain bf16: V propagates linearly -> ~0.2% rel, safe)
    f2b_kernel<<<1024, blk, 0, stream>>>(Wv, whi, HID * HID);
    gemm_mfma<0><<<ggrid, blk, 0, stream>>>(xhi, nullptr, whi, nullptr, Gt, BL_TOT, HID, HID);
    conv_kernel<float><<<BL_TOT, blk, 0, stream>>>(Gt, convv, Vm, 0);
    // K path (split bf16 -> ~f32 fidelity; feeds triangular recurrence). Last user of xlo/wlo.
    split_kernel<<<1024, blk, 0, stream>>>(Wk, whi, wlo, HID * HID);
    gemm_mfma<1><<<ggrid, blk, 0, stream>>>(xhi, xlo, whi, wlo, Gt, BL_TOT, HID, HID);
    conv_kernel<float><<<BL_TOT, blk, 0, stream>>>(Gt, convk, Km, 1);
    // Q path (plain bf16; q is cast to bf16 downstream anyway). Last GEMM: frees xhi.
    f2b_kernel<<<1024, blk, 0, stream>>>(Wq, whi, HID * HID);
    gemm_mfma<0><<<ggrid, blk, 0, stream>>>(xhi, nullptr, whi, nullptr, Gt, BL_TOT, HID, HID);
    conv_kernel<__hip_bfloat16><<<BL_TOT, blk, 0, stream>>>(Gt, convq, Qm, 1);

    // chunked delta rule
    tmat_kernel<<<128, blk, 0, stream>>>(Km, betaB, Tg);
    wu_kernel<<<dim3(128, 4), blk, 0, stream>>>(Tg, Km, Vm, betaB, Wm, Um);
    kwku_kernel<<<dim3(128, 4), blk, 0, stream>>>(Km, Wm, Um, kwB, kuB);
    scan_kernel<<<8, blk, 0, stream>>>(kwB, kuB, dsA);
    o_kernel<<<BL_TOT, blk, 0, stream>>>(Qm, Km, Wm, Um, dsA, rmsw, ob);
    s_kernel<<<dim3(8, 4, 4 * NSPLIT), blk, 0, stream>>>(Km, Wm, Um, dsA, Spart);
    sreduce_kernel<<<2048, blk, 0, stream>>>(Spart, out1);

    // final projection: o(bf16) @ Wo^T -> f32 out0
    f2b_kernel<<<1024, blk, 0, stream>>>(Wo, whi, HID * HID);
    gemm_mfma<0><<<ggrid, blk, 0, stream>>>((const unsigned short*)ob, nullptr, whi, nullptr,
                                            out0, BL_TOT, HID, HID);
}

// Round 6
// 582.364 us; speedup vs baseline: 3.4080x; 1.3016x over previous
//
#include <hip/hip_runtime.h>
#include <hip/hip_bf16.h>

#define L_SEQ 4096
#define HID 1024
#define NH 4
#define DH 256
#define CK 64
#define BL_TOT 8192   // B*L

typedef short v8s __attribute__((ext_vector_type(8)));
typedef unsigned short v8u __attribute__((ext_vector_type(8)));
typedef float v4f __attribute__((ext_vector_type(4)));

__device__ __forceinline__ void storev(float* p, float v) { *p = v; }
__device__ __forceinline__ void storev(__hip_bfloat16* p, float v) { *p = __float2bfloat16(v); }

__device__ __forceinline__ unsigned short f2bu(float f) {
    __hip_bfloat16 h = __float2bfloat16(f);
    return *(unsigned short*)&h;
}
__device__ __forceinline__ float bu2f(unsigned short u) {
    __hip_bfloat16 h = *(__hip_bfloat16*)&u;
    return __bfloat162float(h);
}

// ---------------- f32 -> (bf16 hi, bf16 lo) split ----------------
__global__ __launch_bounds__(256) void split_kernel(const float* __restrict__ in,
                                                    unsigned short* __restrict__ hi,
                                                    unsigned short* __restrict__ lo, int n) {
    int i = blockIdx.x * 256 + threadIdx.x;
    int stride = gridDim.x * 256;
    for (; i < n; i += stride) {
        float v = in[i];
        unsigned short h = f2bu(v);
        hi[i] = h;
        lo[i] = f2bu(v - bu2f(h));
    }
}

// ---------------- f32 -> bf16 (hi only) ----------------
__global__ __launch_bounds__(256) void f2b_kernel(const float* __restrict__ in,
                                                  unsigned short* __restrict__ hi, int n) {
    int i = blockIdx.x * 256 + threadIdx.x;
    int stride = gridDim.x * 256;
    for (; i < n; i += stride) hi[i] = f2bu(in[i]);
}

// ---------------- MFMA bf16 GEMM: C[M,N] = A[M,K] * B[N,K]^T  (f32 out) ----------------
// SPLIT=1: A=Ah+Al, B=Bh+Bl, 3-term (hi*hi + hi*lo + lo*hi) -> ~f32 fidelity.
template <int SPLIT>
__global__ __launch_bounds__(256) void gemm_mfma(const unsigned short* __restrict__ Ah,
                                                 const unsigned short* __restrict__ Al,
                                                 const unsigned short* __restrict__ Bh,
                                                 const unsigned short* __restrict__ Bl,
                                                 float* __restrict__ C, int M, int N, int K) {
    __shared__ unsigned short AsH[128 * 40];
    __shared__ unsigned short BsH[128 * 40];
    __shared__ unsigned short AsL[SPLIT ? 128 * 40 : 8];
    __shared__ unsigned short BsL[SPLIT ? 128 * 40 : 8];
    const int tid = threadIdx.x;
    const int wave = tid >> 6, lane = tid & 63;
    const int quad = lane >> 4, l16 = lane & 15;
    const int m0 = blockIdx.x * 128, n0 = blockIdx.y * 128;
    const int wm = (wave >> 1) * 64, wn = (wave & 1) * 64;
    const int r0 = tid >> 2;        // tile row (0..63); +64 for second issue
    const int kk = (tid & 3) * 8;   // k offset within BK=32 (8 bf16 = 16B)

    v4f acc[4][4];
#pragma unroll
    for (int a = 0; a < 4; ++a)
#pragma unroll
        for (int b = 0; b < 4; ++b) { v4f z = {0.f, 0.f, 0.f, 0.f}; acc[a][b] = z; }

    for (int k0 = 0; k0 < K; k0 += 32) {
        v8u ah0 = *(const v8u*)(Ah + (size_t)(m0 + r0) * K + k0 + kk);
        v8u ah1 = *(const v8u*)(Ah + (size_t)(m0 + r0 + 64) * K + k0 + kk);
        v8u bh0 = *(const v8u*)(Bh + (size_t)(n0 + r0) * K + k0 + kk);
        v8u bh1 = *(const v8u*)(Bh + (size_t)(n0 + r0 + 64) * K + k0 + kk);
        v8u al0, al1, bl0, bl1;
        if (SPLIT) {
            al0 = *(const v8u*)(Al + (size_t)(m0 + r0) * K + k0 + kk);
            al1 = *(const v8u*)(Al + (size_t)(m0 + r0 + 64) * K + k0 + kk);
            bl0 = *(const v8u*)(Bl + (size_t)(n0 + r0) * K + k0 + kk);
            bl1 = *(const v8u*)(Bl + (size_t)(n0 + r0 + 64) * K + k0 + kk);
        }
        __syncthreads();
        *(v8u*)&AsH[r0 * 40 + kk] = ah0;
        *(v8u*)&AsH[(r0 + 64) * 40 + kk] = ah1;
        *(v8u*)&BsH[r0 * 40 + kk] = bh0;
        *(v8u*)&BsH[(r0 + 64) * 40 + kk] = bh1;
        if (SPLIT) {
            *(v8u*)&AsL[r0 * 40 + kk] = al0;
            *(v8u*)&AsL[(r0 + 64) * 40 + kk] = al1;
            *(v8u*)&BsL[r0 * 40 + kk] = bl0;
            *(v8u*)&BsL[(r0 + 64) * 40 + kk] = bl1;
        }
        __syncthreads();
        v8s afh[4], bfh[4], afl[4], bfl[4];
#pragma unroll
        for (int mt = 0; mt < 4; ++mt) afh[mt] = *(const v8s*)&AsH[(wm + mt * 16 + l16) * 40 + quad * 8];
#pragma unroll
        for (int nt = 0; nt < 4; ++nt) bfh[nt] = *(const v8s*)&BsH[(wn + nt * 16 + l16) * 40 + quad * 8];
        if (SPLIT) {
#pragma unroll
            for (int mt = 0; mt < 4; ++mt) afl[mt] = *(const v8s*)&AsL[(wm + mt * 16 + l16) * 40 + quad * 8];
#pragma unroll
            for (int nt = 0; nt < 4; ++nt) bfl[nt] = *(const v8s*)&BsL[(wn + nt * 16 + l16) * 40 + quad * 8];
        }
#pragma unroll
        for (int mt = 0; mt < 4; ++mt)
#pragma unroll
            for (int nt = 0; nt < 4; ++nt) {
                acc[mt][nt] = __builtin_amdgcn_mfma_f32_16x16x32_bf16(afh[mt], bfh[nt], acc[mt][nt], 0, 0, 0);
                if (SPLIT) {
                    acc[mt][nt] = __builtin_amdgcn_mfma_f32_16x16x32_bf16(afh[mt], bfl[nt], acc[mt][nt], 0, 0, 0);
                    acc[mt][nt] = __builtin_amdgcn_mfma_f32_16x16x32_bf16(afl[mt], bfh[nt], acc[mt][nt], 0, 0, 0);
                }
            }
    }
    // C/D layout (m89-verified): col = lane&15, row = (lane>>4)*4 + reg
#pragma unroll
    for (int mt = 0; mt < 4; ++mt)
#pragma unroll
        for (int nt = 0; nt < 4; ++nt) {
            int row = m0 + wm + mt * 16 + quad * 4;
            int col = n0 + wn + nt * 16 + l16;
#pragma unroll
            for (int r = 0; r < 4; ++r)
                C[(size_t)(row + r) * N + col] = acc[mt][nt][r];
        }
}

// ---------------- beta = sigmoid(x @ Wbeta^T) ----------------
__global__ __launch_bounds__(256) void beta_kernel(const float* __restrict__ x,
                                                   const float* __restrict__ Wb,
                                                   float* __restrict__ betaB) {
    const int t = blockIdx.x;  // 0..8191
    const int tid = threadIdx.x;
    const int wave = tid >> 6, lane = tid & 63;
    const float* xr = x + (size_t)t * HID;
    float s[4] = {0.f, 0.f, 0.f, 0.f};
    for (int i = tid; i < HID; i += 256) {
        float xv = xr[i];
        s[0] += xv * Wb[i];
        s[1] += xv * Wb[HID + i];
        s[2] += xv * Wb[2 * HID + i];
        s[3] += xv * Wb[3 * HID + i];
    }
#pragma unroll
    for (int off = 32; off; off >>= 1)
#pragma unroll
        for (int h = 0; h < 4; ++h) s[h] += __shfl_down(s[h], off);
    __shared__ float red[4][4];
    if (lane == 0)
#pragma unroll
        for (int h = 0; h < 4; ++h) red[wave][h] = s[h];
    __syncthreads();
    if (tid < 4) {
        float tot = red[0][tid] + red[1][tid] + red[2][tid] + red[3][tid];
        betaB[(size_t)t * 4 + tid] = 1.f / (1.f + expf(-tot));
    }
}

// ---------------- causal depthwise conv (KS=4) + silu + silu (+ per-head l2norm) ----------------
// Optionally also emits bf16 hi/lo of the result (K path -> gram MFMA inputs).
template <typename OUT>
__global__ __launch_bounds__(256) void conv_kernel(const float* __restrict__ G,
                                                   const float* __restrict__ w,  // [HID][KS]
                                                   OUT* __restrict__ out, int do_norm,
                                                   unsigned short* __restrict__ hi,
                                                   unsigned short* __restrict__ lo) {
    const int bl = blockIdx.x;  // b*L + l
    const int l = bl & (L_SEQ - 1);
    const int tid = threadIdx.x;
    const int wave = tid >> 6, lane = tid & 63;
    float vals[4];
#pragma unroll
    for (int h = 0; h < 4; ++h) {
        const int c = tid + 256 * h;
        float acc = 0.f;
#pragma unroll
        for (int j = 0; j < 4; ++j) {
            int ls = l - 3 + j;
            float xv = 0.f;
            if (ls >= 0) xv = G[(size_t)(bl - 3 + j) * HID + c];
            acc += xv * w[c * 4 + j];
        }
        float s1 = acc / (1.f + expf(-acc));
        float s2 = s1 / (1.f + expf(-s1));
        vals[h] = s2;
    }
    if (do_norm) {
        float sq[4];
#pragma unroll
        for (int h = 0; h < 4; ++h) sq[h] = vals[h] * vals[h];
#pragma unroll
        for (int off = 32; off; off >>= 1)
#pragma unroll
            for (int h = 0; h < 4; ++h) sq[h] += __shfl_down(sq[h], off);
        __shared__ float red[4][4];
        __shared__ float nrm[4];
        if (lane == 0)
#pragma unroll
            for (int h = 0; h < 4; ++h) red[wave][h] = sq[h];
        __syncthreads();
        if (tid < 4) {
            float tot = red[0][tid] + red[1][tid] + red[2][tid] + red[3][tid];
            nrm[tid] = 1.f / fmaxf(sqrtf(tot), 1e-12f);
        }
        __syncthreads();
#pragma unroll
        for (int h = 0; h < 4; ++h) vals[h] *= nrm[h];
    }
#pragma unroll
    for (int h = 0; h < 4; ++h) {
        const int c = tid + 256 * h;
        storev(&out[(size_t)bl * HID + c], vals[h]);
        if (hi) {
            unsigned short hv = f2bu(vals[h]);
            hi[(size_t)bl * HID + c] = hv;
            lo[(size_t)bl * HID + c] = f2bu(vals[h] - bu2f(hv));
        }
    }
}

// ---------------- per-chunk per-head gram: G_h = K_h * K_h^T (split-bf16 MFMA) ----------------
__global__ __launch_bounds__(256) void gram_kernel(const unsigned short* __restrict__ Khi,
                                                   const unsigned short* __restrict__ Klo,
                                                   float* __restrict__ Gg) {
    const int chunk = blockIdx.x;  // 0..127
    const int h = blockIdx.y;      // 0..3
    const int tid = threadIdx.x;
    const int wave = tid >> 6, lane = tid & 63;
    const int quad = lane >> 4, l16 = lane & 15;
    __shared__ unsigned short Hs[64 * 264];
    __shared__ unsigned short Ls[64 * 264];
    const int l0 = chunk * 64;
    const int cb = h * 256;
#pragma unroll
    for (int p = 0; p < 8; ++p) {
        int row = p * 8 + (tid >> 5);
        int col = (tid & 31) * 8;
        v8u hv = *(const v8u*)(Khi + (size_t)(l0 + row) * HID + cb + col);
        v8u lv = *(const v8u*)(Klo + (size_t)(l0 + row) * HID + cb + col);
        *(v8u*)&Hs[row * 264 + col] = hv;
        *(v8u*)&Ls[row * 264 + col] = lv;
    }
    __syncthreads();
    const int wm = wave * 16;  // row band of this wave
    v4f acc[4];
#pragma unroll
    for (int nt = 0; nt < 4; ++nt) { v4f z = {0.f, 0.f, 0.f, 0.f}; acc[nt] = z; }
#pragma unroll
    for (int ks = 0; ks < 8; ++ks) {
        v8s ah = *(const v8s*)&Hs[(wm + l16) * 264 + ks * 32 + quad * 8];
        v8s al = *(const v8s*)&Ls[(wm + l16) * 264 + ks * 32 + quad * 8];
#pragma unroll
        for (int nt = 0; nt < 4; ++nt) {
            v8s bh = *(const v8s*)&Hs[(nt * 16 + l16) * 264 + ks * 32 + quad * 8];
            v8s bl = *(const v8s*)&Ls[(nt * 16 + l16) * 264 + ks * 32 + quad * 8];
            acc[nt] = __builtin_amdgcn_mfma_f32_16x16x32_bf16(ah, bh, acc[nt], 0, 0, 0);
            acc[nt] = __builtin_amdgcn_mfma_f32_16x16x32_bf16(ah, bl, acc[nt], 0, 0, 0);
            acc[nt] = __builtin_amdgcn_mfma_f32_16x16x32_bf16(al, bh, acc[nt], 0, 0, 0);
        }
    }
    float* og = Gg + ((size_t)chunk * 4 + h) * 4096;
#pragma unroll
    for (int nt = 0; nt < 4; ++nt)
#pragma unroll
        for (int r = 0; r < 4; ++r)
            og[(wm + quad * 4 + r) * 64 + nt * 16 + l16] = acc[nt][r];
}

// ---------------- T recurrence per chunk (gram precomputed) ----------------
__global__ __launch_bounds__(256) void trec_kernel(const float* __restrict__ Gg,
                                                   const float* __restrict__ betaB,
                                                   float* __restrict__ Tg) {
    const int chunk = blockIdx.x;  // 0..127
    const int tid = threadIdx.x;
    __shared__ float Ts[64 * 65];
    __shared__ float betS[256];
    betS[tid] = betaB[(size_t)chunk * 256 + tid];
    __syncthreads();
    const float* gg = Gg + (size_t)chunk * 4 * 4096;
#pragma unroll
    for (int s = 0; s < 16; ++s) {
        int idx = tid + 256 * s;
        int i = idx >> 6, j = idx & 63;
        float v;
        if (i > j) {
            float t = betS[i * 4 + 0] * gg[idx] + betS[i * 4 + 1] * gg[4096 + idx] +
                      betS[i * 4 + 2] * gg[2 * 4096 + idx] + betS[i * 4 + 3] * gg[3 * 4096 + idx];
            v = -t;
        } else {
            v = (i == j) ? 1.f : 0.f;
        }
        Ts[i * 65 + j] = v;
    }
    __syncthreads();
    // serial recurrence: T[i,c<i] = 2*T0[i,c] + sum_{j<i} T0[i,j]*T[j,c]
    for (int i = 1; i < 64; ++i) {
        float v = 0.f;
        if (tid < i) {
            v = 2.f * Ts[i * 65 + tid];
            for (int j = 0; j < i; ++j) v += Ts[i * 65 + j] * Ts[j * 65 + tid];
        }
        __syncthreads();
        if (tid < i) Ts[i * 65 + tid] = v;
        __syncthreads();
    }
#pragma unroll
    for (int s = 0; s < 16; ++s) {
        int idx = tid + 256 * s;
        Tg[(size_t)chunk * 4096 + idx] = Ts[(idx >> 6) * 65 + (idx & 63)];
    }
}

// ---------------- W = T*Kb, U = T*Vb  (LDS-staged: safe for Wm==Vm aliasing) ----------------
__global__ __launch_bounds__(256) void wu_kernel(const float* __restrict__ Tg,
                                                 const float* __restrict__ Km,
                                                 const float* __restrict__ Vm,
                                                 const float* __restrict__ betaB,
                                                 float* __restrict__ Wm, float* __restrict__ Um) {
    const int chunk = blockIdx.x;  // 128
    const int h = blockIdx.y;      // 4
    const size_t l0 = (size_t)chunk * 64;
    const int tid = threadIdx.x;
    const int lane = tid & 63, rgrp = tid >> 6;
    __shared__ float Ts[64 * 65];
    __shared__ float KbS[64 * 65];
    __shared__ float VbS[64 * 65];
    __shared__ float betS[64];
#pragma unroll
    for (int s = 0; s < 16; ++s) {
        int idx = tid + 256 * s;
        Ts[(idx >> 6) * 65 + (idx & 63)] = Tg[(size_t)chunk * 4096 + idx];
    }
    if (tid < 64) betS[tid] = betaB[(l0 + tid) * 4 + h];

    for (int fp = 0; fp < 4; ++fp) {
        const int f0 = h * 256 + fp * 64;
        __syncthreads();  // prev-iter compute done; betS/Ts visible on fp==0
#pragma unroll
        for (int s = 0; s < 16; ++s) {
            int idx = tid + 256 * s;
            int row = idx >> 6, col = idx & 63;
            float bj = betS[row];
            size_t gi = (l0 + row) * HID + f0 + col;
            KbS[row * 65 + col] = Km[gi] * bj;
            VbS[row * 65 + col] = Vm[gi] * bj;
        }
        __syncthreads();
        float accW[16], accU[16];
#pragma unroll
        for (int cc = 0; cc < 16; ++cc) { accW[cc] = 0.f; accU[cc] = 0.f; }
        for (int j = 0; j < 64; ++j) {
            float kb = KbS[j * 65 + lane];
            float vb = VbS[j * 65 + lane];
#pragma unroll
            for (int cc = 0; cc < 16; ++cc) {
                float tv = Ts[(rgrp + 4 * cc) * 65 + j];
                accW[cc] += tv * kb;
                accU[cc] += tv * vb;
            }
        }
#pragma unroll
        for (int cc = 0; cc < 16; ++cc) {
            size_t go = (l0 + rgrp + 4 * cc) * HID + f0 + lane;
            Wm[go] = accW[cc];
            Um[go] = accU[cc];
        }
    }
}

// ---------------- per-chunk diagonal dots ----------------
__global__ __launch_bounds__(256) void kwku_kernel(const float* __restrict__ Km,
                                                   const float* __restrict__ Wm,
                                                   const float* __restrict__ Um,
                                                   float* __restrict__ kw, float* __restrict__ ku) {
    const int chunk = blockIdx.x;  // b*64+n
    const int h = blockIdx.y;
    const int e = threadIdx.x;
    const int b = chunk >> 6, n = chunk & 63;
    size_t base = (size_t)chunk * 64 * HID + h * 256 + e;
    float skw = 0.f, sku = 0.f;
    for (int c = 0; c < 64; ++c) {
        float kv = Km[base + (size_t)c * HID];
        skw += kv * Wm[base + (size_t)c * HID];
        sku += kv * Um[base + (size_t)c * HID];
    }
    size_t o = (((size_t)b * 4 + h) * 64 + n) * 256 + e;
    kw[o] = skw;
    ku[o] = sku;
}

// ---------------- diagonal scan over chunks ----------------
__global__ __launch_bounds__(256) void scan_kernel(const float* __restrict__ kw,
                                                   const float* __restrict__ ku,
                                                   float* __restrict__ dsA) {
    const int bh = blockIdx.x;  // 0..7
    const int e = threadIdx.x;
    float ds = 0.f;
    for (int n = 0; n < 64; ++n) {
        size_t idx = ((size_t)bh * 64 + n) * 256 + e;
        dsA[idx] = ds;
        ds = ds * (1.f - kw[idx]) + ku[idx];
    }
}

__device__ __forceinline__ float block_sum(float v, float* red) {
#pragma unroll
    for (int off = 32; off; off >>= 1) v += __shfl_down(v, off);
    const int wave = threadIdx.x >> 6;
    if ((threadIdx.x & 63) == 0) red[wave] = v;
    __syncthreads();
    float t = red[0] + red[1] + red[2] + red[3];
    __syncthreads();
    return t;
}

// ---------------- o = q*ds + [c<=b]*A*(u - w*ds); fused RMSNorm + bf16 cast ----------------
// ob aliases Qb: each thread reads its own q elements into registers before
// overwriting them -> alias-safe.
__global__ __launch_bounds__(256) void o_kernel(const __hip_bfloat16* __restrict__ Qb,
                                                const float* __restrict__ Km,
                                                const float* __restrict__ Wm,
                                                const float* __restrict__ Um,
                                                const float* __restrict__ dsA,
                                                const float* __restrict__ rmsw,
                                                __hip_bfloat16* __restrict__ ob) {
    const int bl = blockIdx.x;
    const int b = bl >> 12, l = bl & (L_SEQ - 1);
    const int n = l >> 6, cpos = l & 63;
    const int tid = threadIdx.x;
    __shared__ float red[4];
    const size_t rowb = (size_t)bl * HID;
    float dsv[4], qv[4], ov[4];
#pragma unroll
    for (int h = 0; h < 4; ++h) {
        dsv[h] = dsA[(((size_t)b * 4 + h) * 64 + n) * 256 + tid];
        qv[h] = __bfloat162float(Qb[rowb + tid + 256 * h]);
    }
    const bool doA = (cpos <= b);  // tril on the (B=2, C=64) A matrix
    float Aval = 0.f;
    if (doA) {
        float s = 0.f;
#pragma unroll
        for (int h = 0; h < 4; ++h) s += qv[h] * Km[rowb + tid + 256 * h];
        Aval = block_sum(s, red);
    }
    float ss = 0.f;
#pragma unroll
    for (int h = 0; h < 4; ++h) {
        int c = tid + 256 * h;
        float u = Um[rowb + c] - Wm[rowb + c] * dsv[h];
        float o = qv[h] * dsv[h];
        if (doA) o += Aval * u;
        ov[h] = o;
        ss += o * o;
    }
    float tot = block_sum(ss, red);
    float scale = rsqrtf(tot * (1.f / 1024.f) + 1e-5f);
#pragma unroll
    for (int h = 0; h < 4; ++h) {
        int c = tid + 256 * h;
        ob[rowb + c] = __float2bfloat16(ov[h] * scale * rmsw[c]);
    }
}

// ---------------- partial state: Spart[ns] = sum_{n in ns-range} K^T (U - W*ds_n) ----------------
#define NSPLIT 8
__global__ __launch_bounds__(256) void s_kernel(const float* __restrict__ Km,
                                                const float* __restrict__ Wm,
                                                const float* __restrict__ Um,
                                                const float* __restrict__ dsA,
                                                float* __restrict__ Spart) {
    const int bh = blockIdx.x;  // 0..7 = b*4+h
    const int b = bh >> 2, h = bh & 3;
    const int dt = blockIdx.y;            // 0..3
    const int et = blockIdx.z & 3;        // 0..3
    const int ns = blockIdx.z >> 2;       // 0..7
    const int tid = threadIdx.x;
    const int td = tid >> 4, te = tid & 15;
    __shared__ float KtS[64 * 68];
    __shared__ float UtS[64 * 68];
    __shared__ float dse[64];
    float acc[16];
#pragma unroll
    for (int q2 = 0; q2 < 16; ++q2) acc[q2] = 0.f;
    const int nlo = ns * (64 / NSPLIT), nhi = nlo + (64 / NSPLIT);
    for (int n = nlo; n < nhi; ++n) {
        const size_t l0 = ((size_t)b * 64 + n) * 64;
        __syncthreads();
        if (tid < 64) dse[tid] = dsA[((size_t)bh * 64 + n) * 256 + et * 64 + tid];
        __syncthreads();
#pragma unroll
        for (int s = 0; s < 16; ++s) {
            int idx = tid + 256 * s;
            int c = idx >> 6, qq = idx & 63;
            size_t gK = (l0 + c) * HID + h * 256 + dt * 64 + qq;
            size_t gU = (l0 + c) * HID + h * 256 + et * 64 + qq;
            KtS[c * 68 + qq] = Km[gK];
            UtS[c * 68 + qq] = Um[gU] - Wm[gU] * dse[qq];
        }
        __syncthreads();
        for (int c = 0; c < 64; ++c) {
            float4 kd = *(const float4*)&KtS[c * 68 + td * 4];
            float4 ue = *(const float4*)&UtS[c * 68 + te * 4];
            acc[0] += kd.x * ue.x;   acc[1] += kd.x * ue.y;   acc[2] += kd.x * ue.z;   acc[3] += kd.x * ue.w;
            acc[4] += kd.y * ue.x;   acc[5] += kd.y * ue.y;   acc[6] += kd.y * ue.z;   acc[7] += kd.y * ue.w;
            acc[8] += kd.z * ue.x;   acc[9] += kd.z * ue.y;   acc[10] += kd.z * ue.z;  acc[11] += kd.z * ue.w;
            acc[12] += kd.w * ue.x;  acc[13] += kd.w * ue.y;  acc[14] += kd.w * ue.z;  acc[15] += kd.w * ue.w;
        }
    }
    float* out = Spart + (size_t)ns * (8 * 256 * 256);
#pragma unroll
    for (int i = 0; i < 4; ++i)
#pragma unroll
        for (int j = 0; j < 4; ++j)
            out[((size_t)bh * 256 + dt * 64 + td * 4 + i) * 256 + et * 64 + te * 4 + j] = acc[i * 4 + j];
}

// ---------------- reduce NSPLIT partials -> out1 ----------------
__global__ __launch_bounds__(256) void sreduce_kernel(const float* __restrict__ Spart,
                                                      float* __restrict__ out) {
    int i = blockIdx.x * 256 + threadIdx.x;  // 8*256*256 = 524288 total
    float s = 0.f;
#pragma unroll
    for (int ns = 0; ns < NSPLIT; ++ns) s += Spart[(size_t)ns * (8 * 256 * 256) + i];
    out[i] = s;
}

extern "C" void kernel_launch(void* const* d_in, const int* in_sizes, int n_in,
                              void* d_out, int out_size, void* d_ws, size_t ws_size,
                              hipStream_t stream) {
    const float* x     = (const float*)d_in[0];
    const float* Wq    = (const float*)d_in[1];
    const float* Wk    = (const float*)d_in[2];
    const float* Wv    = (const float*)d_in[3];
    const float* convq = (const float*)d_in[4];
    const float* convk = (const float*)d_in[5];
    const float* convv = (const float*)d_in[6];
    const float* Wbeta = (const float*)d_in[7];
    const float* rmsw  = (const float*)d_in[8];
    const float* Wo    = (const float*)d_in[9];

    // ---- workspace map (~136 MiB; aliases documented) ----
    char* ws = (char*)d_ws;
    size_t off = 0;
    auto alloc = [&](size_t bytes) {
        char* p = ws + off;
        off += (bytes + 255) & ~(size_t)255;
        return (void*)p;
    };
    unsigned short* xhi = (unsigned short*)alloc((size_t)BL_TOT * HID * 2);  // later Qm/ob
    unsigned short* xlo = (unsigned short*)alloc((size_t)BL_TOT * HID * 2);  // later Khi, then Spart
    unsigned short* whi = (unsigned short*)alloc((size_t)HID * HID * 2);     // per-GEMM reuse
    unsigned short* wlo = (unsigned short*)alloc((size_t)HID * HID * 2);
    float* Gt   = (float*)alloc((size_t)BL_TOT * HID * 4);  // gemm out; later Um
    float* Km   = (float*)alloc((size_t)BL_TOT * HID * 4);
    float* Vm   = (float*)alloc((size_t)BL_TOT * HID * 4);  // later Wm (wu is LDS-staged -> alias-safe)
    float* Tg    = (float*)alloc((size_t)128 * 4096 * 4);
    float* betaB = (float*)alloc((size_t)BL_TOT * 4 * 4);
    float* kwB   = (float*)alloc((size_t)8 * 64 * 256 * 4);
    float* kuB   = (float*)alloc((size_t)8 * 64 * 256 * 4);
    float* dsA   = (float*)alloc((size_t)8 * 64 * 256 * 4);
    float* Um = Gt;                             // Gt dead after the last conv
    float* Wm = Vm;                             // Vm dead after wu_kernel's LDS staging
    __hip_bfloat16* Qm = (__hip_bfloat16*)xhi;  // xhi dead after Q GEMM (last GEMM)
    __hip_bfloat16* ob = Qm;                    // q dead after o_kernel reads its own row
    unsigned short* Khi = xlo;                  // xlo(x_lo) dead after K GEMM; Khi lives conv_k -> gram
    float* Spart = (float*)xlo;                 // Khi dead after gram; Spart lives s_kernel -> sreduce

    float* out0 = (float*)d_out;                // (B, L, HID) f32
    float* out1 = out0 + (size_t)BL_TOT * HID;  // (B, H, DH, DH) f32
    // d_out as pre-final scratch (validated only after launch completes):
    unsigned short* Klo = (unsigned short*)out0;          // 16.78 MB (= first 4.19M floats)
    float* Gg = out0 + (size_t)4400000;                   // 8.39 MB gram buffer; ends < out1

    dim3 blk(256);
    dim3 ggrid(BL_TOT / 128, HID / 128);  // (64, 8)
    const int NTOK = BL_TOT * HID;

    split_kernel<<<4096, blk, 0, stream>>>(x, xhi, xlo, NTOK);
    beta_kernel<<<BL_TOT, blk, 0, stream>>>(x, Wbeta, betaB);

    // V path (plain bf16: V propagates linearly -> ~0.2% rel, safe)
    f2b_kernel<<<1024, blk, 0, stream>>>(Wv, whi, HID * HID);
    gemm_mfma<0><<<ggrid, blk, 0, stream>>>(xhi, nullptr, whi, nullptr, Gt, BL_TOT, HID, HID);
    conv_kernel<float><<<BL_TOT, blk, 0, stream>>>(Gt, convv, Vm, 0, nullptr, nullptr);
    // K path (split bf16 -> ~f32 fidelity; feeds triangular recurrence). Last user of x_lo.
    split_kernel<<<1024, blk, 0, stream>>>(Wk, whi, wlo, HID * HID);
    gemm_mfma<1><<<ggrid, blk, 0, stream>>>(xhi, xlo, whi, wlo, Gt, BL_TOT, HID, HID);
    conv_kernel<float><<<BL_TOT, blk, 0, stream>>>(Gt, convk, Km, 1, Khi, Klo);
    // gram + T recurrence (replaces the old latency-bound tmat_kernel)
    gram_kernel<<<dim3(128, 4), blk, 0, stream>>>(Khi, Klo, Gg);
    trec_kernel<<<128, blk, 0, stream>>>(Gg, betaB, Tg);
    // Q path (plain bf16; q is cast to bf16 downstream anyway). Last GEMM: frees xhi.
    f2b_kernel<<<1024, blk, 0, stream>>>(Wq, whi, HID * HID);
    gemm_mfma<0><<<ggrid, blk, 0, stream>>>(xhi, nullptr, whi, nullptr, Gt, BL_TOT, HID, HID);
    conv_kernel<__hip_bfloat16><<<BL_TOT, blk, 0, stream>>>(Gt, convq, Qm, 1, nullptr, nullptr);

    // chunked delta rule
    wu_kernel<<<dim3(128, 4), blk, 0, stream>>>(Tg, Km, Vm, betaB, Wm, Um);
    kwku_kernel<<<dim3(128, 4), blk, 0, stream>>>(Km, Wm, Um, kwB, kuB);
    scan_kernel<<<8, blk, 0, stream>>>(kwB, kuB, dsA);
    o_kernel<<<BL_TOT, blk, 0, stream>>>(Qm, Km, Wm, Um, dsA, rmsw, ob);
    s_kernel<<<dim3(8, 4, 4 * NSPLIT), blk, 0, stream>>>(Km, Wm, Um, dsA, Spart);
    sreduce_kernel<<<2048, blk, 0, stream>>>(Spart, out1);

    // final projection: o(bf16) @ Wo^T -> f32 out0 (overwrites Klo/Gg scratch)
    f2b_kernel<<<1024, blk, 0, stream>>>(Wo, whi, HID * HID);
    gemm_mfma<0><<<ggrid, blk, 0, stream>>>((const unsigned short*)ob, nullptr, whi, nullptr,
                                            out0, BL_TOT, HID, HID);
}

// Round 7
// 544.929 us; speedup vs baseline: 3.6421x; 1.0687x over previous
//
#include <hip/hip_runtime.h>
#include <hip/hip_bf16.h>

#define L_SEQ 4096
#define HID 1024
#define NH 4
#define DH 256
#define CK 64
#define BL_TOT 8192   // B*L

typedef short v8s __attribute__((ext_vector_type(8)));
typedef unsigned short v8u __attribute__((ext_vector_type(8)));
typedef float v4f __attribute__((ext_vector_type(4)));

__device__ __forceinline__ void storev(float* p, float v) { *p = v; }
__device__ __forceinline__ void storev(__hip_bfloat16* p, float v) { *p = __float2bfloat16(v); }

__device__ __forceinline__ unsigned short f2bu(float f) {
    __hip_bfloat16 h = __float2bfloat16(f);
    return *(unsigned short*)&h;
}
__device__ __forceinline__ float bu2f(unsigned short u) {
    __hip_bfloat16 h = *(__hip_bfloat16*)&u;
    return __bfloat162float(h);
}

// ---------------- f32 -> (bf16 hi, bf16 lo) split ----------------
__global__ __launch_bounds__(256) void split_kernel(const float* __restrict__ in,
                                                    unsigned short* __restrict__ hi,
                                                    unsigned short* __restrict__ lo, int n) {
    int i = blockIdx.x * 256 + threadIdx.x;
    int stride = gridDim.x * 256;
    for (; i < n; i += stride) {
        float v = in[i];
        unsigned short h = f2bu(v);
        hi[i] = h;
        lo[i] = f2bu(v - bu2f(h));
    }
}

// ---------------- f32 -> bf16 (hi only) ----------------
__global__ __launch_bounds__(256) void f2b_kernel(const float* __restrict__ in,
                                                  unsigned short* __restrict__ hi, int n) {
    int i = blockIdx.x * 256 + threadIdx.x;
    int stride = gridDim.x * 256;
    for (; i < n; i += stride) hi[i] = f2bu(in[i]);
}

// ---------------- MFMA bf16 GEMM: C[M,N] = A[M,K] * B[N,K]^T  (f32 out) ----------------
// SPLIT=1: A=Ah+Al, B=Bh+Bl, 3-term (hi*hi + hi*lo + lo*hi) -> ~f32 fidelity.
template <int SPLIT>
__global__ __launch_bounds__(256) void gemm_mfma(const unsigned short* __restrict__ Ah,
                                                 const unsigned short* __restrict__ Al,
                                                 const unsigned short* __restrict__ Bh,
                                                 const unsigned short* __restrict__ Bl,
                                                 float* __restrict__ C, int M, int N, int K) {
    __shared__ unsigned short AsH[128 * 40];
    __shared__ unsigned short BsH[128 * 40];
    __shared__ unsigned short AsL[SPLIT ? 128 * 40 : 8];
    __shared__ unsigned short BsL[SPLIT ? 128 * 40 : 8];
    const int tid = threadIdx.x;
    const int wave = tid >> 6, lane = tid & 63;
    const int quad = lane >> 4, l16 = lane & 15;
    const int m0 = blockIdx.x * 128, n0 = blockIdx.y * 128;
    const int wm = (wave >> 1) * 64, wn = (wave & 1) * 64;
    const int r0 = tid >> 2;        // tile row (0..63); +64 for second issue
    const int kk = (tid & 3) * 8;   // k offset within BK=32 (8 bf16 = 16B)

    v4f acc[4][4];
#pragma unroll
    for (int a = 0; a < 4; ++a)
#pragma unroll
        for (int b = 0; b < 4; ++b) { v4f z = {0.f, 0.f, 0.f, 0.f}; acc[a][b] = z; }

    for (int k0 = 0; k0 < K; k0 += 32) {
        v8u ah0 = *(const v8u*)(Ah + (size_t)(m0 + r0) * K + k0 + kk);
        v8u ah1 = *(const v8u*)(Ah + (size_t)(m0 + r0 + 64) * K + k0 + kk);
        v8u bh0 = *(const v8u*)(Bh + (size_t)(n0 + r0) * K + k0 + kk);
        v8u bh1 = *(const v8u*)(Bh + (size_t)(n0 + r0 + 64) * K + k0 + kk);
        v8u al0, al1, bl0, bl1;
        if (SPLIT) {
            al0 = *(const v8u*)(Al + (size_t)(m0 + r0) * K + k0 + kk);
            al1 = *(const v8u*)(Al + (size_t)(m0 + r0 + 64) * K + k0 + kk);
            bl0 = *(const v8u*)(Bl + (size_t)(n0 + r0) * K + k0 + kk);
            bl1 = *(const v8u*)(Bl + (size_t)(n0 + r0 + 64) * K + k0 + kk);
        }
        __syncthreads();
        *(v8u*)&AsH[r0 * 40 + kk] = ah0;
        *(v8u*)&AsH[(r0 + 64) * 40 + kk] = ah1;
        *(v8u*)&BsH[r0 * 40 + kk] = bh0;
        *(v8u*)&BsH[(r0 + 64) * 40 + kk] = bh1;
        if (SPLIT) {
            *(v8u*)&AsL[r0 * 40 + kk] = al0;
            *(v8u*)&AsL[(r0 + 64) * 40 + kk] = al1;
            *(v8u*)&BsL[r0 * 40 + kk] = bl0;
            *(v8u*)&BsL[(r0 + 64) * 40 + kk] = bl1;
        }
        __syncthreads();
        v8s afh[4], bfh[4], afl[4], bfl[4];
#pragma unroll
        for (int mt = 0; mt < 4; ++mt) afh[mt] = *(const v8s*)&AsH[(wm + mt * 16 + l16) * 40 + quad * 8];
#pragma unroll
        for (int nt = 0; nt < 4; ++nt) bfh[nt] = *(const v8s*)&BsH[(wn + nt * 16 + l16) * 40 + quad * 8];
        if (SPLIT) {
#pragma unroll
            for (int mt = 0; mt < 4; ++mt) afl[mt] = *(const v8s*)&AsL[(wm + mt * 16 + l16) * 40 + quad * 8];
#pragma unroll
            for (int nt = 0; nt < 4; ++nt) bfl[nt] = *(const v8s*)&BsL[(wn + nt * 16 + l16) * 40 + quad * 8];
        }
#pragma unroll
        for (int mt = 0; mt < 4; ++mt)
#pragma unroll
            for (int nt = 0; nt < 4; ++nt) {
                acc[mt][nt] = __builtin_amdgcn_mfma_f32_16x16x32_bf16(afh[mt], bfh[nt], acc[mt][nt], 0, 0, 0);
                if (SPLIT) {
                    acc[mt][nt] = __builtin_amdgcn_mfma_f32_16x16x32_bf16(afh[mt], bfl[nt], acc[mt][nt], 0, 0, 0);
                    acc[mt][nt] = __builtin_amdgcn_mfma_f32_16x16x32_bf16(afl[mt], bfh[nt], acc[mt][nt], 0, 0, 0);
                }
            }
    }
    // C/D layout (m89-verified): col = lane&15, row = (lane>>4)*4 + reg
#pragma unroll
    for (int mt = 0; mt < 4; ++mt)
#pragma unroll
        for (int nt = 0; nt < 4; ++nt) {
            int row = m0 + wm + mt * 16 + quad * 4;
            int col = n0 + wn + nt * 16 + l16;
#pragma unroll
            for (int r = 0; r < 4; ++r)
                C[(size_t)(row + r) * N + col] = acc[mt][nt][r];
        }
}

// ---------------- beta = sigmoid(x @ Wbeta^T) ----------------
__global__ __launch_bounds__(256) void beta_kernel(const float* __restrict__ x,
                                                   const float* __restrict__ Wb,
                                                   float* __restrict__ betaB) {
    const int t = blockIdx.x;  // 0..8191
    const int tid = threadIdx.x;
    const int wave = tid >> 6, lane = tid & 63;
    const float* xr = x + (size_t)t * HID;
    float s[4] = {0.f, 0.f, 0.f, 0.f};
    for (int i = tid; i < HID; i += 256) {
        float xv = xr[i];
        s[0] += xv * Wb[i];
        s[1] += xv * Wb[HID + i];
        s[2] += xv * Wb[2 * HID + i];
        s[3] += xv * Wb[3 * HID + i];
    }
#pragma unroll
    for (int off = 32; off; off >>= 1)
#pragma unroll
        for (int h = 0; h < 4; ++h) s[h] += __shfl_down(s[h], off);
    __shared__ float red[4][4];
    if (lane == 0)
#pragma unroll
        for (int h = 0; h < 4; ++h) red[wave][h] = s[h];
    __syncthreads();
    if (tid < 4) {
        float tot = red[0][tid] + red[1][tid] + red[2][tid] + red[3][tid];
        betaB[(size_t)t * 4 + tid] = 1.f / (1.f + expf(-tot));
    }
}

// ---------------- causal depthwise conv (KS=4) + silu + silu (+ per-head l2norm) ----------------
// Optionally also emits bf16 hi/lo of the result (K path -> gram MFMA inputs).
template <typename OUT>
__global__ __launch_bounds__(256) void conv_kernel(const float* __restrict__ G,
                                                   const float* __restrict__ w,  // [HID][KS]
                                                   OUT* __restrict__ out, int do_norm,
                                                   unsigned short* __restrict__ hi,
                                                   unsigned short* __restrict__ lo) {
    const int bl = blockIdx.x;  // b*L + l
    const int l = bl & (L_SEQ - 1);
    const int tid = threadIdx.x;
    const int wave = tid >> 6, lane = tid & 63;
    float vals[4];
#pragma unroll
    for (int h = 0; h < 4; ++h) {
        const int c = tid + 256 * h;
        float acc = 0.f;
#pragma unroll
        for (int j = 0; j < 4; ++j) {
            int ls = l - 3 + j;
            float xv = 0.f;
            if (ls >= 0) xv = G[(size_t)(bl - 3 + j) * HID + c];
            acc += xv * w[c * 4 + j];
        }
        float s1 = acc / (1.f + expf(-acc));
        float s2 = s1 / (1.f + expf(-s1));
        vals[h] = s2;
    }
    if (do_norm) {
        float sq[4];
#pragma unroll
        for (int h = 0; h < 4; ++h) sq[h] = vals[h] * vals[h];
#pragma unroll
        for (int off = 32; off; off >>= 1)
#pragma unroll
            for (int h = 0; h < 4; ++h) sq[h] += __shfl_down(sq[h], off);
        __shared__ float red[4][4];
        __shared__ float nrm[4];
        if (lane == 0)
#pragma unroll
            for (int h = 0; h < 4; ++h) red[wave][h] = sq[h];
        __syncthreads();
        if (tid < 4) {
            float tot = red[0][tid] + red[1][tid] + red[2][tid] + red[3][tid];
            nrm[tid] = 1.f / fmaxf(sqrtf(tot), 1e-12f);
        }
        __syncthreads();
#pragma unroll
        for (int h = 0; h < 4; ++h) vals[h] *= nrm[h];
    }
#pragma unroll
    for (int h = 0; h < 4; ++h) {
        const int c = tid + 256 * h;
        storev(&out[(size_t)bl * HID + c], vals[h]);
        if (hi) {
            unsigned short hv = f2bu(vals[h]);
            hi[(size_t)bl * HID + c] = hv;
            lo[(size_t)bl * HID + c] = f2bu(vals[h] - bu2f(hv));
        }
    }
}

// ---------------- per-chunk per-head gram: G_h = K_h * K_h^T (split-bf16 MFMA) ----------------
__global__ __launch_bounds__(256) void gram_kernel(const unsigned short* __restrict__ Khi,
                                                   const unsigned short* __restrict__ Klo,
                                                   float* __restrict__ Gg) {
    const int chunk = blockIdx.x;  // 0..127
    const int h = blockIdx.y;      // 0..3
    const int tid = threadIdx.x;
    const int wave = tid >> 6, lane = tid & 63;
    const int quad = lane >> 4, l16 = lane & 15;
    __shared__ unsigned short Hs[64 * 264];
    __shared__ unsigned short Ls[64 * 264];
    const int l0 = chunk * 64;
    const int cb = h * 256;
#pragma unroll
    for (int p = 0; p < 8; ++p) {
        int row = p * 8 + (tid >> 5);
        int col = (tid & 31) * 8;
        v8u hv = *(const v8u*)(Khi + (size_t)(l0 + row) * HID + cb + col);
        v8u lv = *(const v8u*)(Klo + (size_t)(l0 + row) * HID + cb + col);
        *(v8u*)&Hs[row * 264 + col] = hv;
        *(v8u*)&Ls[row * 264 + col] = lv;
    }
    __syncthreads();
    const int wm = wave * 16;  // row band of this wave
    v4f acc[4];
#pragma unroll
    for (int nt = 0; nt < 4; ++nt) { v4f z = {0.f, 0.f, 0.f, 0.f}; acc[nt] = z; }
#pragma unroll
    for (int ks = 0; ks < 8; ++ks) {
        v8s ah = *(const v8s*)&Hs[(wm + l16) * 264 + ks * 32 + quad * 8];
        v8s al = *(const v8s*)&Ls[(wm + l16) * 264 + ks * 32 + quad * 8];
#pragma unroll
        for (int nt = 0; nt < 4; ++nt) {
            v8s bh = *(const v8s*)&Hs[(nt * 16 + l16) * 264 + ks * 32 + quad * 8];
            v8s bl = *(const v8s*)&Ls[(nt * 16 + l16) * 264 + ks * 32 + quad * 8];
            acc[nt] = __builtin_amdgcn_mfma_f32_16x16x32_bf16(ah, bh, acc[nt], 0, 0, 0);
            acc[nt] = __builtin_amdgcn_mfma_f32_16x16x32_bf16(ah, bl, acc[nt], 0, 0, 0);
            acc[nt] = __builtin_amdgcn_mfma_f32_16x16x32_bf16(al, bh, acc[nt], 0, 0, 0);
        }
    }
    float* og = Gg + ((size_t)chunk * 4 + h) * 4096;
#pragma unroll
    for (int nt = 0; nt < 4; ++nt)
#pragma unroll
        for (int r = 0; r < 4; ++r)
            og[(wm + quad * 4 + r) * 64 + nt * 16 + l16] = acc[nt][r];
}

// ---------------- T recurrence per chunk (gram precomputed) ----------------
__global__ __launch_bounds__(256) void trec_kernel(const float* __restrict__ Gg,
                                                   const float* __restrict__ betaB,
                                                   float* __restrict__ Tg) {
    const int chunk = blockIdx.x;  // 0..127
    const int tid = threadIdx.x;
    __shared__ float Ts[64 * 65];
    __shared__ float betS[256];
    betS[tid] = betaB[(size_t)chunk * 256 + tid];
    __syncthreads();
    const float* gg = Gg + (size_t)chunk * 4 * 4096;
#pragma unroll
    for (int s = 0; s < 16; ++s) {
        int idx = tid + 256 * s;
        int i = idx >> 6, j = idx & 63;
        float v;
        if (i > j) {
            float t = betS[i * 4 + 0] * gg[idx] + betS[i * 4 + 1] * gg[4096 + idx] +
                      betS[i * 4 + 2] * gg[2 * 4096 + idx] + betS[i * 4 + 3] * gg[3 * 4096 + idx];
            v = -t;
        } else {
            v = (i == j) ? 1.f : 0.f;
        }
        Ts[i * 65 + j] = v;
    }
    __syncthreads();
    // serial recurrence: T[i,c<i] = 2*T0[i,c] + sum_{j<i} T0[i,j]*T[j,c]
    for (int i = 1; i < 64; ++i) {
        float v = 0.f;
        if (tid < i) {
            v = 2.f * Ts[i * 65 + tid];
            for (int j = 0; j < i; ++j) v += Ts[i * 65 + j] * Ts[j * 65 + tid];
        }
        __syncthreads();
        if (tid < i) Ts[i * 65 + tid] = v;
        __syncthreads();
    }
#pragma unroll
    for (int s = 0; s < 16; ++s) {
        int idx = tid + 256 * s;
        Tg[(size_t)chunk * 4096 + idx] = Ts[(idx >> 6) * 65 + (idx & 63)];
    }
}

// ---------------- W = T*Kb, U = T*Vb  + fused kw/ku diagonal dots ----------------
__global__ __launch_bounds__(256) void wu_kernel(const float* __restrict__ Tg,
                                                 const float* __restrict__ Km,
                                                 const float* __restrict__ Vm,
                                                 const float* __restrict__ betaB,
                                                 float* __restrict__ Wm, float* __restrict__ Um,
                                                 float* __restrict__ kw, float* __restrict__ ku) {
    const int chunk = blockIdx.x;  // 128
    const int h = blockIdx.y;      // 4
    const size_t l0 = (size_t)chunk * 64;
    const int tid = threadIdx.x;
    const int lane = tid & 63, rgrp = tid >> 6;
    __shared__ float Ts[64 * 65];
    __shared__ float KbS[64 * 65];
    __shared__ float VbS[64 * 65];
    __shared__ float betS[64];
    __shared__ float kredW[256], kredU[256];
#pragma unroll
    for (int s = 0; s < 16; ++s) {
        int idx = tid + 256 * s;
        Ts[(idx >> 6) * 65 + (idx & 63)] = Tg[(size_t)chunk * 4096 + idx];
    }
    if (tid < 64) betS[tid] = betaB[(l0 + tid) * 4 + h];

    for (int fp = 0; fp < 4; ++fp) {
        const int f0 = h * 256 + fp * 64;
        __syncthreads();  // prev-iter done; betS/Ts visible on fp==0
#pragma unroll
        for (int s = 0; s < 16; ++s) {
            int idx = tid + 256 * s;
            int row = idx >> 6, col = idx & 63;
            float bj = betS[row];
            size_t gi = (l0 + row) * HID + f0 + col;
            KbS[row * 65 + col] = Km[gi] * bj;
            VbS[row * 65 + col] = Vm[gi] * bj;
        }
        __syncthreads();
        float accW[16], accU[16];
#pragma unroll
        for (int cc = 0; cc < 16; ++cc) { accW[cc] = 0.f; accU[cc] = 0.f; }
        for (int j = 0; j < 64; ++j) {
            float kb = KbS[j * 65 + lane];
            float vb = VbS[j * 65 + lane];
#pragma unroll
            for (int cc = 0; cc < 16; ++cc) {
                float tv = Ts[(rgrp + 4 * cc) * 65 + j];
                accW[cc] += tv * kb;
                accU[cc] += tv * vb;
            }
        }
        float kwp = 0.f, kup = 0.f;
#pragma unroll
        for (int cc = 0; cc < 16; ++cc) {
            size_t go = (l0 + rgrp + 4 * cc) * HID + f0 + lane;
            Wm[go] = accW[cc];
            Um[go] = accU[cc];
            float kraw = Km[go];  // L1-hot (staged just above)
            kwp += kraw * accW[cc];
            kup += kraw * accU[cc];
        }
        kredW[rgrp * 64 + lane] = kwp;
        kredU[rgrp * 64 + lane] = kup;
        __syncthreads();
        if (rgrp == 0) {
            float sw = kredW[lane] + kredW[64 + lane] + kredW[128 + lane] + kredW[192 + lane];
            float su = kredU[lane] + kredU[64 + lane] + kredU[128 + lane] + kredU[192 + lane];
            int bb = chunk >> 6, n = chunk & 63;
            size_t o = (((size_t)bb * 4 + h) * 64 + n) * 256 + fp * 64 + lane;
            kw[o] = sw;
            ku[o] = su;
        }
    }
}

// ---------------- diagonal scan over chunks ----------------
__global__ __launch_bounds__(256) void scan_kernel(const float* __restrict__ kw,
                                                   const float* __restrict__ ku,
                                                   float* __restrict__ dsA) {
    const int bh = blockIdx.x;  // 0..7
    const int e = threadIdx.x;
    float ds = 0.f;
    for (int n = 0; n < 64; ++n) {
        size_t idx = ((size_t)bh * 64 + n) * 256 + e;
        dsA[idx] = ds;
        ds = ds * (1.f - kw[idx]) + ku[idx];
    }
}

__device__ __forceinline__ float block_sum(float v, float* red) {
#pragma unroll
    for (int off = 32; off; off >>= 1) v += __shfl_down(v, off);
    const int wave = threadIdx.x >> 6;
    if ((threadIdx.x & 63) == 0) red[wave] = v;
    __syncthreads();
    float t = red[0] + red[1] + red[2] + red[3];
    __syncthreads();
    return t;
}

// ---------------- o = q*ds + [c<=b]*A*(u - w*ds); fused RMSNorm + bf16 cast ----------------
// Also emits ub = bf16(u') for the MFMA state kernel.
// ob aliases Qb: each thread reads its own q elements into registers first -> alias-safe.
__global__ __launch_bounds__(256) void o_kernel(const __hip_bfloat16* __restrict__ Qb,
                                                const float* __restrict__ Km,
                                                const float* __restrict__ Wm,
                                                const float* __restrict__ Um,
                                                const float* __restrict__ dsA,
                                                const float* __restrict__ rmsw,
                                                __hip_bfloat16* __restrict__ ob,
                                                unsigned short* __restrict__ ub) {
    const int bl = blockIdx.x;
    const int b = bl >> 12, l = bl & (L_SEQ - 1);
    const int n = l >> 6, cpos = l & 63;
    const int tid = threadIdx.x;
    __shared__ float red[4];
    const size_t rowb = (size_t)bl * HID;
    float dsv[4], qv[4], ov[4];
#pragma unroll
    for (int h = 0; h < 4; ++h) {
        dsv[h] = dsA[(((size_t)b * 4 + h) * 64 + n) * 256 + tid];
        qv[h] = __bfloat162float(Qb[rowb + tid + 256 * h]);
    }
    const bool doA = (cpos <= b);  // tril on the (B=2, C=64) A matrix
    float Aval = 0.f;
    if (doA) {
        float s = 0.f;
#pragma unroll
        for (int h = 0; h < 4; ++h) s += qv[h] * Km[rowb + tid + 256 * h];
        Aval = block_sum(s, red);
    }
    float ss = 0.f;
#pragma unroll
    for (int h = 0; h < 4; ++h) {
        int c = tid + 256 * h;
        float u = Um[rowb + c] - Wm[rowb + c] * dsv[h];
        ub[rowb + c] = f2bu(u);
        float o = qv[h] * dsv[h];
        if (doA) o += Aval * u;
        ov[h] = o;
        ss += o * o;
    }
    float tot = block_sum(ss, red);
    float scale = rsqrtf(tot * (1.f / 1024.f) + 1e-5f);
#pragma unroll
    for (int h = 0; h < 4; ++h) {
        int c = tid + 256 * h;
        ob[rowb + c] = __float2bfloat16(ov[h] * scale * rmsw[c]);
    }
}

// ---------------- state S = K^T u'  via MFMA (n-split partials) ----------------
#define SNS 16
__global__ __launch_bounds__(256) void s_mfma_kernel(const unsigned short* __restrict__ Khi,
                                                     const unsigned short* __restrict__ Ub,
                                                     float* __restrict__ Spart) {
    const int bh = blockIdx.x;       // 0..7 = b*4+h
    const int b = bh >> 2, h = bh & 3;
    const int dt = blockIdx.y;       // 0..1
    const int et = blockIdx.z & 1;   // 0..1
    const int ns = blockIdx.z >> 1;  // 0..15
    const int tid = threadIdx.x;
    const int wave = tid >> 6, lane = tid & 63;
    const int quad = lane >> 4, l16 = lane & 15;
    const int wm = (wave >> 1) * 64, wn = (wave & 1) * 64;
    __shared__ unsigned short Kt[128 * 40];  // [d][c] transposed
    __shared__ unsigned short Ut[128 * 40];  // [e][c] transposed
    const int cc = tid >> 3;          // 0..31
    const int dcol = (tid & 7) * 16;  // 0..112
    const size_t rowbase = (size_t)b * 4096 + (size_t)ns * 256;
    const int ck = h * 256 + dt * 128;
    const int ce = h * 256 + et * 128;
    v4f acc[4][4];
#pragma unroll
    for (int a = 0; a < 4; ++a)
#pragma unroll
        for (int c2 = 0; c2 < 4; ++c2) { v4f z = {0.f, 0.f, 0.f, 0.f}; acc[a][c2] = z; }

    for (int kt = 0; kt < 8; ++kt) {
        size_t row = rowbase + kt * 32 + cc;
        v8u k0 = *(const v8u*)(Khi + row * HID + ck + dcol);
        v8u k1 = *(const v8u*)(Khi + row * HID + ck + dcol + 8);
        v8u u0 = *(const v8u*)(Ub + row * HID + ce + dcol);
        v8u u1 = *(const v8u*)(Ub + row * HID + ce + dcol + 8);
        __syncthreads();
#pragma unroll
        for (int j = 0; j < 8; ++j) {
            Kt[(dcol + j) * 40 + cc] = k0[j];
            Kt[(dcol + 8 + j) * 40 + cc] = k1[j];
            Ut[(dcol + j) * 40 + cc] = u0[j];
            Ut[(dcol + 8 + j) * 40 + cc] = u1[j];
        }
        __syncthreads();
        v8s af[4], bf[4];
#pragma unroll
        for (int mt = 0; mt < 4; ++mt) af[mt] = *(const v8s*)&Kt[(wm + mt * 16 + l16) * 40 + quad * 8];
#pragma unroll
        for (int nt = 0; nt < 4; ++nt) bf[nt] = *(const v8s*)&Ut[(wn + nt * 16 + l16) * 40 + quad * 8];
#pragma unroll
        for (int mt = 0; mt < 4; ++mt)
#pragma unroll
            for (int nt = 0; nt < 4; ++nt)
                acc[mt][nt] = __builtin_amdgcn_mfma_f32_16x16x32_bf16(af[mt], bf[nt], acc[mt][nt], 0, 0, 0);
    }
    float* out = Spart + (size_t)ns * (8 * 256 * 256);
#pragma unroll
    for (int mt = 0; mt < 4; ++mt)
#pragma unroll
        for (int nt = 0; nt < 4; ++nt) {
            int row = dt * 128 + wm + mt * 16 + quad * 4;
            int col = et * 128 + wn + nt * 16 + l16;
#pragma unroll
            for (int r = 0; r < 4; ++r)
                out[((size_t)bh * 256 + row + r) * 256 + col] = acc[mt][nt][r];
        }
}

// ---------------- reduce SNS partials -> out1 ----------------
__global__ __launch_bounds__(256) void sreduce_kernel(const float* __restrict__ Spart,
                                                      float* __restrict__ out) {
    int i = blockIdx.x * 256 + threadIdx.x;  // 8*256*256 = 524288 total
    float s = 0.f;
#pragma unroll
    for (int ns = 0; ns < SNS; ++ns) s += Spart[(size_t)ns * (8 * 256 * 256) + i];
    out[i] = s;
}

extern "C" void kernel_launch(void* const* d_in, const int* in_sizes, int n_in,
                              void* d_out, int out_size, void* d_ws, size_t ws_size,
                              hipStream_t stream) {
    const float* x     = (const float*)d_in[0];
    const float* Wq    = (const float*)d_in[1];
    const float* Wk    = (const float*)d_in[2];
    const float* Wv    = (const float*)d_in[3];
    const float* convq = (const float*)d_in[4];
    const float* convk = (const float*)d_in[5];
    const float* convv = (const float*)d_in[6];
    const float* Wbeta = (const float*)d_in[7];
    const float* rmsw  = (const float*)d_in[8];
    const float* Wo    = (const float*)d_in[9];

    // ---- workspace map (~136 MiB; aliases documented) ----
    char* ws = (char*)d_ws;
    size_t off = 0;
    auto alloc = [&](size_t bytes) {
        char* p = ws + off;
        off += (bytes + 255) & ~(size_t)255;
        return (void*)p;
    };
    unsigned short* xhi = (unsigned short*)alloc((size_t)BL_TOT * HID * 2);  // later Qm/ob
    unsigned short* xlo = (unsigned short*)alloc((size_t)BL_TOT * HID * 2);  // later Khi (lives to s_mfma)
    unsigned short* whi = (unsigned short*)alloc((size_t)HID * HID * 2);     // per-GEMM reuse
    unsigned short* wlo = (unsigned short*)alloc((size_t)HID * HID * 2);
    float* Gt   = (float*)alloc((size_t)BL_TOT * HID * 4);  // gemm out; later Um; later Spart
    float* Km   = (float*)alloc((size_t)BL_TOT * HID * 4);
    float* Vm   = (float*)alloc((size_t)BL_TOT * HID * 4);  // later Wm (wu is LDS-staged -> alias-safe)
    float* Tg    = (float*)alloc((size_t)128 * 4096 * 4);
    float* betaB = (float*)alloc((size_t)BL_TOT * 4 * 4);
    float* kwB   = (float*)alloc((size_t)8 * 64 * 256 * 4);
    float* kuB   = (float*)alloc((size_t)8 * 64 * 256 * 4);
    float* dsA   = (float*)alloc((size_t)8 * 64 * 256 * 4);
    float* Um = Gt;                             // Gt dead after the last conv
    float* Wm = Vm;                             // Vm dead after wu_kernel's LDS staging
    __hip_bfloat16* Qm = (__hip_bfloat16*)xhi;  // xhi dead after Q GEMM (last GEMM)
    __hip_bfloat16* ob = Qm;                    // q dead after o_kernel reads its own row
    unsigned short* Khi = xlo;                  // xlo(x_lo) dead after K GEMM; Khi lives conv_k -> s_mfma
    float* Spart = Gt;                          // Um dead after o_kernel; 16*8*256*256*4 = 33.5 MB = Gt size

    float* out0 = (float*)d_out;                // (B, L, HID) f32
    float* out1 = out0 + (size_t)BL_TOT * HID;  // (B, H, DH, DH) f32
    // d_out as pre-final scratch (validated only after launch completes):
    unsigned short* Klo = (unsigned short*)out0;            // first half of out0 region (16.78 MB)
    unsigned short* ubf = (unsigned short*)out0 + 8388608;  // second half of out0 region (16.78 MB)
    float* Gg = out0 + (size_t)4400000;                     // 8.39 MB gram scratch; dead before o_kernel

    dim3 blk(256);
    dim3 ggrid(BL_TOT / 128, HID / 128);  // (64, 8)
    const int NTOK = BL_TOT * HID;

    split_kernel<<<4096, blk, 0, stream>>>(x, xhi, xlo, NTOK);
    beta_kernel<<<BL_TOT, blk, 0, stream>>>(x, Wbeta, betaB);

    // V path (plain bf16: V propagates linearly -> ~0.2% rel, safe)
    f2b_kernel<<<1024, blk, 0, stream>>>(Wv, whi, HID * HID);
    gemm_mfma<0><<<ggrid, blk, 0, stream>>>(xhi, nullptr, whi, nullptr, Gt, BL_TOT, HID, HID);
    conv_kernel<float><<<BL_TOT, blk, 0, stream>>>(Gt, convv, Vm, 0, nullptr, nullptr);
    // K path (split bf16 -> ~f32 fidelity; feeds triangular recurrence). Last user of x_lo.
    split_kernel<<<1024, blk, 0, stream>>>(Wk, whi, wlo, HID * HID);
    gemm_mfma<1><<<ggrid, blk, 0, stream>>>(xhi, xlo, whi, wlo, Gt, BL_TOT, HID, HID);
    conv_kernel<float><<<BL_TOT, blk, 0, stream>>>(Gt, convk, Km, 1, Khi, Klo);
    // gram + T recurrence
    gram_kernel<<<dim3(128, 4), blk, 0, stream>>>(Khi, Klo, Gg);
    trec_kernel<<<128, blk, 0, stream>>>(Gg, betaB, Tg);
    // Q path (plain bf16; q is cast to bf16 downstream anyway). Last GEMM: frees xhi.
    f2b_kernel<<<1024, blk, 0, stream>>>(Wq, whi, HID * HID);
    gemm_mfma<0><<<ggrid, blk, 0, stream>>>(xhi, nullptr, whi, nullptr, Gt, BL_TOT, HID, HID);
    conv_kernel<__hip_bfloat16><<<BL_TOT, blk, 0, stream>>>(Gt, convq, Qm, 1, nullptr, nullptr);

    // chunked delta rule
    wu_kernel<<<dim3(128, 4), blk, 0, stream>>>(Tg, Km, Vm, betaB, Wm, Um, kwB, kuB);
    scan_kernel<<<8, blk, 0, stream>>>(kwB, kuB, dsA);
    o_kernel<<<BL_TOT, blk, 0, stream>>>(Qm, Km, Wm, Um, dsA, rmsw, ob, ubf);
    s_mfma_kernel<<<dim3(8, 2, 2 * SNS), blk, 0, stream>>>(Khi, ubf, Spart);
    sreduce_kernel<<<2048, blk, 0, stream>>>(Spart, out1);

    // final projection: o(bf16) @ Wo^T -> f32 out0 (overwrites Klo/ubf scratch)
    f2b_kernel<<<1024, blk, 0, stream>>>(Wo, whi, HID * HID);
    gemm_mfma<0><<<ggrid, blk, 0, stream>>>((const unsigned short*)ob, nullptr, whi, nullptr,
                                            out0, BL_TOT, HID, HID);
}

// Round 8
// 495.953 us; speedup vs baseline: 4.0018x; 1.0988x over previous
//
#include <hip/hip_runtime.h>
#include <hip/hip_bf16.h>

#define L_SEQ 4096
#define HID 1024
#define NH 4
#define DH 256
#define CK 64
#define BL_TOT 8192   // B*L

typedef short v8s __attribute__((ext_vector_type(8)));
typedef unsigned short v8u __attribute__((ext_vector_type(8)));
typedef float v4f __attribute__((ext_vector_type(4)));

__device__ __forceinline__ void storev(float* p, float v) { *p = v; }
__device__ __forceinline__ void storev(__hip_bfloat16* p, float v) { *p = __float2bfloat16(v); }

__device__ __forceinline__ unsigned short f2bu(float f) {
    __hip_bfloat16 h = __float2bfloat16(f);
    return *(unsigned short*)&h;
}
__device__ __forceinline__ float bu2f(unsigned short u) {
    __hip_bfloat16 h = *(__hip_bfloat16*)&u;
    return __bfloat162float(h);
}

// ---------------- f32 -> (bf16 hi, bf16 lo) split ----------------
__global__ __launch_bounds__(256) void split_kernel(const float* __restrict__ in,
                                                    unsigned short* __restrict__ hi,
                                                    unsigned short* __restrict__ lo, int n) {
    int i = blockIdx.x * 256 + threadIdx.x;
    int stride = gridDim.x * 256;
    for (; i < n; i += stride) {
        float v = in[i];
        unsigned short h = f2bu(v);
        hi[i] = h;
        lo[i] = f2bu(v - bu2f(h));
    }
}

// ---------------- f32 -> bf16 (hi only) ----------------
__global__ __launch_bounds__(256) void f2b_kernel(const float* __restrict__ in,
                                                  unsigned short* __restrict__ hi, int n) {
    int i = blockIdx.x * 256 + threadIdx.x;
    int stride = gridDim.x * 256;
    for (; i < n; i += stride) hi[i] = f2bu(in[i]);
}

// ---------------- MFMA bf16 GEMM: C[M,N] = A[M,K] * B[N,K]^T  (f32 out) ----------------
template <int SPLIT>
__global__ __launch_bounds__(256) void gemm_mfma(const unsigned short* __restrict__ Ah,
                                                 const unsigned short* __restrict__ Al,
                                                 const unsigned short* __restrict__ Bh,
                                                 const unsigned short* __restrict__ Bl,
                                                 float* __restrict__ C, int M, int N, int K) {
    __shared__ unsigned short AsH[128 * 40];
    __shared__ unsigned short BsH[128 * 40];
    __shared__ unsigned short AsL[SPLIT ? 128 * 40 : 8];
    __shared__ unsigned short BsL[SPLIT ? 128 * 40 : 8];
    const int tid = threadIdx.x;
    const int wave = tid >> 6, lane = tid & 63;
    const int quad = lane >> 4, l16 = lane & 15;
    const int m0 = blockIdx.x * 128, n0 = blockIdx.y * 128;
    const int wm = (wave >> 1) * 64, wn = (wave & 1) * 64;
    const int r0 = tid >> 2;
    const int kk = (tid & 3) * 8;

    v4f acc[4][4];
#pragma unroll
    for (int a = 0; a < 4; ++a)
#pragma unroll
        for (int b = 0; b < 4; ++b) { v4f z = {0.f, 0.f, 0.f, 0.f}; acc[a][b] = z; }

    for (int k0 = 0; k0 < K; k0 += 32) {
        v8u ah0 = *(const v8u*)(Ah + (size_t)(m0 + r0) * K + k0 + kk);
        v8u ah1 = *(const v8u*)(Ah + (size_t)(m0 + r0 + 64) * K + k0 + kk);
        v8u bh0 = *(const v8u*)(Bh + (size_t)(n0 + r0) * K + k0 + kk);
        v8u bh1 = *(const v8u*)(Bh + (size_t)(n0 + r0 + 64) * K + k0 + kk);
        v8u al0, al1, bl0, bl1;
        if (SPLIT) {
            al0 = *(const v8u*)(Al + (size_t)(m0 + r0) * K + k0 + kk);
            al1 = *(const v8u*)(Al + (size_t)(m0 + r0 + 64) * K + k0 + kk);
            bl0 = *(const v8u*)(Bl + (size_t)(n0 + r0) * K + k0 + kk);
            bl1 = *(const v8u*)(Bl + (size_t)(n0 + r0 + 64) * K + k0 + kk);
        }
        __syncthreads();
        *(v8u*)&AsH[r0 * 40 + kk] = ah0;
        *(v8u*)&AsH[(r0 + 64) * 40 + kk] = ah1;
        *(v8u*)&BsH[r0 * 40 + kk] = bh0;
        *(v8u*)&BsH[(r0 + 64) * 40 + kk] = bh1;
        if (SPLIT) {
            *(v8u*)&AsL[r0 * 40 + kk] = al0;
            *(v8u*)&AsL[(r0 + 64) * 40 + kk] = al1;
            *(v8u*)&BsL[r0 * 40 + kk] = bl0;
            *(v8u*)&BsL[(r0 + 64) * 40 + kk] = bl1;
        }
        __syncthreads();
        v8s afh[4], bfh[4], afl[4], bfl[4];
#pragma unroll
        for (int mt = 0; mt < 4; ++mt) afh[mt] = *(const v8s*)&AsH[(wm + mt * 16 + l16) * 40 + quad * 8];
#pragma unroll
        for (int nt = 0; nt < 4; ++nt) bfh[nt] = *(const v8s*)&BsH[(wn + nt * 16 + l16) * 40 + quad * 8];
        if (SPLIT) {
#pragma unroll
            for (int mt = 0; mt < 4; ++mt) afl[mt] = *(const v8s*)&AsL[(wm + mt * 16 + l16) * 40 + quad * 8];
#pragma unroll
            for (int nt = 0; nt < 4; ++nt) bfl[nt] = *(const v8s*)&BsL[(wn + nt * 16 + l16) * 40 + quad * 8];
        }
#pragma unroll
        for (int mt = 0; mt < 4; ++mt)
#pragma unroll
            for (int nt = 0; nt < 4; ++nt) {
                acc[mt][nt] = __builtin_amdgcn_mfma_f32_16x16x32_bf16(afh[mt], bfh[nt], acc[mt][nt], 0, 0, 0);
                if (SPLIT) {
                    acc[mt][nt] = __builtin_amdgcn_mfma_f32_16x16x32_bf16(afh[mt], bfl[nt], acc[mt][nt], 0, 0, 0);
                    acc[mt][nt] = __builtin_amdgcn_mfma_f32_16x16x32_bf16(afl[mt], bfh[nt], acc[mt][nt], 0, 0, 0);
                }
            }
    }
#pragma unroll
    for (int mt = 0; mt < 4; ++mt)
#pragma unroll
        for (int nt = 0; nt < 4; ++nt) {
            int row = m0 + wm + mt * 16 + quad * 4;
            int col = n0 + wn + nt * 16 + l16;
#pragma unroll
            for (int r = 0; r < 4; ++r)
                C[(size_t)(row + r) * N + col] = acc[mt][nt][r];
        }
}

// ---------------- beta = sigmoid(x @ Wbeta^T) ----------------
__global__ __launch_bounds__(256) void beta_kernel(const float* __restrict__ x,
                                                   const float* __restrict__ Wb,
                                                   float* __restrict__ betaB) {
    const int t = blockIdx.x;
    const int tid = threadIdx.x;
    const int wave = tid >> 6, lane = tid & 63;
    const float* xr = x + (size_t)t * HID;
    float s[4] = {0.f, 0.f, 0.f, 0.f};
    for (int i = tid; i < HID; i += 256) {
        float xv = xr[i];
        s[0] += xv * Wb[i];
        s[1] += xv * Wb[HID + i];
        s[2] += xv * Wb[2 * HID + i];
        s[3] += xv * Wb[3 * HID + i];
    }
#pragma unroll
    for (int off = 32; off; off >>= 1)
#pragma unroll
        for (int h = 0; h < 4; ++h) s[h] += __shfl_down(s[h], off);
    __shared__ float red[4][4];
    if (lane == 0)
#pragma unroll
        for (int h = 0; h < 4; ++h) red[wave][h] = s[h];
    __syncthreads();
    if (tid < 4) {
        float tot = red[0][tid] + red[1][tid] + red[2][tid] + red[3][tid];
        betaB[(size_t)t * 4 + tid] = 1.f / (1.f + expf(-tot));
    }
}

// ---------------- causal depthwise conv (KS=4) + silu + silu (+ per-head l2norm) ----------------
// out (f32 or bf16) optional; hi/lo bf16 split outputs optional.
template <typename OUT>
__global__ __launch_bounds__(256) void conv_kernel(const float* __restrict__ G,
                                                   const float* __restrict__ w,  // [HID][KS]
                                                   OUT* __restrict__ out, int do_norm,
                                                   unsigned short* __restrict__ hi,
                                                   unsigned short* __restrict__ lo) {
    const int bl = blockIdx.x;
    const int l = bl & (L_SEQ - 1);
    const int tid = threadIdx.x;
    const int wave = tid >> 6, lane = tid & 63;
    float vals[4];
#pragma unroll
    for (int h = 0; h < 4; ++h) {
        const int c = tid + 256 * h;
        float acc = 0.f;
#pragma unroll
        for (int j = 0; j < 4; ++j) {
            int ls = l - 3 + j;
            float xv = 0.f;
            if (ls >= 0) xv = G[(size_t)(bl - 3 + j) * HID + c];
            acc += xv * w[c * 4 + j];
        }
        float s1 = acc / (1.f + expf(-acc));
        float s2 = s1 / (1.f + expf(-s1));
        vals[h] = s2;
    }
    if (do_norm) {
        float sq[4];
#pragma unroll
        for (int h = 0; h < 4; ++h) sq[h] = vals[h] * vals[h];
#pragma unroll
        for (int off = 32; off; off >>= 1)
#pragma unroll
            for (int h = 0; h < 4; ++h) sq[h] += __shfl_down(sq[h], off);
        __shared__ float red[4][4];
        __shared__ float nrm[4];
        if (lane == 0)
#pragma unroll
            for (int h = 0; h < 4; ++h) red[wave][h] = sq[h];
        __syncthreads();
        if (tid < 4) {
            float tot = red[0][tid] + red[1][tid] + red[2][tid] + red[3][tid];
            nrm[tid] = 1.f / fmaxf(sqrtf(tot), 1e-12f);
        }
        __syncthreads();
#pragma unroll
        for (int h = 0; h < 4; ++h) vals[h] *= nrm[h];
    }
#pragma unroll
    for (int h = 0; h < 4; ++h) {
        const int c = tid + 256 * h;
        if (out) storev(&out[(size_t)bl * HID + c], vals[h]);
        if (hi) {
            unsigned short hv = f2bu(vals[h]);
            hi[(size_t)bl * HID + c] = hv;
            lo[(size_t)bl * HID + c] = f2bu(vals[h] - bu2f(hv));
        }
    }
}

// ---------------- per-chunk per-head gram: G_h = K_h * K_h^T (split-bf16 MFMA) ----------------
__global__ __launch_bounds__(256) void gram_kernel(const unsigned short* __restrict__ Khi,
                                                   const unsigned short* __restrict__ Klo,
                                                   float* __restrict__ Gg) {
    const int chunk = blockIdx.x;
    const int h = blockIdx.y;
    const int tid = threadIdx.x;
    const int wave = tid >> 6, lane = tid & 63;
    const int quad = lane >> 4, l16 = lane & 15;
    __shared__ unsigned short Hs[64 * 264];
    __shared__ unsigned short Ls[64 * 264];
    const int l0 = chunk * 64;
    const int cb = h * 256;
#pragma unroll
    for (int p = 0; p < 8; ++p) {
        int row = p * 8 + (tid >> 5);
        int col = (tid & 31) * 8;
        v8u hv = *(const v8u*)(Khi + (size_t)(l0 + row) * HID + cb + col);
        v8u lv = *(const v8u*)(Klo + (size_t)(l0 + row) * HID + cb + col);
        *(v8u*)&Hs[row * 264 + col] = hv;
        *(v8u*)&Ls[row * 264 + col] = lv;
    }
    __syncthreads();
    const int wm = wave * 16;
    v4f acc[4];
#pragma unroll
    for (int nt = 0; nt < 4; ++nt) { v4f z = {0.f, 0.f, 0.f, 0.f}; acc[nt] = z; }
#pragma unroll
    for (int ks = 0; ks < 8; ++ks) {
        v8s ah = *(const v8s*)&Hs[(wm + l16) * 264 + ks * 32 + quad * 8];
        v8s al = *(const v8s*)&Ls[(wm + l16) * 264 + ks * 32 + quad * 8];
#pragma unroll
        for (int nt = 0; nt < 4; ++nt) {
            v8s bh = *(const v8s*)&Hs[(nt * 16 + l16) * 264 + ks * 32 + quad * 8];
            v8s bl = *(const v8s*)&Ls[(nt * 16 + l16) * 264 + ks * 32 + quad * 8];
            acc[nt] = __builtin_amdgcn_mfma_f32_16x16x32_bf16(ah, bh, acc[nt], 0, 0, 0);
            acc[nt] = __builtin_amdgcn_mfma_f32_16x16x32_bf16(ah, bl, acc[nt], 0, 0, 0);
            acc[nt] = __builtin_amdgcn_mfma_f32_16x16x32_bf16(al, bh, acc[nt], 0, 0, 0);
        }
    }
    float* og = Gg + ((size_t)chunk * 4 + h) * 4096;
#pragma unroll
    for (int nt = 0; nt < 4; ++nt)
#pragma unroll
        for (int r = 0; r < 4; ++r)
            og[(wm + quad * 4 + r) * 64 + nt * 16 + l16] = acc[nt][r];
}

// ---------------- T recurrence per chunk (gram precomputed) ----------------
__global__ __launch_bounds__(256) void trec_kernel(const float* __restrict__ Gg,
                                                   const float* __restrict__ betaB,
                                                   float* __restrict__ Tg) {
    const int chunk = blockIdx.x;
    const int tid = threadIdx.x;
    __shared__ float Ts[64 * 65];
    __shared__ float betS[256];
    betS[tid] = betaB[(size_t)chunk * 256 + tid];
    __syncthreads();
    const float* gg = Gg + (size_t)chunk * 4 * 4096;
#pragma unroll
    for (int s = 0; s < 16; ++s) {
        int idx = tid + 256 * s;
        int i = idx >> 6, j = idx & 63;
        float v;
        if (i > j) {
            float t = betS[i * 4 + 0] * gg[idx] + betS[i * 4 + 1] * gg[4096 + idx] +
                      betS[i * 4 + 2] * gg[2 * 4096 + idx] + betS[i * 4 + 3] * gg[3 * 4096 + idx];
            v = -t;
        } else {
            v = (i == j) ? 1.f : 0.f;
        }
        Ts[i * 65 + j] = v;
    }
    __syncthreads();
    for (int i = 1; i < 64; ++i) {
        float v = 0.f;
        if (tid < i) {
            v = 2.f * Ts[i * 65 + tid];
            for (int j = 0; j < i; ++j) v += Ts[i * 65 + j] * Ts[j * 65 + tid];
        }
        __syncthreads();
        if (tid < i) Ts[i * 65 + tid] = v;
        __syncthreads();
    }
#pragma unroll
    for (int s = 0; s < 16; ++s) {
        int idx = tid + 256 * s;
        Tg[(size_t)chunk * 4096 + idx] = Ts[(idx >> 6) * 65 + (idx & 63)];
    }
}

// ---------------- W = T'·K, U = T'·V via MFMA (T' = T·diag(beta)); fused kw/ku ----------------
// B-operands are RAW Khi/Vhi (beta folded into T'). kw/ku diag dots reuse staged KT.
__global__ __launch_bounds__(256) void wu_mfma_kernel(const float* __restrict__ Tg,
                                                      const unsigned short* __restrict__ Khi,
                                                      const unsigned short* __restrict__ Vhi,
                                                      const float* __restrict__ betaB,
                                                      unsigned short* __restrict__ Wb,
                                                      unsigned short* __restrict__ Ub,
                                                      float* __restrict__ kw, float* __restrict__ ku) {
    const int chunk = blockIdx.x;  // 128
    const int h = blockIdx.y;      // 4
    const int half = blockIdx.z;   // 2
    const int tid = threadIdx.x;
    const int wave = tid >> 6, lane = tid & 63;
    const int quad = lane >> 4, l16 = lane & 15;
    const size_t l0 = (size_t)chunk * 64;
    const int f0 = h * 256 + half * 128;  // global feature base (128-wide slab)
    __shared__ unsigned short Th[64 * 72], Tl[64 * 72];   // T' split, [c][j], pitch 72 (144B, 16B-mult)
    __shared__ unsigned short KT[128 * 72], VT[128 * 72]; // K^T,V^T [f][j]
    __shared__ float betS[64];
    if (tid < 64) betS[tid] = betaB[(l0 + tid) * 4 + h];
    __syncthreads();
    // stage T' = T * diag(beta), split hi/lo
#pragma unroll
    for (int s = 0; s < 16; ++s) {
        int idx = tid + 256 * s;
        int c = idx >> 6, j = idx & 63;
        float v = Tg[(size_t)chunk * 4096 + idx] * betS[j];
        unsigned short hv = f2bu(v);
        Th[c * 72 + j] = hv;
        Tl[c * 72 + j] = f2bu(v - bu2f(hv));
    }
    // stage KT/VT transposed: [f][j]
#pragma unroll
    for (int pass = 0; pass < 4; ++pass) {
        int j = pass * 16 + (tid >> 4);
        int fc = (tid & 15) * 8;
        v8u kv = *(const v8u*)(Khi + (l0 + j) * HID + f0 + fc);
        v8u vv = *(const v8u*)(Vhi + (l0 + j) * HID + f0 + fc);
#pragma unroll
        for (int i = 0; i < 8; ++i) {
            KT[(fc + i) * 72 + j] = kv[i];
            VT[(fc + i) * 72 + j] = vv[i];
        }
    }
    __syncthreads();

    const int nf = wave * 32;  // this wave's 32-wide f sub-slab within the 128 slab
    const int bb = chunk >> 6, nn = chunk & 63;
    const size_t obase = (((size_t)bb * 4 + h) * 64 + nn) * 256 + half * 128;

    // ---- phase W (B = KT), then phase U (B = VT) ----
#pragma unroll
    for (int phase = 0; phase < 2; ++phase) {
        const unsigned short* BT = phase ? VT : KT;
        v4f acc[4][2];
#pragma unroll
        for (int mt = 0; mt < 4; ++mt)
#pragma unroll
            for (int nt = 0; nt < 2; ++nt) { v4f z = {0.f, 0.f, 0.f, 0.f}; acc[mt][nt] = z; }
#pragma unroll
        for (int k0 = 0; k0 < 64; k0 += 32) {
            v8s ah[4], al[4], bf[2];
#pragma unroll
            for (int mt = 0; mt < 4; ++mt) {
                ah[mt] = *(const v8s*)&Th[(mt * 16 + l16) * 72 + k0 + quad * 8];
                al[mt] = *(const v8s*)&Tl[(mt * 16 + l16) * 72 + k0 + quad * 8];
            }
#pragma unroll
            for (int nt = 0; nt < 2; ++nt)
                bf[nt] = *(const v8s*)&BT[(nf + nt * 16 + l16) * 72 + k0 + quad * 8];
#pragma unroll
            for (int mt = 0; mt < 4; ++mt)
#pragma unroll
                for (int nt = 0; nt < 2; ++nt) {
                    acc[mt][nt] = __builtin_amdgcn_mfma_f32_16x16x32_bf16(ah[mt], bf[nt], acc[mt][nt], 0, 0, 0);
                    acc[mt][nt] = __builtin_amdgcn_mfma_f32_16x16x32_bf16(al[mt], bf[nt], acc[mt][nt], 0, 0, 0);
                }
        }
        // write out + diagonal dot vs raw K (from KT)
        unsigned short* Out = phase ? Ub : Wb;
        float* kk = phase ? ku : kw;
#pragma unroll
        for (int nt = 0; nt < 2; ++nt) {
            const int fl = nf + nt * 16 + l16;      // f within 256-slab... within 128 slab
            float dot = 0.f;
#pragma unroll
            for (int mt = 0; mt < 4; ++mt)
#pragma unroll
                for (int r = 0; r < 4; ++r) {
                    const int c = mt * 16 + quad * 4 + r;
                    float wv = acc[mt][nt][r];
                    Out[(l0 + c) * HID + f0 + fl] = f2bu(wv);
                    dot += bu2f(KT[fl * 72 + c]) * wv;
                }
            dot += __shfl_xor(dot, 16);
            dot += __shfl_xor(dot, 32);
            if (quad == 0) kk[obase + fl] = dot;
        }
    }
}

// ---------------- diagonal scan over chunks ----------------
__global__ __launch_bounds__(256) void scan_kernel(const float* __restrict__ kw,
                                                   const float* __restrict__ ku,
                                                   float* __restrict__ dsA) {
    const int bh = blockIdx.x;
    const int e = threadIdx.x;
    float ds = 0.f;
    for (int n = 0; n < 64; ++n) {
        size_t idx = ((size_t)bh * 64 + n) * 256 + e;
        dsA[idx] = ds;
        ds = ds * (1.f - kw[idx]) + ku[idx];
    }
}

__device__ __forceinline__ float block_sum(float v, float* red) {
#pragma unroll
    for (int off = 32; off; off >>= 1) v += __shfl_down(v, off);
    const int wave = threadIdx.x >> 6;
    if ((threadIdx.x & 63) == 0) red[wave] = v;
    __syncthreads();
    float t = red[0] + red[1] + red[2] + red[3];
    __syncthreads();
    return t;
}

// ---------------- o = q*ds + [c<=b]*A*(u - w*ds); fused RMSNorm + bf16 cast ----------------
__global__ __launch_bounds__(256) void o_kernel(const __hip_bfloat16* __restrict__ Qb,
                                                const unsigned short* __restrict__ Khi,
                                                const unsigned short* __restrict__ Wb,
                                                const unsigned short* __restrict__ Ub,
                                                const float* __restrict__ dsA,
                                                const float* __restrict__ rmsw,
                                                __hip_bfloat16* __restrict__ ob,
                                                unsigned short* __restrict__ ub) {
    const int bl = blockIdx.x;
    const int b = bl >> 12, l = bl & (L_SEQ - 1);
    const int n = l >> 6, cpos = l & 63;
    const int tid = threadIdx.x;
    __shared__ float red[4];
    const size_t rowb = (size_t)bl * HID;
    float dsv[4], qv[4], ov[4];
#pragma unroll
    for (int h = 0; h < 4; ++h) {
        dsv[h] = dsA[(((size_t)b * 4 + h) * 64 + n) * 256 + tid];
        qv[h] = __bfloat162float(Qb[rowb + tid + 256 * h]);
    }
    const bool doA = (cpos <= b);
    float Aval = 0.f;
    if (doA) {
        float s = 0.f;
#pragma unroll
        for (int h = 0; h < 4; ++h) s += qv[h] * bu2f(Khi[rowb + tid + 256 * h]);
        Aval = block_sum(s, red);
    }
    float ss = 0.f;
#pragma unroll
    for (int h = 0; h < 4; ++h) {
        int c = tid + 256 * h;
        float u = bu2f(Ub[rowb + c]) - bu2f(Wb[rowb + c]) * dsv[h];
        ub[rowb + c] = f2bu(u);
        float o = qv[h] * dsv[h];
        if (doA) o += Aval * u;
        ov[h] = o;
        ss += o * o;
    }
    float tot = block_sum(ss, red);
    float scale = rsqrtf(tot * (1.f / 1024.f) + 1e-5f);
#pragma unroll
    for (int h = 0; h < 4; ++h) {
        int c = tid + 256 * h;
        ob[rowb + c] = __float2bfloat16(ov[h] * scale * rmsw[c]);
    }
}

// ---------------- state S = K^T u'  via MFMA (n-split partials) ----------------
#define SNS 16
__global__ __launch_bounds__(256) void s_mfma_kernel(const unsigned short* __restrict__ Khi,
                                                     const unsigned short* __restrict__ Ub,
                                                     float* __restrict__ Spart) {
    const int bh = blockIdx.x;
    const int b = bh >> 2, h = bh & 3;
    const int dt = blockIdx.y;
    const int et = blockIdx.z & 1;
    const int ns = blockIdx.z >> 1;
    const int tid = threadIdx.x;
    const int wave = tid >> 6, lane = tid & 63;
    const int quad = lane >> 4, l16 = lane & 15;
    const int wm = (wave >> 1) * 64, wn = (wave & 1) * 64;
    __shared__ unsigned short Kt[128 * 40];
    __shared__ unsigned short Ut[128 * 40];
    const int cc = tid >> 3;
    const int dcol = (tid & 7) * 16;
    const size_t rowbase = (size_t)b * 4096 + (size_t)ns * 256;
    const int ck = h * 256 + dt * 128;
    const int ce = h * 256 + et * 128;
    v4f acc[4][4];
#pragma unroll
    for (int a = 0; a < 4; ++a)
#pragma unroll
        for (int c2 = 0; c2 < 4; ++c2) { v4f z = {0.f, 0.f, 0.f, 0.f}; acc[a][c2] = z; }

    for (int kt = 0; kt < 8; ++kt) {
        size_t row = rowbase + kt * 32 + cc;
        v8u k0 = *(const v8u*)(Khi + row * HID + ck + dcol);
        v8u k1 = *(const v8u*)(Khi + row * HID + ck + dcol + 8);
        v8u u0 = *(const v8u*)(Ub + row * HID + ce + dcol);
        v8u u1 = *(const v8u*)(Ub + row * HID + ce + dcol + 8);
        __syncthreads();
#pragma unroll
        for (int j = 0; j < 8; ++j) {
            Kt[(dcol + j) * 40 + cc] = k0[j];
            Kt[(dcol + 8 + j) * 40 + cc] = k1[j];
            Ut[(dcol + j) * 40 + cc] = u0[j];
            Ut[(dcol + 8 + j) * 40 + cc] = u1[j];
        }
        __syncthreads();
        v8s af[4], bf[4];
#pragma unroll
        for (int mt = 0; mt < 4; ++mt) af[mt] = *(const v8s*)&Kt[(wm + mt * 16 + l16) * 40 + quad * 8];
#pragma unroll
        for (int nt = 0; nt < 4; ++nt) bf[nt] = *(const v8s*)&Ut[(wn + nt * 16 + l16) * 40 + quad * 8];
#pragma unroll
        for (int mt = 0; mt < 4; ++mt)
#pragma unroll
            for (int nt = 0; nt < 4; ++nt)
                acc[mt][nt] = __builtin_amdgcn_mfma_f32_16x16x32_bf16(af[mt], bf[nt], acc[mt][nt], 0, 0, 0);
    }
    float* out = Spart + (size_t)ns * (8 * 256 * 256);
#pragma unroll
    for (int mt = 0; mt < 4; ++mt)
#pragma unroll
        for (int nt = 0; nt < 4; ++nt) {
            int row = dt * 128 + wm + mt * 16 + quad * 4;
            int col = et * 128 + wn + nt * 16 + l16;
#pragma unroll
            for (int r = 0; r < 4; ++r)
                out[((size_t)bh * 256 + row + r) * 256 + col] = acc[mt][nt][r];
        }
}

// ---------------- reduce SNS partials -> out1 ----------------
__global__ __launch_bounds__(256) void sreduce_kernel(const float* __restrict__ Spart,
                                                      float* __restrict__ out) {
    int i = blockIdx.x * 256 + threadIdx.x;
    float s = 0.f;
#pragma unroll
    for (int ns = 0; ns < SNS; ++ns) s += Spart[(size_t)ns * (8 * 256 * 256) + i];
    out[i] = s;
}

extern "C" void kernel_launch(void* const* d_in, const int* in_sizes, int n_in,
                              void* d_out, int out_size, void* d_ws, size_t ws_size,
                              hipStream_t stream) {
    const float* x     = (const float*)d_in[0];
    const float* Wq    = (const float*)d_in[1];
    const float* Wk    = (const float*)d_in[2];
    const float* Wv    = (const float*)d_in[3];
    const float* convq = (const float*)d_in[4];
    const float* convk = (const float*)d_in[5];
    const float* convv = (const float*)d_in[6];
    const float* Wbeta = (const float*)d_in[7];
    const float* rmsw  = (const float*)d_in[8];
    const float* Wo    = (const float*)d_in[9];

    // ---- workspace map (~125 MiB; aliases documented) ----
    char* ws = (char*)d_ws;
    size_t off = 0;
    auto alloc = [&](size_t bytes) {
        char* p = ws + off;
        off += (bytes + 255) & ~(size_t)255;
        return (void*)p;
    };
    unsigned short* xhi  = (unsigned short*)alloc((size_t)BL_TOT * HID * 2);  // later Qm/ob
    unsigned short* xlo  = (unsigned short*)alloc((size_t)BL_TOT * HID * 2);  // later Khi (lives to s_mfma)
    unsigned short* whi  = (unsigned short*)alloc((size_t)HID * HID * 2);
    unsigned short* wlo  = (unsigned short*)alloc((size_t)HID * HID * 2);
    float*          Gt   = (float*)alloc((size_t)BL_TOT * HID * 4);  // gemm out; later Spart
    unsigned short* Vhi  = (unsigned short*)alloc((size_t)BL_TOT * HID * 2);
    unsigned short* Wb16 = (unsigned short*)alloc((size_t)BL_TOT * HID * 2);
    unsigned short* Ub16 = (unsigned short*)alloc((size_t)BL_TOT * HID * 2);
    float* Tg    = (float*)alloc((size_t)128 * 4096 * 4);
    float* betaB = (float*)alloc((size_t)BL_TOT * 4 * 4);
    float* kwB   = (float*)alloc((size_t)8 * 64 * 256 * 4);
    float* kuB   = (float*)alloc((size_t)8 * 64 * 256 * 4);
    float* dsA   = (float*)alloc((size_t)8 * 64 * 256 * 4);
    __hip_bfloat16* Qm = (__hip_bfloat16*)xhi;  // xhi dead after Q GEMM (last x-GEMM)
    __hip_bfloat16* ob = Qm;                    // q dead after o_kernel reads its own row
    unsigned short* Khi = xlo;                  // x_lo dead after K GEMM
    float* Spart = Gt;                          // Gt dead after conv_q; SNS*8*256*256*4 = Gt size

    float* out0 = (float*)d_out;
    float* out1 = out0 + (size_t)BL_TOT * HID;
    // d_out as pre-final scratch (validated only after launch):
    unsigned short* Klo = (unsigned short*)out0;            // bytes 0..16.78M
    unsigned short* ubf = (unsigned short*)out0 + 8388608;  // bytes 16.78M..33.55M
    float* Gg = out0 + (size_t)4400000;                     // gram scratch; dead before o_kernel

    dim3 blk(256);
    dim3 ggrid(BL_TOT / 128, HID / 128);
    const int NTOK = BL_TOT * HID;

    split_kernel<<<4096, blk, 0, stream>>>(x, xhi, xlo, NTOK);
    beta_kernel<<<BL_TOT, blk, 0, stream>>>(x, Wbeta, betaB);

    // V path (plain bf16; emits bf16 only)
    f2b_kernel<<<1024, blk, 0, stream>>>(Wv, whi, HID * HID);
    gemm_mfma<0><<<ggrid, blk, 0, stream>>>(xhi, nullptr, whi, nullptr, Gt, BL_TOT, HID, HID);
    conv_kernel<__hip_bfloat16><<<BL_TOT, blk, 0, stream>>>(Gt, convv, (__hip_bfloat16*)Vhi, 0, nullptr, nullptr);
    // K path (split GEMM -> ~f32 into conv; conv emits bf16 hi/lo only)
    split_kernel<<<1024, blk, 0, stream>>>(Wk, whi, wlo, HID * HID);
    gemm_mfma<1><<<ggrid, blk, 0, stream>>>(xhi, xlo, whi, wlo, Gt, BL_TOT, HID, HID);
    conv_kernel<float><<<BL_TOT, blk, 0, stream>>>(Gt, convk, (float*)nullptr, 1, Khi, Klo);
    // gram + T recurrence
    gram_kernel<<<dim3(128, 4), blk, 0, stream>>>(Khi, Klo, Gg);
    trec_kernel<<<128, blk, 0, stream>>>(Gg, betaB, Tg);
    // Q path (plain bf16)
    f2b_kernel<<<1024, blk, 0, stream>>>(Wq, whi, HID * HID);
    gemm_mfma<0><<<ggrid, blk, 0, stream>>>(xhi, nullptr, whi, nullptr, Gt, BL_TOT, HID, HID);
    conv_kernel<__hip_bfloat16><<<BL_TOT, blk, 0, stream>>>(Gt, convq, Qm, 1, nullptr, nullptr);

    // chunked delta rule
    wu_mfma_kernel<<<dim3(128, 4, 2), blk, 0, stream>>>(Tg, Khi, Vhi, betaB, Wb16, Ub16, kwB, kuB);
    scan_kernel<<<8, blk, 0, stream>>>(kwB, kuB, dsA);
    o_kernel<<<BL_TOT, blk, 0, stream>>>(Qm, Khi, Wb16, Ub16, dsA, rmsw, ob, ubf);
    s_mfma_kernel<<<dim3(8, 2, 2 * SNS), blk, 0, stream>>>(Khi, ubf, Spart);
    sreduce_kernel<<<2048, blk, 0, stream>>>(Spart, out1);

    // final projection: o(bf16) @ Wo^T -> f32 out0 (overwrites Klo/ubf scratch)
    f2b_kernel<<<1024, blk, 0, stream>>>(Wo, whi, HID * HID);
    gemm_mfma<0><<<ggrid, blk, 0, stream>>>((const unsigned short*)ob, nullptr, whi, nullptr,
                                            out0, BL_TOT, HID, HID);
}

// Round 9
// 453.317 us; speedup vs baseline: 4.3782x; 1.0941x over previous
//
#include <hip/hip_runtime.h>
#include <hip/hip_bf16.h>

#define L_SEQ 4096
#define HID 1024
#define NH 4
#define DH 256
#define CK 64
#define BL_TOT 8192   // B*L

typedef short v8s __attribute__((ext_vector_type(8)));
typedef unsigned short v8u __attribute__((ext_vector_type(8)));
typedef float v4f __attribute__((ext_vector_type(4)));

__device__ __forceinline__ void storev(float* p, float v) { *p = v; }
__device__ __forceinline__ void storev(__hip_bfloat16* p, float v) { *p = __float2bfloat16(v); }

__device__ __forceinline__ unsigned short f2bu(float f) {
    __hip_bfloat16 h = __float2bfloat16(f);
    return *(unsigned short*)&h;
}
__device__ __forceinline__ float bu2f(unsigned short u) {
    __hip_bfloat16 h = *(__hip_bfloat16*)&u;
    return __bfloat162float(h);
}

// ---------------- all-weights f32 -> bf16 in one dispatch ----------------
__global__ __launch_bounds__(256) void wcvt_kernel(const float* __restrict__ s0, const float* __restrict__ s1,
                                                   const float* __restrict__ s2, const float* __restrict__ s3,
                                                   unsigned short* __restrict__ d0, unsigned short* __restrict__ d1,
                                                   unsigned short* __restrict__ d2, unsigned short* __restrict__ d3) {
    const float* s = blockIdx.y == 0 ? s0 : blockIdx.y == 1 ? s1 : blockIdx.y == 2 ? s2 : s3;
    unsigned short* d = blockIdx.y == 0 ? d0 : blockIdx.y == 1 ? d1 : blockIdx.y == 2 ? d2 : d3;
    int i = blockIdx.x * 256 + threadIdx.x;
    int stride = gridDim.x * 256;
    for (; i < HID * HID; i += stride) d[i] = f2bu(s[i]);
}

// ---------------- MFMA bf16 GEMM: C[M,N] = A[M,K] * B[N,K]^T  (f32 out) ----------------
__global__ __launch_bounds__(256) void gemm_mfma(const unsigned short* __restrict__ Ah,
                                                 const unsigned short* __restrict__ Bh,
                                                 float* __restrict__ C, int M, int N, int K) {
    __shared__ unsigned short AsH[128 * 40];
    __shared__ unsigned short BsH[128 * 40];
    const int tid = threadIdx.x;
    const int wave = tid >> 6, lane = tid & 63;
    const int quad = lane >> 4, l16 = lane & 15;
    const int m0 = blockIdx.x * 128, n0 = blockIdx.y * 128;
    const int wm = (wave >> 1) * 64, wn = (wave & 1) * 64;
    const int r0 = tid >> 2;
    const int kk = (tid & 3) * 8;

    v4f acc[4][4];
#pragma unroll
    for (int a = 0; a < 4; ++a)
#pragma unroll
        for (int b = 0; b < 4; ++b) { v4f z = {0.f, 0.f, 0.f, 0.f}; acc[a][b] = z; }

    for (int k0 = 0; k0 < K; k0 += 32) {
        v8u ah0 = *(const v8u*)(Ah + (size_t)(m0 + r0) * K + k0 + kk);
        v8u ah1 = *(const v8u*)(Ah + (size_t)(m0 + r0 + 64) * K + k0 + kk);
        v8u bh0 = *(const v8u*)(Bh + (size_t)(n0 + r0) * K + k0 + kk);
        v8u bh1 = *(const v8u*)(Bh + (size_t)(n0 + r0 + 64) * K + k0 + kk);
        __syncthreads();
        *(v8u*)&AsH[r0 * 40 + kk] = ah0;
        *(v8u*)&AsH[(r0 + 64) * 40 + kk] = ah1;
        *(v8u*)&BsH[r0 * 40 + kk] = bh0;
        *(v8u*)&BsH[(r0 + 64) * 40 + kk] = bh1;
        __syncthreads();
        v8s afh[4], bfh[4];
#pragma unroll
        for (int mt = 0; mt < 4; ++mt) afh[mt] = *(const v8s*)&AsH[(wm + mt * 16 + l16) * 40 + quad * 8];
#pragma unroll
        for (int nt = 0; nt < 4; ++nt) bfh[nt] = *(const v8s*)&BsH[(wn + nt * 16 + l16) * 40 + quad * 8];
#pragma unroll
        for (int mt = 0; mt < 4; ++mt)
#pragma unroll
            for (int nt = 0; nt < 4; ++nt)
                acc[mt][nt] = __builtin_amdgcn_mfma_f32_16x16x32_bf16(afh[mt], bfh[nt], acc[mt][nt], 0, 0, 0);
    }
#pragma unroll
    for (int mt = 0; mt < 4; ++mt)
#pragma unroll
        for (int nt = 0; nt < 4; ++nt) {
            int row = m0 + wm + mt * 16 + quad * 4;
            int col = n0 + wn + nt * 16 + l16;
#pragma unroll
            for (int r = 0; r < 4; ++r)
                C[(size_t)(row + r) * N + col] = acc[mt][nt][r];
        }
}

// ---------------- beta = sigmoid(x @ Wbeta^T); fused x -> bf16 ----------------
__global__ __launch_bounds__(256) void beta_kernel(const float* __restrict__ x,
                                                   const float* __restrict__ Wb,
                                                   float* __restrict__ betaB,
                                                   unsigned short* __restrict__ xh) {
    const int t = blockIdx.x;
    const int tid = threadIdx.x;
    const int wave = tid >> 6, lane = tid & 63;
    const float* xr = x + (size_t)t * HID;
    float s[4] = {0.f, 0.f, 0.f, 0.f};
    for (int i = tid; i < HID; i += 256) {
        float xv = xr[i];
        xh[(size_t)t * HID + i] = f2bu(xv);
        s[0] += xv * Wb[i];
        s[1] += xv * Wb[HID + i];
        s[2] += xv * Wb[2 * HID + i];
        s[3] += xv * Wb[3 * HID + i];
    }
#pragma unroll
    for (int off = 32; off; off >>= 1)
#pragma unroll
        for (int h = 0; h < 4; ++h) s[h] += __shfl_down(s[h], off);
    __shared__ float red[4][4];
    if (lane == 0)
#pragma unroll
        for (int h = 0; h < 4; ++h) red[wave][h] = s[h];
    __syncthreads();
    if (tid < 4) {
        float tot = red[0][tid] + red[1][tid] + red[2][tid] + red[3][tid];
        betaB[(size_t)t * 4 + tid] = 1.f / (1.f + expf(-tot));
    }
}

// ---------------- causal depthwise conv (KS=4) + silu + silu (+ per-head l2norm) ----------------
template <typename OUT>
__global__ __launch_bounds__(256) void conv_kernel(const float* __restrict__ G,
                                                   const float* __restrict__ w,  // [HID][KS]
                                                   OUT* __restrict__ out, int do_norm,
                                                   unsigned short* __restrict__ hi,
                                                   unsigned short* __restrict__ lo) {
    const int bl = blockIdx.x;
    const int l = bl & (L_SEQ - 1);
    const int tid = threadIdx.x;
    const int wave = tid >> 6, lane = tid & 63;
    float vals[4];
#pragma unroll
    for (int h = 0; h < 4; ++h) {
        const int c = tid + 256 * h;
        float acc = 0.f;
#pragma unroll
        for (int j = 0; j < 4; ++j) {
            int ls = l - 3 + j;
            float xv = 0.f;
            if (ls >= 0) xv = G[(size_t)(bl - 3 + j) * HID + c];
            acc += xv * w[c * 4 + j];
        }
        float s1 = acc / (1.f + expf(-acc));
        float s2 = s1 / (1.f + expf(-s1));
        vals[h] = s2;
    }
    if (do_norm) {
        float sq[4];
#pragma unroll
        for (int h = 0; h < 4; ++h) sq[h] = vals[h] * vals[h];
#pragma unroll
        for (int off = 32; off; off >>= 1)
#pragma unroll
            for (int h = 0; h < 4; ++h) sq[h] += __shfl_down(sq[h], off);
        __shared__ float red[4][4];
        __shared__ float nrm[4];
        if (lane == 0)
#pragma unroll
            for (int h = 0; h < 4; ++h) red[wave][h] = sq[h];
        __syncthreads();
        if (tid < 4) {
            float tot = red[0][tid] + red[1][tid] + red[2][tid] + red[3][tid];
            nrm[tid] = 1.f / fmaxf(sqrtf(tot), 1e-12f);
        }
        __syncthreads();
#pragma unroll
        for (int h = 0; h < 4; ++h) vals[h] *= nrm[h];
    }
#pragma unroll
    for (int h = 0; h < 4; ++h) {
        const int c = tid + 256 * h;
        if (out) storev(&out[(size_t)bl * HID + c], vals[h]);
        if (hi) {
            unsigned short hv = f2bu(vals[h]);
            hi[(size_t)bl * HID + c] = hv;
            lo[(size_t)bl * HID + c] = f2bu(vals[h] - bu2f(hv));
        }
    }
}

// ---------------- per-chunk per-head gram: G_h = K_h * K_h^T (split-bf16 MFMA) ----------------
__global__ __launch_bounds__(256) void gram_kernel(const unsigned short* __restrict__ Khi,
                                                   const unsigned short* __restrict__ Klo,
                                                   float* __restrict__ Gg) {
    const int chunk = blockIdx.x;
    const int h = blockIdx.y;
    const int tid = threadIdx.x;
    const int wave = tid >> 6, lane = tid & 63;
    const int quad = lane >> 4, l16 = lane & 15;
    __shared__ unsigned short Hs[64 * 264];
    __shared__ unsigned short Ls[64 * 264];
    const int l0 = chunk * 64;
    const int cb = h * 256;
#pragma unroll
    for (int p = 0; p < 8; ++p) {
        int row = p * 8 + (tid >> 5);
        int col = (tid & 31) * 8;
        v8u hv = *(const v8u*)(Khi + (size_t)(l0 + row) * HID + cb + col);
        v8u lv = *(const v8u*)(Klo + (size_t)(l0 + row) * HID + cb + col);
        *(v8u*)&Hs[row * 264 + col] = hv;
        *(v8u*)&Ls[row * 264 + col] = lv;
    }
    __syncthreads();
    const int wm = wave * 16;
    v4f acc[4];
#pragma unroll
    for (int nt = 0; nt < 4; ++nt) { v4f z = {0.f, 0.f, 0.f, 0.f}; acc[nt] = z; }
#pragma unroll
    for (int ks = 0; ks < 8; ++ks) {
        v8s ah = *(const v8s*)&Hs[(wm + l16) * 264 + ks * 32 + quad * 8];
        v8s al = *(const v8s*)&Ls[(wm + l16) * 264 + ks * 32 + quad * 8];
#pragma unroll
        for (int nt = 0; nt < 4; ++nt) {
            v8s bh = *(const v8s*)&Hs[(nt * 16 + l16) * 264 + ks * 32 + quad * 8];
            v8s bl = *(const v8s*)&Ls[(nt * 16 + l16) * 264 + ks * 32 + quad * 8];
            acc[nt] = __builtin_amdgcn_mfma_f32_16x16x32_bf16(ah, bh, acc[nt], 0, 0, 0);
            acc[nt] = __builtin_amdgcn_mfma_f32_16x16x32_bf16(ah, bl, acc[nt], 0, 0, 0);
            acc[nt] = __builtin_amdgcn_mfma_f32_16x16x32_bf16(al, bh, acc[nt], 0, 0, 0);
        }
    }
    float* og = Gg + ((size_t)chunk * 4 + h) * 4096;
#pragma unroll
    for (int nt = 0; nt < 4; ++nt)
#pragma unroll
        for (int r = 0; r < 4; ++r)
            og[(wm + quad * 4 + r) * 64 + nt * 16 + l16] = acc[nt][r];
}

// ---------------- T recurrence per chunk (gram precomputed) ----------------
__global__ __launch_bounds__(256) void trec_kernel(const float* __restrict__ Gg,
                                                   const float* __restrict__ betaB,
                                                   float* __restrict__ Tg) {
    const int chunk = blockIdx.x;
    const int tid = threadIdx.x;
    __shared__ float Ts[64 * 65];
    __shared__ float betS[256];
    betS[tid] = betaB[(size_t)chunk * 256 + tid];
    __syncthreads();
    const float* gg = Gg + (size_t)chunk * 4 * 4096;
#pragma unroll
    for (int s = 0; s < 16; ++s) {
        int idx = tid + 256 * s;
        int i = idx >> 6, j = idx & 63;
        float v;
        if (i > j) {
            float t = betS[i * 4 + 0] * gg[idx] + betS[i * 4 + 1] * gg[4096 + idx] +
                      betS[i * 4 + 2] * gg[2 * 4096 + idx] + betS[i * 4 + 3] * gg[3 * 4096 + idx];
            v = -t;
        } else {
            v = (i == j) ? 1.f : 0.f;
        }
        Ts[i * 65 + j] = v;
    }
    __syncthreads();
    for (int i = 1; i < 64; ++i) {
        float v = 0.f;
        if (tid < i) {
            v = 2.f * Ts[i * 65 + tid];
            for (int j = 0; j < i; ++j) v += Ts[i * 65 + j] * Ts[j * 65 + tid];
        }
        __syncthreads();
        if (tid < i) Ts[i * 65 + tid] = v;
        __syncthreads();
    }
#pragma unroll
    for (int s = 0; s < 16; ++s) {
        int idx = tid + 256 * s;
        Tg[(size_t)chunk * 4096 + idx] = Ts[(idx >> 6) * 65 + (idx & 63)];
    }
}

// ---------------- W = T'·K, U = T'·V via MFMA (T' = T·diag(beta)); fused kw/ku ----------------
__global__ __launch_bounds__(256) void wu_mfma_kernel(const float* __restrict__ Tg,
                                                      const unsigned short* __restrict__ Khi,
                                                      const unsigned short* __restrict__ Vhi,
                                                      const float* __restrict__ betaB,
                                                      unsigned short* __restrict__ Wb,
                                                      unsigned short* __restrict__ Ub,
                                                      float* __restrict__ kw, float* __restrict__ ku) {
    const int chunk = blockIdx.x;  // 128
    const int h = blockIdx.y;      // 4
    const int half = blockIdx.z;   // 2
    const int tid = threadIdx.x;
    const int wave = tid >> 6, lane = tid & 63;
    const int quad = lane >> 4, l16 = lane & 15;
    const size_t l0 = (size_t)chunk * 64;
    const int f0 = h * 256 + half * 128;
    __shared__ unsigned short Th[64 * 72], Tl[64 * 72];
    __shared__ unsigned short KT[128 * 72], VT[128 * 72];
    __shared__ float betS[64];
    if (tid < 64) betS[tid] = betaB[(l0 + tid) * 4 + h];
    __syncthreads();
#pragma unroll
    for (int s = 0; s < 16; ++s) {
        int idx = tid + 256 * s;
        int c = idx >> 6, j = idx & 63;
        float v = Tg[(size_t)chunk * 4096 + idx] * betS[j];
        unsigned short hv = f2bu(v);
        Th[c * 72 + j] = hv;
        Tl[c * 72 + j] = f2bu(v - bu2f(hv));
    }
#pragma unroll
    for (int pass = 0; pass < 4; ++pass) {
        int j = pass * 16 + (tid >> 4);
        int fc = (tid & 15) * 8;
        v8u kv = *(const v8u*)(Khi + (l0 + j) * HID + f0 + fc);
        v8u vv = *(const v8u*)(Vhi + (l0 + j) * HID + f0 + fc);
#pragma unroll
        for (int i = 0; i < 8; ++i) {
            KT[(fc + i) * 72 + j] = kv[i];
            VT[(fc + i) * 72 + j] = vv[i];
        }
    }
    __syncthreads();

    const int nf = wave * 32;
    const int bb = chunk >> 6, nn = chunk & 63;
    const size_t obase = (((size_t)bb * 4 + h) * 64 + nn) * 256 + half * 128;

#pragma unroll
    for (int phase = 0; phase < 2; ++phase) {
        const unsigned short* BT = phase ? VT : KT;
        v4f acc[4][2];
#pragma unroll
        for (int mt = 0; mt < 4; ++mt)
#pragma unroll
            for (int nt = 0; nt < 2; ++nt) { v4f z = {0.f, 0.f, 0.f, 0.f}; acc[mt][nt] = z; }
#pragma unroll
        for (int k0 = 0; k0 < 64; k0 += 32) {
            v8s ah[4], al[4], bf[2];
#pragma unroll
            for (int mt = 0; mt < 4; ++mt) {
                ah[mt] = *(const v8s*)&Th[(mt * 16 + l16) * 72 + k0 + quad * 8];
                al[mt] = *(const v8s*)&Tl[(mt * 16 + l16) * 72 + k0 + quad * 8];
            }
#pragma unroll
            for (int nt = 0; nt < 2; ++nt)
                bf[nt] = *(const v8s*)&BT[(nf + nt * 16 + l16) * 72 + k0 + quad * 8];
#pragma unroll
            for (int mt = 0; mt < 4; ++mt)
#pragma unroll
                for (int nt = 0; nt < 2; ++nt) {
                    acc[mt][nt] = __builtin_amdgcn_mfma_f32_16x16x32_bf16(ah[mt], bf[nt], acc[mt][nt], 0, 0, 0);
                    acc[mt][nt] = __builtin_amdgcn_mfma_f32_16x16x32_bf16(al[mt], bf[nt], acc[mt][nt], 0, 0, 0);
                }
        }
        unsigned short* Out = phase ? Ub : Wb;
        float* kk = phase ? ku : kw;
#pragma unroll
        for (int nt = 0; nt < 2; ++nt) {
            const int fl = nf + nt * 16 + l16;
            float dot = 0.f;
#pragma unroll
            for (int mt = 0; mt < 4; ++mt)
#pragma unroll
                for (int r = 0; r < 4; ++r) {
                    const int c = mt * 16 + quad * 4 + r;
                    float wv = acc[mt][nt][r];
                    Out[(l0 + c) * HID + f0 + fl] = f2bu(wv);
                    dot += bu2f(KT[fl * 72 + c]) * wv;
                }
            dot += __shfl_xor(dot, 16);
            dot += __shfl_xor(dot, 32);
            if (quad == 0) kk[obase + fl] = dot;
        }
    }
}

// ---------------- diagonal scan over chunks ----------------
__global__ __launch_bounds__(256) void scan_kernel(const float* __restrict__ kw,
                                                   const float* __restrict__ ku,
                                                   float* __restrict__ dsA) {
    const int bh = blockIdx.x;
    const int e = threadIdx.x;
    float ds = 0.f;
    for (int n = 0; n < 64; ++n) {
        size_t idx = ((size_t)bh * 64 + n) * 256 + e;
        dsA[idx] = ds;
        ds = ds * (1.f - kw[idx]) + ku[idx];
    }
}

__device__ __forceinline__ float block_sum(float v, float* red) {
#pragma unroll
    for (int off = 32; off; off >>= 1) v += __shfl_down(v, off);
    const int wave = threadIdx.x >> 6;
    if ((threadIdx.x & 63) == 0) red[wave] = v;
    __syncthreads();
    float t = red[0] + red[1] + red[2] + red[3];
    __syncthreads();
    return t;
}

// ---------------- o = q*ds + [c<=b]*A*(u - w*ds); fused RMSNorm + bf16 cast ----------------
__global__ __launch_bounds__(256) void o_kernel(const __hip_bfloat16* __restrict__ Qb,
                                                const unsigned short* __restrict__ Khi,
                                                const unsigned short* __restrict__ Wb,
                                                const unsigned short* __restrict__ Ub,
                                                const float* __restrict__ dsA,
                                                const float* __restrict__ rmsw,
                                                __hip_bfloat16* __restrict__ ob,
                                                unsigned short* __restrict__ ub) {
    const int bl = blockIdx.x;
    const int b = bl >> 12, l = bl & (L_SEQ - 1);
    const int n = l >> 6, cpos = l & 63;
    const int tid = threadIdx.x;
    __shared__ float red[4];
    const size_t rowb = (size_t)bl * HID;
    float dsv[4], qv[4], ov[4];
#pragma unroll
    for (int h = 0; h < 4; ++h) {
        dsv[h] = dsA[(((size_t)b * 4 + h) * 64 + n) * 256 + tid];
        qv[h] = __bfloat162float(Qb[rowb + tid + 256 * h]);
    }
    const bool doA = (cpos <= b);
    float Aval = 0.f;
    if (doA) {
        float s = 0.f;
#pragma unroll
        for (int h = 0; h < 4; ++h) s += qv[h] * bu2f(Khi[rowb + tid + 256 * h]);
        Aval = block_sum(s, red);
    }
    float ss = 0.f;
#pragma unroll
    for (int h = 0; h < 4; ++h) {
        int c = tid + 256 * h;
        float u = bu2f(Ub[rowb + c]) - bu2f(Wb[rowb + c]) * dsv[h];
        ub[rowb + c] = f2bu(u);
        float o = qv[h] * dsv[h];
        if (doA) o += Aval * u;
        ov[h] = o;
        ss += o * o;
    }
    float tot = block_sum(ss, red);
    float scale = rsqrtf(tot * (1.f / 1024.f) + 1e-5f);
#pragma unroll
    for (int h = 0; h < 4; ++h) {
        int c = tid + 256 * h;
        ob[rowb + c] = __float2bfloat16(ov[h] * scale * rmsw[c]);
    }
}

// ---------------- state S = K^T u'  via MFMA (n-split partials) ----------------
#define SNS 16
__global__ __launch_bounds__(256) void s_mfma_kernel(const unsigned short* __restrict__ Khi,
                                                     const unsigned short* __restrict__ Ub,
                                                     float* __restrict__ Spart) {
    const int bh = blockIdx.x;
    const int b = bh >> 2, h = bh & 3;
    const int dt = blockIdx.y;
    const int et = blockIdx.z & 1;
    const int ns = blockIdx.z >> 1;
    const int tid = threadIdx.x;
    const int wave = tid >> 6, lane = tid & 63;
    const int quad = lane >> 4, l16 = lane & 15;
    const int wm = (wave >> 1) * 64, wn = (wave & 1) * 64;
    __shared__ unsigned short Kt[128 * 40];
    __shared__ unsigned short Ut[128 * 40];
    const int cc = tid >> 3;
    const int dcol = (tid & 7) * 16;
    const size_t rowbase = (size_t)b * 4096 + (size_t)ns * 256;
    const int ck = h * 256 + dt * 128;
    const int ce = h * 256 + et * 128;
    v4f acc[4][4];
#pragma unroll
    for (int a = 0; a < 4; ++a)
#pragma unroll
        for (int c2 = 0; c2 < 4; ++c2) { v4f z = {0.f, 0.f, 0.f, 0.f}; acc[a][c2] = z; }

    for (int kt = 0; kt < 8; ++kt) {
        size_t row = rowbase + kt * 32 + cc;
        v8u k0 = *(const v8u*)(Khi + row * HID + ck + dcol);
        v8u k1 = *(const v8u*)(Khi + row * HID + ck + dcol + 8);
        v8u u0 = *(const v8u*)(Ub + row * HID + ce + dcol);
        v8u u1 = *(const v8u*)(Ub + row * HID + ce + dcol + 8);
        __syncthreads();
#pragma unroll
        for (int j = 0; j < 8; ++j) {
            Kt[(dcol + j) * 40 + cc] = k0[j];
            Kt[(dcol + 8 + j) * 40 + cc] = k1[j];
            Ut[(dcol + j) * 40 + cc] = u0[j];
            Ut[(dcol + 8 + j) * 40 + cc] = u1[j];
        }
        __syncthreads();
        v8s af[4], bf[4];
#pragma unroll
        for (int mt = 0; mt < 4; ++mt) af[mt] = *(const v8s*)&Kt[(wm + mt * 16 + l16) * 40 + quad * 8];
#pragma unroll
        for (int nt = 0; nt < 4; ++nt) bf[nt] = *(const v8s*)&Ut[(wn + nt * 16 + l16) * 40 + quad * 8];
#pragma unroll
        for (int mt = 0; mt < 4; ++mt)
#pragma unroll
            for (int nt = 0; nt < 4; ++nt)
                acc[mt][nt] = __builtin_amdgcn_mfma_f32_16x16x32_bf16(af[mt], bf[nt], acc[mt][nt], 0, 0, 0);
    }
    float* out = Spart + (size_t)ns * (8 * 256 * 256);
#pragma unroll
    for (int mt = 0; mt < 4; ++mt)
#pragma unroll
        for (int nt = 0; nt < 4; ++nt) {
            int row = dt * 128 + wm + mt * 16 + quad * 4;
            int col = et * 128 + wn + nt * 16 + l16;
#pragma unroll
            for (int r = 0; r < 4; ++r)
                out[((size_t)bh * 256 + row + r) * 256 + col] = acc[mt][nt][r];
        }
}

// ---------------- reduce SNS partials -> out1 ----------------
__global__ __launch_bounds__(256) void sreduce_kernel(const float* __restrict__ Spart,
                                                      float* __restrict__ out) {
    int i = blockIdx.x * 256 + threadIdx.x;
    float s = 0.f;
#pragma unroll
    for (int ns = 0; ns < SNS; ++ns) s += Spart[(size_t)ns * (8 * 256 * 256) + i];
    out[i] = s;
}

extern "C" void kernel_launch(void* const* d_in, const int* in_sizes, int n_in,
                              void* d_out, int out_size, void* d_ws, size_t ws_size,
                              hipStream_t stream) {
    const float* x     = (const float*)d_in[0];
    const float* Wq    = (const float*)d_in[1];
    const float* Wk    = (const float*)d_in[2];
    const float* Wv    = (const float*)d_in[3];
    const float* convq = (const float*)d_in[4];
    const float* convk = (const float*)d_in[5];
    const float* convv = (const float*)d_in[6];
    const float* Wbeta = (const float*)d_in[7];
    const float* rmsw  = (const float*)d_in[8];
    const float* Wo    = (const float*)d_in[9];

    // ---- workspace map (~130 MiB; aliases documented) ----
    char* ws = (char*)d_ws;
    size_t off = 0;
    auto alloc = [&](size_t bytes) {
        char* p = ws + off;
        off += (bytes + 255) & ~(size_t)255;
        return (void*)p;
    };
    unsigned short* xhi  = (unsigned short*)alloc((size_t)BL_TOT * HID * 2);  // later Qm/ob
    unsigned short* Khi  = (unsigned short*)alloc((size_t)BL_TOT * HID * 2);  // conv_k -> s_mfma
    unsigned short* wbV  = (unsigned short*)alloc((size_t)HID * HID * 2);
    unsigned short* wbK  = (unsigned short*)alloc((size_t)HID * HID * 2);
    unsigned short* wbQ  = (unsigned short*)alloc((size_t)HID * HID * 2);
    unsigned short* wbO  = (unsigned short*)alloc((size_t)HID * HID * 2);
    float*          Gt   = (float*)alloc((size_t)BL_TOT * HID * 4);  // gemm out; later Spart
    unsigned short* Vhi  = (unsigned short*)alloc((size_t)BL_TOT * HID * 2);
    unsigned short* Wb16 = (unsigned short*)alloc((size_t)BL_TOT * HID * 2);
    unsigned short* Ub16 = (unsigned short*)alloc((size_t)BL_TOT * HID * 2);
    float* Tg    = (float*)alloc((size_t)128 * 4096 * 4);
    float* betaB = (float*)alloc((size_t)BL_TOT * 4 * 4);
    float* kwB   = (float*)alloc((size_t)8 * 64 * 256 * 4);
    float* kuB   = (float*)alloc((size_t)8 * 64 * 256 * 4);
    float* dsA   = (float*)alloc((size_t)8 * 64 * 256 * 4);
    __hip_bfloat16* Qm = (__hip_bfloat16*)xhi;  // xhi dead after Q GEMM (last x-GEMM)
    __hip_bfloat16* ob = Qm;                    // q dead after o_kernel reads its own row
    float* Spart = Gt;                          // Gt dead after conv_q

    float* out0 = (float*)d_out;
    float* out1 = out0 + (size_t)BL_TOT * HID;
    // d_out as pre-final scratch (validated only after launch):
    unsigned short* Klo = (unsigned short*)out0;            // bytes 0..16.78M
    unsigned short* ubf = (unsigned short*)out0 + 8388608;  // bytes 16.78M..33.55M
    float* Gg = out0 + (size_t)4400000;                     // gram scratch; dead before o_kernel

    dim3 blk(256);
    dim3 ggrid(BL_TOT / 128, HID / 128);

    wcvt_kernel<<<dim3(256, 4), blk, 0, stream>>>(Wv, Wk, Wq, Wo, wbV, wbK, wbQ, wbO);
    beta_kernel<<<BL_TOT, blk, 0, stream>>>(x, Wbeta, betaB, xhi);

    // V path (plain bf16)
    gemm_mfma<<<ggrid, blk, 0, stream>>>(xhi, wbV, Gt, BL_TOT, HID, HID);
    conv_kernel<__hip_bfloat16><<<BL_TOT, blk, 0, stream>>>(Gt, convv, (__hip_bfloat16*)Vhi, 0, nullptr, nullptr);
    // K path (plain bf16 GEMM; conv emits bf16 hi/lo — gram stays faithful to the K actually used)
    gemm_mfma<<<ggrid, blk, 0, stream>>>(xhi, wbK, Gt, BL_TOT, HID, HID);
    conv_kernel<float><<<BL_TOT, blk, 0, stream>>>(Gt, convk, (float*)nullptr, 1, Khi, Klo);
    // gram + T recurrence
    gram_kernel<<<dim3(128, 4), blk, 0, stream>>>(Khi, Klo, Gg);
    trec_kernel<<<128, blk, 0, stream>>>(Gg, betaB, Tg);
    // Q path (plain bf16). Last x-GEMM: frees xhi.
    gemm_mfma<<<ggrid, blk, 0, stream>>>(xhi, wbQ, Gt, BL_TOT, HID, HID);
    conv_kernel<__hip_bfloat16><<<BL_TOT, blk, 0, stream>>>(Gt, convq, Qm, 1, nullptr, nullptr);

    // chunked delta rule
    wu_mfma_kernel<<<dim3(128, 4, 2), blk, 0, stream>>>(Tg, Khi, Vhi, betaB, Wb16, Ub16, kwB, kuB);
    scan_kernel<<<8, blk, 0, stream>>>(kwB, kuB, dsA);
    o_kernel<<<BL_TOT, blk, 0, stream>>>(Qm, Khi, Wb16, Ub16, dsA, rmsw, ob, ubf);
    s_mfma_kernel<<<dim3(8, 2, 2 * SNS), blk, 0, stream>>>(Khi, ubf, Spart);
    sreduce_kernel<<<2048, blk, 0, stream>>>(Spart, out1);

    // final projection: o(bf16) @ Wo^T -> f32 out0 (overwrites Klo/ubf scratch)
    gemm_mfma<<<ggrid, blk, 0, stream>>>((const unsigned short*)ob, wbO, out0, BL_TOT, HID, HID);
}